// Round 7
// baseline (387.203 us; speedup 1.0000x reference)
//
#include <hip/hip_runtime.h>
#include <math.h>

// Problem constants (reference: N=20000, E=160000, F=128, H=4, C1=128, C2=256, G=64, NCLS=10)
#define FDIM 128
#define HEADS 4
#define C1DIM 128
#define C2DIM 256
#define NGRAPH 64
#define NCLS 10
#define PCHUNK 8

typedef __attribute__((ext_vector_type(8))) short short8;   // 8 bf16 (4 VGPRs)
typedef __attribute__((ext_vector_type(4))) float float4v;  // 4 fp32 acc

__device__ __forceinline__ unsigned short f2bf(float f) {
    unsigned u = __builtin_bit_cast(unsigned, f);
    unsigned r = (u + 0x7FFFu + ((u >> 16) & 1u)) >> 16;   // RNE
    return (unsigned short)r;
}
__device__ __forceinline__ float bflo(int u) { return __builtin_bit_cast(float, (unsigned)u << 16); }
__device__ __forceinline__ float bfhi(int u) { return __builtin_bit_cast(float, (unsigned)u & 0xffff0000u); }
__device__ __forceinline__ float bfu(unsigned short u) { return __builtin_bit_cast(float, (unsigned)u << 16); }
__device__ __forceinline__ float lrelu(float x) { return x > 0.f ? x : 0.2f * x; }

// ---------------- CSR build ----------------
__global__ void hist_kernel(const int* __restrict__ ei, int E, int* __restrict__ counts) {
    int i = blockIdx.x * blockDim.x + threadIdx.x;
    if (i >= 2 * E) return;
    int dst = (i < E) ? ei[E + i] : ei[i - E];
    atomicAdd(&counts[dst], 1);
}

__global__ __launch_bounds__(1024) void scan_kernel(int* __restrict__ counts_cursor,
                                                    int* __restrict__ ofs, int N) {
    __shared__ int part[1024];
    int t = threadIdx.x;
    int chunk = (N + 1023) / 1024;
    int b = t * chunk;
    int e = b + chunk; if (e > N) e = N;
    int s = 0;
    for (int i = b; i < e; ++i) s += counts_cursor[i];
    part[t] = s;
    __syncthreads();
    for (int o = 1; o < 1024; o <<= 1) {
        int v = (t >= o) ? part[t - o] : 0;
        __syncthreads();
        part[t] += v;
        __syncthreads();
    }
    int run = part[t] - s;
    for (int i = b; i < e; ++i) {
        int c = counts_cursor[i];
        ofs[i] = run;
        counts_cursor[i] = run;
        run += c;
    }
    if (t == 1023) ofs[N] = part[1023];
}

__global__ void scatter_kernel(const int* __restrict__ ei, int E,
                               int* __restrict__ cursor, int* __restrict__ esrc,
                               int* __restrict__ edst) {
    int i = blockIdx.x * blockDim.x + threadIdx.x;
    if (i >= 2 * E) return;
    int src = ei[i];
    int dst = (i < E) ? ei[E + i] : ei[i - E];
    int pos = atomicAdd(&cursor[dst], 1);
    esrc[pos] = src;
    edst[pos] = dst;
}

// ---------------- fp32 -> bf16 conversions ----------------
__global__ void cvt_kernel(const float* __restrict__ src, unsigned short* __restrict__ dst, int n4) {
    int i = blockIdx.x * blockDim.x + threadIdx.x;
    if (i >= n4) return;
    float4 v = ((const float4*)src)[i];
    ushort4 o;
    o.x = f2bf(v.x); o.y = f2bf(v.y); o.z = f2bf(v.z); o.w = f2bf(v.w);
    ((ushort4*)dst)[i] = o;
}

// Transpose-convert weights: W[K,N] fp32 -> Wt[N,K] bf16. Grid (N/32, K/32), block (32,8).
__global__ void tconv_kernel(const float* __restrict__ W, unsigned short* __restrict__ Wt,
                             int K, int N_) {
    __shared__ float tile[32][33];
    int bx = blockIdx.x * 32;
    int by = blockIdx.y * 32;
    int tx = threadIdx.x, ty = threadIdx.y;
    #pragma unroll
    for (int r = 0; r < 32; r += 8)
        tile[ty + r][tx] = W[(size_t)(by + ty + r) * N_ + bx + tx];
    __syncthreads();
    #pragma unroll
    for (int r = 0; r < 32; r += 8)
        Wt[(size_t)(bx + ty + r) * K + by + tx] = f2bf(tile[tx][ty + r]);
}

// ---------------- bf16 MFMA GEMM: C[M,N] = A[M,K] @ Bt[N,K]^T, bf16 out ----------------
__global__ __launch_bounds__(256) void bgemm_kernel(
        const unsigned short* __restrict__ A,   // [M,K] bf16
        const unsigned short* __restrict__ Bt,  // [N,K] bf16
        unsigned short* __restrict__ C,         // [M,N] bf16
        int M, int N_, int K) {
    __shared__ unsigned short As[128 * 32];
    __shared__ unsigned short Bs[128 * 32];
    const int t = threadIdx.x;
    const int lane = t & 63;
    const int wave = t >> 6;
    const int row0 = blockIdx.y * 128, col0 = blockIdx.x * 128;
    const int wr = (wave >> 1) * 64, wc = (wave & 1) * 64;
    float4v acc[4][4] = {};
    for (int k0 = 0; k0 < K; k0 += 32) {
        #pragma unroll
        for (int c = 0; c < 2; ++c) {
            int i = c * 256 + t;
            int gr = row0 + (i >> 2); if (gr >= M) gr = M - 1;
            const unsigned short* gp = A + (size_t)gr * K + k0 + ((i & 3) << 3);
            __builtin_amdgcn_global_load_lds(
                (const __attribute__((address_space(1))) unsigned int*)gp,
                (__attribute__((address_space(3))) unsigned int*)&As[i * 8], 16, 0, 0);
        }
        #pragma unroll
        for (int c = 0; c < 2; ++c) {
            int i = c * 256 + t;
            int gn = col0 + (i >> 2);
            const unsigned short* gp = Bt + (size_t)gn * K + k0 + ((i & 3) << 3);
            __builtin_amdgcn_global_load_lds(
                (const __attribute__((address_space(1))) unsigned int*)gp,
                (__attribute__((address_space(3))) unsigned int*)&Bs[i * 8], 16, 0, 0);
        }
        __syncthreads();
        short8 af[4], bfr[4];
        #pragma unroll
        for (int i = 0; i < 4; ++i)
            af[i] = *(const short8*)&As[(wr + i * 16 + (lane & 15)) * 32 + (lane >> 4) * 8];
        #pragma unroll
        for (int j = 0; j < 4; ++j)
            bfr[j] = *(const short8*)&Bs[(wc + j * 16 + (lane & 15)) * 32 + (lane >> 4) * 8];
        #pragma unroll
        for (int i = 0; i < 4; ++i)
            #pragma unroll
            for (int j = 0; j < 4; ++j)
                acc[i][j] = __builtin_amdgcn_mfma_f32_16x16x32_bf16(af[i], bfr[j], acc[i][j], 0, 0, 0);
        __syncthreads();
    }
    #pragma unroll
    for (int i = 0; i < 4; ++i) {
        int rbase = row0 + wr + i * 16 + (lane >> 4) * 4;
        #pragma unroll
        for (int j = 0; j < 4; ++j) {
            int cc = col0 + wc + j * 16 + (lane & 15);
            #pragma unroll
            for (int p = 0; p < 4; ++p) {
                int r = rbase + p;
                if (r < M) C[(size_t)r * N_ + cc] = f2bf(acc[i][j][p]);
            }
        }
    }
}

// ---------------- attention scalars (bf16 inputs) ----------------
__global__ __launch_bounds__(256) void att1_kernel(const unsigned short* __restrict__ h1b,
                                                   const float* __restrict__ att_src,
                                                   const float* __restrict__ att_dst,
                                                   float* __restrict__ as1,
                                                   float* __restrict__ ad1, int N) {
    int wave = threadIdx.x >> 6, lane = threadIdx.x & 63;
    int node = blockIdx.x * 4 + wave;
    if (node >= N) return;
    int c0 = lane * 8;
    int4 r = *(const int4*)&h1b[(size_t)node * 512 + c0];
    float f0 = bflo(r.x), f1 = bfhi(r.x), f2 = bflo(r.y), f3 = bfhi(r.y);
    float f4 = bflo(r.z), f5 = bfhi(r.z), f6 = bflo(r.w), f7 = bfhi(r.w);
    float4 sA = *(const float4*)&att_src[c0], sB = *(const float4*)&att_src[c0 + 4];
    float4 dA = *(const float4*)&att_dst[c0], dB = *(const float4*)&att_dst[c0 + 4];
    float s = f0 * sA.x + f1 * sA.y + f2 * sA.z + f3 * sA.w
            + f4 * sB.x + f5 * sB.y + f6 * sB.z + f7 * sB.w;
    float d = f0 * dA.x + f1 * dA.y + f2 * dA.z + f3 * dA.w
            + f4 * dB.x + f5 * dB.y + f6 * dB.z + f7 * dB.w;
    #pragma unroll
    for (int o = 1; o <= 8; o <<= 1) { s += __shfl_xor(s, o); d += __shfl_xor(d, o); }
    if ((lane & 15) == 0) {
        int hd = lane >> 4;
        as1[node * 4 + hd] = s;
        ad1[node * 4 + hd] = d;
    }
}

__global__ __launch_bounds__(256) void att2_kernel(const unsigned short* __restrict__ h2b,
                                                   const float* __restrict__ att_src,
                                                   const float* __restrict__ att_dst,
                                                   float* __restrict__ as2,
                                                   float* __restrict__ ad2, int N) {
    int wave = threadIdx.x >> 6, lane = threadIdx.x & 63;
    int node = blockIdx.x * 4 + wave;
    if (node >= N) return;
    int c0 = lane * 4;
    int2 r = *(const int2*)&h2b[(size_t)node * 256 + c0];
    float f0 = bflo(r.x), f1 = bfhi(r.x), f2 = bflo(r.y), f3 = bfhi(r.y);
    float4 sv = *(const float4*)&att_src[c0];
    float4 dv = *(const float4*)&att_dst[c0];
    float s = f0 * sv.x + f1 * sv.y + f2 * sv.z + f3 * sv.w;
    float d = f0 * dv.x + f1 * dv.y + f2 * dv.z + f3 * dv.w;
    #pragma unroll
    for (int o = 32; o > 0; o >>= 1) { s += __shfl_xor(s, o); d += __shfl_xor(d, o); }
    if (lane == 0) { as2[node] = s; ad2[node] = d; }
}

// ---------------- edge-parallel attention-weight precompute ----------------
__global__ void wcalc1_kernel(const float4* __restrict__ as14, const float4* __restrict__ ad14,
                              const int* __restrict__ esrc, const int* __restrict__ edst,
                              float4* __restrict__ wexp4, int tot) {
    int e = blockIdx.x * blockDim.x + threadIdx.x;
    if (e >= tot) return;
    float4 a = as14[esrc[e]];
    float4 b = ad14[edst[e]];
    float4 w;
    w.x = __expf(lrelu(a.x + b.x));
    w.y = __expf(lrelu(a.y + b.y));
    w.z = __expf(lrelu(a.z + b.z));
    w.w = __expf(lrelu(a.w + b.w));
    wexp4[e] = w;
}

__global__ void wcalc2_kernel(const float* __restrict__ as2, const float* __restrict__ ad2,
                              const int* __restrict__ esrc, const int* __restrict__ edst,
                              float* __restrict__ wexp, int tot) {
    int e = blockIdx.x * blockDim.x + threadIdx.x;
    if (e >= tot) return;
    wexp[e] = __expf(lrelu(as2[esrc[e]] + ad2[edst[e]]));
}

// ---------------- edge aggregate: channel-sliced, XCD-pinned ----------------
// Layer 1: grid (8 slices, N/4). Slice s = channels [64s, 64s+64), lands on XCD s
// (round-robin heuristic). Per-XCD gather working set = 20000*64*2B = 2.5 MB -> L2-resident.
// One wave per (node, slice); lane = 1 channel (ushort gather). head = slice>>1.
__global__ __launch_bounds__(256) void edge_agg1_kernel(
        const unsigned short* __restrict__ h1b,   // [N,512] bf16
        const float* __restrict__ as1,            // [N*4]
        const float* __restrict__ ad1,
        const int* __restrict__ ofs,
        const int* __restrict__ esrc,
        const float* __restrict__ wexp,           // [tot*4]
        const float* __restrict__ b1,
        unsigned short* __restrict__ ho1b, int N) {
    int wid = threadIdx.x >> 6, lane = threadIdx.x & 63;
    int slice = blockIdx.x;                 // 0..7
    int node = blockIdx.y * 4 + wid;
    if (node >= N) return;
    int hd = slice >> 1;
    int cg = slice * 64 + lane;
    int beg = ofs[node], end = ofs[node + 1];
    float wself = __expf(lrelu(as1[node * 4 + hd] + ad1[node * 4 + hd]));
    float dsum = 0.f;
    for (int e = beg + lane; e < end; e += 64) dsum += wexp[(size_t)e * 4 + hd];
    #pragma unroll
    for (int o = 32; o > 0; o >>= 1) dsum += __shfl_xor(dsum, o);
    dsum += wself;
    float acc = wself * bfu(h1b[(size_t)node * 512 + cg]);
    int e = beg;
    for (; e + 8 <= end; e += 8) {
        int s[8]; float u[8]; unsigned short v[8];
        #pragma unroll
        for (int q = 0; q < 8; ++q) s[q] = esrc[e + q];
        #pragma unroll
        for (int q = 0; q < 8; ++q) u[q] = wexp[(size_t)(e + q) * 4 + hd];
        #pragma unroll
        for (int q = 0; q < 8; ++q) v[q] = h1b[(size_t)s[q] * 512 + cg];
        #pragma unroll
        for (int q = 0; q < 8; ++q) acc += u[q] * bfu(v[q]);
    }
    for (; e < end; ++e) {
        int s = esrc[e];
        float u = wexp[(size_t)e * 4 + hd];
        acc += u * bfu(h1b[(size_t)s * 512 + cg]);
    }
    float v = fmaxf(acc / dsum + b1[cg], 0.f);   // +bias, fused ReLU
    ho1b[(size_t)node * 512 + cg] = f2bf(v);
}

// Layer 2: grid (4 slices, N/4). Slice s = channels [64s, 64s+64); working set 2.5 MB.
__global__ __launch_bounds__(256) void edge_agg2_kernel(
        const unsigned short* __restrict__ h2b,   // [N,256] bf16
        const float* __restrict__ as2,
        const float* __restrict__ ad2,
        const int* __restrict__ ofs,
        const int* __restrict__ esrc,
        const float* __restrict__ wexp,           // [tot]
        const float* __restrict__ b2,
        unsigned short* __restrict__ ho2b, int N) {
    int wid = threadIdx.x >> 6, lane = threadIdx.x & 63;
    int slice = blockIdx.x;                 // 0..3
    int node = blockIdx.y * 4 + wid;
    if (node >= N) return;
    int cg = slice * 64 + lane;
    int beg = ofs[node], end = ofs[node + 1];
    float wself = __expf(lrelu(as2[node] + ad2[node]));
    float dsum = 0.f;
    for (int e = beg + lane; e < end; e += 64) dsum += wexp[e];
    #pragma unroll
    for (int o = 32; o > 0; o >>= 1) dsum += __shfl_xor(dsum, o);
    dsum += wself;
    float acc = wself * bfu(h2b[(size_t)node * 256 + cg]);
    int e = beg;
    for (; e + 8 <= end; e += 8) {
        int s[8]; float u[8]; unsigned short v[8];
        #pragma unroll
        for (int q = 0; q < 8; ++q) s[q] = esrc[e + q];
        #pragma unroll
        for (int q = 0; q < 8; ++q) u[q] = wexp[e + q];
        #pragma unroll
        for (int q = 0; q < 8; ++q) v[q] = h2b[(size_t)s[q] * 256 + cg];
        #pragma unroll
        for (int q = 0; q < 8; ++q) acc += u[q] * bfu(v[q]);
    }
    for (; e < end; ++e) {
        acc += wexp[e] * bfu(h2b[(size_t)esrc[e] * 256 + cg]);
    }
    float v = acc / dsum + b2[cg];
    ho2b[(size_t)node * 256 + cg] = f2bf(v);
}

// ---------------- global max pool, stage 1 (batch is sorted; bf16 input) ----------------
__global__ __launch_bounds__(256) void pool1_kernel(const unsigned short* __restrict__ ho2b,
                                                    const int* __restrict__ batch,
                                                    int N, float* __restrict__ part) {
    int g = blockIdx.x, c = blockIdx.y, t = threadIdx.x;
    int lo = 0, hi = N;
    while (lo < hi) { int mid = (lo + hi) >> 1; if (batch[mid] < g) lo = mid + 1; else hi = mid; }
    int start = lo;
    lo = 0; hi = N;
    while (lo < hi) { int mid = (lo + hi) >> 1; if (batch[mid] < g + 1) lo = mid + 1; else hi = mid; }
    int end = lo;
    int len = end - start;
    int cb = start + (int)(((long long)len * c) / PCHUNK);
    int ce = start + (int)(((long long)len * (c + 1)) / PCHUNK);
    float m = -INFINITY;
    for (int n = cb; n < ce; ++n) m = fmaxf(m, bfu(ho2b[(size_t)n * 256 + t]));
    part[((size_t)g * PCHUNK + c) * 256 + t] = m;
}

// ---------------- FC head (+pool stage 2) + log_softmax ----------------
__global__ __launch_bounds__(64) void head_kernel(const float* __restrict__ part,
                                                  const float* __restrict__ fc1w,
                                                  const float* __restrict__ fc1b,
                                                  const float* __restrict__ fc2w,
                                                  const float* __restrict__ fc2b,
                                                  float* __restrict__ out) {
    __shared__ float gr[256];
    __shared__ float hid[64];
    __shared__ float o10[NCLS];
    int g = blockIdx.x, t = threadIdx.x;
    for (int i = t; i < 256; i += 64) {
        float m = -INFINITY;
        #pragma unroll
        for (int c = 0; c < PCHUNK; ++c)
            m = fmaxf(m, part[((size_t)g * PCHUNK + c) * 256 + i]);
        gr[i] = m;
    }
    __syncthreads();
    float s = fc1b[t];
    for (int k = 0; k < 256; ++k) s += gr[k] * fc1w[k * 64 + t];
    hid[t] = s > 0.f ? s : 0.f;
    __syncthreads();
    if (t < NCLS) {
        float s2 = fc2b[t];
        for (int k = 0; k < 64; ++k) s2 += hid[k] * fc2w[k * NCLS + t];
        o10[t] = s2;
    }
    __syncthreads();
    if (t == 0) {
        float mx = -INFINITY;
        for (int c = 0; c < NCLS; ++c) mx = fmaxf(mx, o10[c]);
        float se = 0.f;
        for (int c = 0; c < NCLS; ++c) se += __expf(o10[c] - mx);
        float lse = mx + logf(se);
        for (int c = 0; c < NCLS; ++c) out[g * NCLS + c] = o10[c] - lse;
    }
}

extern "C" void kernel_launch(void* const* d_in, const int* in_sizes, int n_in,
                              void* d_out, int out_size, void* d_ws, size_t ws_size,
                              hipStream_t stream) {
    (void)n_in; (void)out_size; (void)ws_size;
    const float* x        = (const float*)d_in[0];
    const int*   ei       = (const int*)d_in[1];
    const int*   batch    = (const int*)d_in[2];
    const float* W1       = (const float*)d_in[3];
    const float* att_src1 = (const float*)d_in[4];
    const float* att_dst1 = (const float*)d_in[5];
    const float* b1       = (const float*)d_in[6];
    const float* W2       = (const float*)d_in[7];
    const float* att_src2 = (const float*)d_in[8];
    const float* att_dst2 = (const float*)d_in[9];
    const float* b2       = (const float*)d_in[10];
    const float* fc1w     = (const float*)d_in[11];
    const float* fc1b     = (const float*)d_in[12];
    const float* fc2w     = (const float*)d_in[13];
    const float* fc2b     = (const float*)d_in[14];

    const int N = in_sizes[2];
    const int E = in_sizes[1] / 2;
    const int tot = 2 * E;

    char* base = (char*)d_ws;
    size_t off = 0;
    auto alloc = [&](size_t bytes) -> void* {
        void* p = base + off;
        off = (off + bytes + 255) & ~(size_t)255;
        return p;
    };
    int*   ofs    = (int*)alloc((size_t)(N + 1) * 4);
    int*   cursor = (int*)alloc((size_t)N * 4);
    int*   esrc   = (int*)alloc((size_t)tot * 4);
    int*   edst   = (int*)alloc((size_t)tot * 4);
    float* as1    = (float*)alloc((size_t)N * HEADS * 4);
    float* ad1    = (float*)alloc((size_t)N * HEADS * 4);
    float* as2    = (float*)alloc((size_t)N * 4);
    float* ad2    = (float*)alloc((size_t)N * 4);
    float* wexp1  = (float*)alloc((size_t)tot * HEADS * 4);
    float* wexp2  = (float*)alloc((size_t)tot * 4);
    unsigned short* xb   = (unsigned short*)alloc((size_t)N * FDIM * 2);
    unsigned short* W1t  = (unsigned short*)alloc((size_t)512 * 128 * 2);
    unsigned short* W2t  = (unsigned short*)alloc((size_t)256 * 512 * 2);
    unsigned short* h1b  = (unsigned short*)alloc((size_t)N * 512 * 2);
    unsigned short* ho1b = (unsigned short*)alloc((size_t)N * 512 * 2);
    unsigned short* h2b  = (unsigned short*)alloc((size_t)N * 256 * 2);
    unsigned short* ho2b = (unsigned short*)alloc((size_t)N * 256 * 2);
    float* ppart  = (float*)alloc((size_t)NGRAPH * PCHUNK * 256 * 4);

    // CSR build
    hipMemsetAsync(cursor, 0, (size_t)N * 4, stream);
    hist_kernel<<<(tot + 255) / 256, 256, 0, stream>>>(ei, E, cursor);
    scan_kernel<<<1, 1024, 0, stream>>>(cursor, ofs, N);
    scatter_kernel<<<(tot + 255) / 256, 256, 0, stream>>>(ei, E, cursor, esrc, edst);

    // bf16 conversions
    cvt_kernel<<<(N * FDIM / 4 + 255) / 256, 256, 0, stream>>>(x, xb, N * FDIM / 4);
    tconv_kernel<<<dim3(512 / 32, 128 / 32), dim3(32, 8), 0, stream>>>(W1, W1t, 128, 512);
    tconv_kernel<<<dim3(256 / 32, 512 / 32), dim3(32, 8), 0, stream>>>(W2, W2t, 512, 256);

    // Layer 1: h1 = x @ W1  (M=N, N=512, K=128)
    bgemm_kernel<<<dim3(512 / 128, (N + 127) / 128), 256, 0, stream>>>(xb, W1t, h1b, N, 512, 128);
    att1_kernel<<<(N + 3) / 4, 256, 0, stream>>>(h1b, att_src1, att_dst1, as1, ad1, N);
    wcalc1_kernel<<<(tot + 255) / 256, 256, 0, stream>>>((const float4*)as1, (const float4*)ad1,
                                                         esrc, edst, (float4*)wexp1, tot);
    edge_agg1_kernel<<<dim3(8, (N + 3) / 4), 256, 0, stream>>>(h1b, as1, ad1,
                                                               ofs, esrc, wexp1, b1, ho1b, N);

    // Layer 2: h2 = ho1 @ W2  (M=N, N=256, K=512)
    bgemm_kernel<<<dim3(256 / 128, (N + 127) / 128), 256, 0, stream>>>(ho1b, W2t, h2b, N, 256, 512);
    att2_kernel<<<(N + 3) / 4, 256, 0, stream>>>(h2b, att_src2, att_dst2, as2, ad2, N);
    wcalc2_kernel<<<(tot + 255) / 256, 256, 0, stream>>>(as2, ad2, esrc, edst, wexp2, tot);
    edge_agg2_kernel<<<dim3(4, (N + 3) / 4), 256, 0, stream>>>(h2b, as2, ad2,
                                                               ofs, esrc, wexp2, b2, ho2b, N);

    // Pool stage 1 + fused (pool stage 2 + head)
    pool1_kernel<<<dim3(NGRAPH, PCHUNK), 256, 0, stream>>>(ho2b, batch, N, ppart);
    head_kernel<<<NGRAPH, 64, 0, stream>>>(ppart, fc1w, fc1b, fc2w, fc2b, (float*)d_out);
}

// Round 8
// 312.605 us; speedup vs baseline: 1.2386x; 1.2386x over previous
//
#include <hip/hip_runtime.h>
#include <math.h>

// Problem constants (reference: N=20000, E=160000, F=128, H=4, C1=128, C2=256, G=64, NCLS=10)
#define FDIM 128
#define HEADS 4
#define C1DIM 128
#define C2DIM 256
#define NGRAPH 64
#define NCLS 10
#define PCHUNK 8

typedef __attribute__((ext_vector_type(8))) short short8;   // 8 bf16 (4 VGPRs)
typedef __attribute__((ext_vector_type(4))) float float4v;  // 4 fp32 acc

__device__ __forceinline__ unsigned short f2bf(float f) {
    unsigned u = __builtin_bit_cast(unsigned, f);
    unsigned r = (u + 0x7FFFu + ((u >> 16) & 1u)) >> 16;   // RNE
    return (unsigned short)r;
}
__device__ __forceinline__ float bflo(int u) { return __builtin_bit_cast(float, (unsigned)u << 16); }
__device__ __forceinline__ float bfhi(int u) { return __builtin_bit_cast(float, (unsigned)u & 0xffff0000u); }
__device__ __forceinline__ float bfu(unsigned short u) { return __builtin_bit_cast(float, (unsigned)u << 16); }
__device__ __forceinline__ float lrelu(float x) { return x > 0.f ? x : 0.2f * x; }

// ---------------- CSR build ----------------
__global__ void hist_kernel(const int* __restrict__ ei, int E, int* __restrict__ counts) {
    int i = blockIdx.x * blockDim.x + threadIdx.x;
    if (i >= 2 * E) return;
    int dst = (i < E) ? ei[E + i] : ei[i - E];
    atomicAdd(&counts[dst], 1);
}

__global__ __launch_bounds__(1024) void scan_kernel(int* __restrict__ counts_cursor,
                                                    int* __restrict__ ofs, int N) {
    __shared__ int part[1024];
    int t = threadIdx.x;
    int chunk = (N + 1023) / 1024;
    int b = t * chunk;
    int e = b + chunk; if (e > N) e = N;
    int s = 0;
    for (int i = b; i < e; ++i) s += counts_cursor[i];
    part[t] = s;
    __syncthreads();
    for (int o = 1; o < 1024; o <<= 1) {
        int v = (t >= o) ? part[t - o] : 0;
        __syncthreads();
        part[t] += v;
        __syncthreads();
    }
    int run = part[t] - s;
    for (int i = b; i < e; ++i) {
        int c = counts_cursor[i];
        ofs[i] = run;
        counts_cursor[i] = run;
        run += c;
    }
    if (t == 1023) ofs[N] = part[1023];
}

__global__ void scatter_kernel(const int* __restrict__ ei, int E,
                               int* __restrict__ cursor, int* __restrict__ esrc,
                               int* __restrict__ edst) {
    int i = blockIdx.x * blockDim.x + threadIdx.x;
    if (i >= 2 * E) return;
    int src = ei[i];
    int dst = (i < E) ? ei[E + i] : ei[i - E];
    int pos = atomicAdd(&cursor[dst], 1);
    esrc[pos] = src;
    edst[pos] = dst;
}

// ---------------- fp32 -> bf16 conversions ----------------
__global__ void cvt_kernel(const float* __restrict__ src, unsigned short* __restrict__ dst, int n4) {
    int i = blockIdx.x * blockDim.x + threadIdx.x;
    if (i >= n4) return;
    float4 v = ((const float4*)src)[i];
    ushort4 o;
    o.x = f2bf(v.x); o.y = f2bf(v.y); o.z = f2bf(v.z); o.w = f2bf(v.w);
    ((ushort4*)dst)[i] = o;
}

// Transpose-convert weights: W[K,N] fp32 -> Wt[N,K] bf16. Grid (N/32, K/32), block (32,8).
__global__ void tconv_kernel(const float* __restrict__ W, unsigned short* __restrict__ Wt,
                             int K, int N_) {
    __shared__ float tile[32][33];
    int bx = blockIdx.x * 32;
    int by = blockIdx.y * 32;
    int tx = threadIdx.x, ty = threadIdx.y;
    #pragma unroll
    for (int r = 0; r < 32; r += 8)
        tile[ty + r][tx] = W[(size_t)(by + ty + r) * N_ + bx + tx];
    __syncthreads();
    #pragma unroll
    for (int r = 0; r < 32; r += 8)
        Wt[(size_t)(bx + ty + r) * K + by + tx] = f2bf(tile[tx][ty + r]);
}

// ---------------- bf16 MFMA GEMM: C[M,N] = A[M,K] @ Bt[N,K]^T, bf16 out ----------------
__global__ __launch_bounds__(256) void bgemm_kernel(
        const unsigned short* __restrict__ A,   // [M,K] bf16
        const unsigned short* __restrict__ Bt,  // [N,K] bf16
        unsigned short* __restrict__ C,         // [M,N] bf16
        int M, int N_, int K) {
    __shared__ unsigned short As[128 * 32];
    __shared__ unsigned short Bs[128 * 32];
    const int t = threadIdx.x;
    const int lane = t & 63;
    const int wave = t >> 6;
    const int row0 = blockIdx.y * 128, col0 = blockIdx.x * 128;
    const int wr = (wave >> 1) * 64, wc = (wave & 1) * 64;
    float4v acc[4][4] = {};
    for (int k0 = 0; k0 < K; k0 += 32) {
        #pragma unroll
        for (int c = 0; c < 2; ++c) {
            int i = c * 256 + t;
            int gr = row0 + (i >> 2); if (gr >= M) gr = M - 1;
            const unsigned short* gp = A + (size_t)gr * K + k0 + ((i & 3) << 3);
            __builtin_amdgcn_global_load_lds(
                (const __attribute__((address_space(1))) unsigned int*)gp,
                (__attribute__((address_space(3))) unsigned int*)&As[i * 8], 16, 0, 0);
        }
        #pragma unroll
        for (int c = 0; c < 2; ++c) {
            int i = c * 256 + t;
            int gn = col0 + (i >> 2);
            const unsigned short* gp = Bt + (size_t)gn * K + k0 + ((i & 3) << 3);
            __builtin_amdgcn_global_load_lds(
                (const __attribute__((address_space(1))) unsigned int*)gp,
                (__attribute__((address_space(3))) unsigned int*)&Bs[i * 8], 16, 0, 0);
        }
        __syncthreads();
        short8 af[4], bfr[4];
        #pragma unroll
        for (int i = 0; i < 4; ++i)
            af[i] = *(const short8*)&As[(wr + i * 16 + (lane & 15)) * 32 + (lane >> 4) * 8];
        #pragma unroll
        for (int j = 0; j < 4; ++j)
            bfr[j] = *(const short8*)&Bs[(wc + j * 16 + (lane & 15)) * 32 + (lane >> 4) * 8];
        #pragma unroll
        for (int i = 0; i < 4; ++i)
            #pragma unroll
            for (int j = 0; j < 4; ++j)
                acc[i][j] = __builtin_amdgcn_mfma_f32_16x16x32_bf16(af[i], bfr[j], acc[i][j], 0, 0, 0);
        __syncthreads();
    }
    #pragma unroll
    for (int i = 0; i < 4; ++i) {
        int rbase = row0 + wr + i * 16 + (lane >> 4) * 4;
        #pragma unroll
        for (int j = 0; j < 4; ++j) {
            int cc = col0 + wc + j * 16 + (lane & 15);
            #pragma unroll
            for (int p = 0; p < 4; ++p) {
                int r = rbase + p;
                if (r < M) C[(size_t)r * N_ + cc] = f2bf(acc[i][j][p]);
            }
        }
    }
}

// ---------------- attention scalars (bf16 inputs) ----------------
__global__ __launch_bounds__(256) void att1_kernel(const unsigned short* __restrict__ h1b,
                                                   const float* __restrict__ att_src,
                                                   const float* __restrict__ att_dst,
                                                   float* __restrict__ as1,
                                                   float* __restrict__ ad1, int N) {
    int wave = threadIdx.x >> 6, lane = threadIdx.x & 63;
    int node = blockIdx.x * 4 + wave;
    if (node >= N) return;
    int c0 = lane * 8;
    int4 r = *(const int4*)&h1b[(size_t)node * 512 + c0];
    float f0 = bflo(r.x), f1 = bfhi(r.x), f2 = bflo(r.y), f3 = bfhi(r.y);
    float f4 = bflo(r.z), f5 = bfhi(r.z), f6 = bflo(r.w), f7 = bfhi(r.w);
    float4 sA = *(const float4*)&att_src[c0], sB = *(const float4*)&att_src[c0 + 4];
    float4 dA = *(const float4*)&att_dst[c0], dB = *(const float4*)&att_dst[c0 + 4];
    float s = f0 * sA.x + f1 * sA.y + f2 * sA.z + f3 * sA.w
            + f4 * sB.x + f5 * sB.y + f6 * sB.z + f7 * sB.w;
    float d = f0 * dA.x + f1 * dA.y + f2 * dA.z + f3 * dA.w
            + f4 * dB.x + f5 * dB.y + f6 * dB.z + f7 * dB.w;
    #pragma unroll
    for (int o = 1; o <= 8; o <<= 1) { s += __shfl_xor(s, o); d += __shfl_xor(d, o); }
    if ((lane & 15) == 0) {
        int hd = lane >> 4;
        as1[node * 4 + hd] = s;
        ad1[node * 4 + hd] = d;
    }
}

__global__ __launch_bounds__(256) void att2_kernel(const unsigned short* __restrict__ h2b,
                                                   const float* __restrict__ att_src,
                                                   const float* __restrict__ att_dst,
                                                   float* __restrict__ as2,
                                                   float* __restrict__ ad2, int N) {
    int wave = threadIdx.x >> 6, lane = threadIdx.x & 63;
    int node = blockIdx.x * 4 + wave;
    if (node >= N) return;
    int c0 = lane * 4;
    int2 r = *(const int2*)&h2b[(size_t)node * 256 + c0];
    float f0 = bflo(r.x), f1 = bfhi(r.x), f2 = bflo(r.y), f3 = bfhi(r.y);
    float4 sv = *(const float4*)&att_src[c0];
    float4 dv = *(const float4*)&att_dst[c0];
    float s = f0 * sv.x + f1 * sv.y + f2 * sv.z + f3 * sv.w;
    float d = f0 * dv.x + f1 * dv.y + f2 * dv.z + f3 * dv.w;
    #pragma unroll
    for (int o = 32; o > 0; o >>= 1) { s += __shfl_xor(s, o); d += __shfl_xor(d, o); }
    if (lane == 0) { as2[node] = s; ad2[node] = d; }
}

// ---------------- edge-parallel attention-weight precompute ----------------
__global__ void wcalc1_kernel(const float4* __restrict__ as14, const float4* __restrict__ ad14,
                              const int* __restrict__ esrc, const int* __restrict__ edst,
                              float4* __restrict__ wexp4, int tot) {
    int e = blockIdx.x * blockDim.x + threadIdx.x;
    if (e >= tot) return;
    float4 a = as14[esrc[e]];
    float4 b = ad14[edst[e]];
    float4 w;
    w.x = __expf(lrelu(a.x + b.x));
    w.y = __expf(lrelu(a.y + b.y));
    w.z = __expf(lrelu(a.z + b.z));
    w.w = __expf(lrelu(a.w + b.w));
    wexp4[e] = w;
}

__global__ void wcalc2_kernel(const float* __restrict__ as2, const float* __restrict__ ad2,
                              const int* __restrict__ esrc, const int* __restrict__ edst,
                              float* __restrict__ wexp, int tot) {
    int e = blockIdx.x * blockDim.x + threadIdx.x;
    if (e >= tot) return;
    wexp[e] = __expf(lrelu(as2[esrc[e]] + ad2[edst[e]]));
}

// ---------------- edge aggregate: full-channel wave + edge-range split ----------------
// Layer 1: block = 4 waves = 2 nodes x 2 edge-halves. Each wave covers all 512 ch
// (8 ch/lane, int4 gathers) over HALF the node's edges; partials combined via LDS.
// Per-edge instruction cost identical to the R5 form; serial chain halved; 2x waves.
__global__ __launch_bounds__(256) void edge_agg1_kernel(
        const unsigned short* __restrict__ h1b,   // [N,512] bf16
        const float4* __restrict__ as14,
        const float4* __restrict__ ad14,
        const int* __restrict__ ofs,
        const int* __restrict__ esrc,
        const float* __restrict__ wexp,           // [tot*4]
        const float* __restrict__ b1,
        unsigned short* __restrict__ ho1b, int N) {
    __shared__ float comb[4][512];
    int wid = threadIdx.x >> 6, lane = threadIdx.x & 63;
    int node = blockIdx.x * 2 + (wid >> 1);
    int ehalf = wid & 1;
    bool valid = node < N;
    int beg = 0, end = 0;
    if (valid) { beg = ofs[node]; end = ofs[node + 1]; }
    float w0 = 0.f, w1 = 0.f, w2 = 0.f, w3 = 0.f;
    if (valid) {
        float4 asn = as14[node], adn = ad14[node];
        w0 = __expf(lrelu(asn.x + adn.x));
        w1 = __expf(lrelu(asn.y + adn.y));
        w2 = __expf(lrelu(asn.z + adn.z));
        w3 = __expf(lrelu(asn.w + adn.w));
    }
    // full denominator (both waves compute; coalesced float4 reads, deg~16 -> 1 iter)
    float d0 = 0.f, d1 = 0.f, d2 = 0.f, d3 = 0.f;
    for (int e = beg + lane; e < end; e += 64) {
        float4 w = ((const float4*)wexp)[e];
        d0 += w.x; d1 += w.y; d2 += w.z; d3 += w.w;
    }
    #pragma unroll
    for (int o = 32; o > 0; o >>= 1) {
        d0 += __shfl_xor(d0, o); d1 += __shfl_xor(d1, o);
        d2 += __shfl_xor(d2, o); d3 += __shfl_xor(d3, o);
    }
    d0 += w0; d1 += w1; d2 += w2; d3 += w3;
    int hd = lane >> 4;
    int c0 = lane * 8;
    float wsh = hd == 0 ? w0 : hd == 1 ? w1 : hd == 2 ? w2 : w3;
    float dh  = hd == 0 ? d0 : hd == 1 ? d1 : hd == 2 ? d2 : d3;

    float acc[8] = {0.f, 0.f, 0.f, 0.f, 0.f, 0.f, 0.f, 0.f};
    if (valid && ehalf == 0) {          // self term in half 0 only
        int4 r = *(const int4*)&h1b[(size_t)node * 512 + c0];
        acc[0] = wsh * bflo(r.x); acc[1] = wsh * bfhi(r.x);
        acc[2] = wsh * bflo(r.y); acc[3] = wsh * bfhi(r.y);
        acc[4] = wsh * bflo(r.z); acc[5] = wsh * bfhi(r.z);
        acc[6] = wsh * bflo(r.w); acc[7] = wsh * bfhi(r.w);
    }
    int mid = beg + ((end - beg) >> 1);
    int eb = ehalf ? mid : beg;
    int ee = ehalf ? end : mid;
    int e = eb;
    for (; e + 4 <= ee; e += 4) {
        int s0 = esrc[e], s1 = esrc[e + 1], s2 = esrc[e + 2], s3 = esrc[e + 3];
        float u0 = wexp[(size_t)(e + 0) * 4 + hd];
        float u1 = wexp[(size_t)(e + 1) * 4 + hd];
        float u2 = wexp[(size_t)(e + 2) * 4 + hd];
        float u3 = wexp[(size_t)(e + 3) * 4 + hd];
        int4 r0 = *(const int4*)&h1b[(size_t)s0 * 512 + c0];
        int4 r1 = *(const int4*)&h1b[(size_t)s1 * 512 + c0];
        int4 r2 = *(const int4*)&h1b[(size_t)s2 * 512 + c0];
        int4 r3 = *(const int4*)&h1b[(size_t)s3 * 512 + c0];
        acc[0] += u0 * bflo(r0.x); acc[1] += u0 * bfhi(r0.x);
        acc[2] += u0 * bflo(r0.y); acc[3] += u0 * bfhi(r0.y);
        acc[4] += u0 * bflo(r0.z); acc[5] += u0 * bfhi(r0.z);
        acc[6] += u0 * bflo(r0.w); acc[7] += u0 * bfhi(r0.w);
        acc[0] += u1 * bflo(r1.x); acc[1] += u1 * bfhi(r1.x);
        acc[2] += u1 * bflo(r1.y); acc[3] += u1 * bfhi(r1.y);
        acc[4] += u1 * bflo(r1.z); acc[5] += u1 * bfhi(r1.z);
        acc[6] += u1 * bflo(r1.w); acc[7] += u1 * bfhi(r1.w);
        acc[0] += u2 * bflo(r2.x); acc[1] += u2 * bfhi(r2.x);
        acc[2] += u2 * bflo(r2.y); acc[3] += u2 * bfhi(r2.y);
        acc[4] += u2 * bflo(r2.z); acc[5] += u2 * bfhi(r2.z);
        acc[6] += u2 * bflo(r2.w); acc[7] += u2 * bfhi(r2.w);
        acc[0] += u3 * bflo(r3.x); acc[1] += u3 * bfhi(r3.x);
        acc[2] += u3 * bflo(r3.y); acc[3] += u3 * bfhi(r3.y);
        acc[4] += u3 * bflo(r3.z); acc[5] += u3 * bfhi(r3.z);
        acc[6] += u3 * bflo(r3.w); acc[7] += u3 * bfhi(r3.w);
    }
    for (; e < ee; ++e) {
        int s = esrc[e];
        float u = wexp[(size_t)e * 4 + hd];
        int4 r = *(const int4*)&h1b[(size_t)s * 512 + c0];
        acc[0] += u * bflo(r.x); acc[1] += u * bfhi(r.x);
        acc[2] += u * bflo(r.y); acc[3] += u * bfhi(r.y);
        acc[4] += u * bflo(r.z); acc[5] += u * bfhi(r.z);
        acc[6] += u * bflo(r.w); acc[7] += u * bfhi(r.w);
    }
    // combine the two halves through LDS
    *(float4*)&comb[wid][lane * 8]     = make_float4(acc[0], acc[1], acc[2], acc[3]);
    *(float4*)&comb[wid][lane * 8 + 4] = make_float4(acc[4], acc[5], acc[6], acc[7]);
    __syncthreads();
    if (valid && ehalf == 0) {
        float4 pA = *(const float4*)&comb[wid + 1][lane * 8];
        float4 pB = *(const float4*)&comb[wid + 1][lane * 8 + 4];
        float inv = 1.f / dh;
        float4 bA = *(const float4*)&b1[c0], bB = *(const float4*)&b1[c0 + 4];
        float v0 = fmaxf((acc[0] + pA.x) * inv + bA.x, 0.f);
        float v1 = fmaxf((acc[1] + pA.y) * inv + bA.y, 0.f);
        float v2 = fmaxf((acc[2] + pA.z) * inv + bA.z, 0.f);
        float v3 = fmaxf((acc[3] + pA.w) * inv + bA.w, 0.f);
        float v4 = fmaxf((acc[4] + pB.x) * inv + bB.x, 0.f);
        float v5 = fmaxf((acc[5] + pB.y) * inv + bB.y, 0.f);
        float v6 = fmaxf((acc[6] + pB.z) * inv + bB.z, 0.f);
        float v7 = fmaxf((acc[7] + pB.w) * inv + bB.w, 0.f);
        int4 o;
        o.x = (int)((unsigned)f2bf(v0) | ((unsigned)f2bf(v1) << 16));
        o.y = (int)((unsigned)f2bf(v2) | ((unsigned)f2bf(v3) << 16));
        o.z = (int)((unsigned)f2bf(v4) | ((unsigned)f2bf(v5) << 16));
        o.w = (int)((unsigned)f2bf(v6) | ((unsigned)f2bf(v7) << 16));
        *(int4*)&ho1b[(size_t)node * 512 + c0] = o;
    }
}

// Layer 2: block = 4 waves = 2 nodes x 2 edge-halves; lane = 4 ch of 256 (int2 gathers).
__global__ __launch_bounds__(256) void edge_agg2_kernel(
        const unsigned short* __restrict__ h2b,   // [N,256] bf16
        const float* __restrict__ as2,
        const float* __restrict__ ad2,
        const int* __restrict__ ofs,
        const int* __restrict__ esrc,
        const float* __restrict__ wexp,           // [tot]
        const float* __restrict__ b2,
        unsigned short* __restrict__ ho2b, int N) {
    __shared__ float comb[4][256];
    int wid = threadIdx.x >> 6, lane = threadIdx.x & 63;
    int node = blockIdx.x * 2 + (wid >> 1);
    int ehalf = wid & 1;
    bool valid = node < N;
    int beg = 0, end = 0;
    if (valid) { beg = ofs[node]; end = ofs[node + 1]; }
    float wself = valid ? __expf(lrelu(as2[node] + ad2[node])) : 0.f;
    float dsum = 0.f;
    for (int e = beg + lane; e < end; e += 64) dsum += wexp[e];
    #pragma unroll
    for (int o = 32; o > 0; o >>= 1) dsum += __shfl_xor(dsum, o);
    dsum += wself;
    int c0 = lane * 4;
    float a0 = 0.f, a1 = 0.f, a2 = 0.f, a3 = 0.f;
    if (valid && ehalf == 0) {
        int2 r = *(const int2*)&h2b[(size_t)node * 256 + c0];
        a0 = wself * bflo(r.x); a1 = wself * bfhi(r.x);
        a2 = wself * bflo(r.y); a3 = wself * bfhi(r.y);
    }
    int mid = beg + ((end - beg) >> 1);
    int eb = ehalf ? mid : beg;
    int ee = ehalf ? end : mid;
    int e = eb;
    for (; e + 4 <= ee; e += 4) {
        int s0 = esrc[e], s1 = esrc[e + 1], s2 = esrc[e + 2], s3 = esrc[e + 3];
        float u0 = wexp[e], u1 = wexp[e + 1], u2 = wexp[e + 2], u3 = wexp[e + 3];
        int2 r0 = *(const int2*)&h2b[(size_t)s0 * 256 + c0];
        int2 r1 = *(const int2*)&h2b[(size_t)s1 * 256 + c0];
        int2 r2 = *(const int2*)&h2b[(size_t)s2 * 256 + c0];
        int2 r3 = *(const int2*)&h2b[(size_t)s3 * 256 + c0];
        a0 += u0 * bflo(r0.x); a1 += u0 * bfhi(r0.x);
        a2 += u0 * bflo(r0.y); a3 += u0 * bfhi(r0.y);
        a0 += u1 * bflo(r1.x); a1 += u1 * bfhi(r1.x);
        a2 += u1 * bflo(r1.y); a3 += u1 * bfhi(r1.y);
        a0 += u2 * bflo(r2.x); a1 += u2 * bfhi(r2.x);
        a2 += u2 * bflo(r2.y); a3 += u2 * bfhi(r2.y);
        a0 += u3 * bflo(r3.x); a1 += u3 * bfhi(r3.x);
        a2 += u3 * bflo(r3.y); a3 += u3 * bfhi(r3.y);
    }
    for (; e < ee; ++e) {
        int s = esrc[e];
        float u = wexp[e];
        int2 r = *(const int2*)&h2b[(size_t)s * 256 + c0];
        a0 += u * bflo(r.x); a1 += u * bfhi(r.x);
        a2 += u * bflo(r.y); a3 += u * bfhi(r.y);
    }
    *(float4*)&comb[wid][lane * 4] = make_float4(a0, a1, a2, a3);
    __syncthreads();
    if (valid && ehalf == 0) {
        float4 p = *(const float4*)&comb[wid + 1][lane * 4];
        float inv = 1.f / dsum;
        float4 bv = *(const float4*)&b2[c0];
        float v0 = (a0 + p.x) * inv + bv.x;
        float v1 = (a1 + p.y) * inv + bv.y;
        float v2 = (a2 + p.z) * inv + bv.z;
        float v3 = (a3 + p.w) * inv + bv.w;
        int2 o;
        o.x = (int)((unsigned)f2bf(v0) | ((unsigned)f2bf(v1) << 16));
        o.y = (int)((unsigned)f2bf(v2) | ((unsigned)f2bf(v3) << 16));
        *(int2*)&ho2b[(size_t)node * 256 + c0] = o;
    }
}

// ---------------- global max pool, stage 1 (batch is sorted; bf16 input) ----------------
__global__ __launch_bounds__(256) void pool1_kernel(const unsigned short* __restrict__ ho2b,
                                                    const int* __restrict__ batch,
                                                    int N, float* __restrict__ part) {
    int g = blockIdx.x, c = blockIdx.y, t = threadIdx.x;
    int lo = 0, hi = N;
    while (lo < hi) { int mid = (lo + hi) >> 1; if (batch[mid] < g) lo = mid + 1; else hi = mid; }
    int start = lo;
    lo = 0; hi = N;
    while (lo < hi) { int mid = (lo + hi) >> 1; if (batch[mid] < g + 1) lo = mid + 1; else hi = mid; }
    int end = lo;
    int len = end - start;
    int cb = start + (int)(((long long)len * c) / PCHUNK);
    int ce = start + (int)(((long long)len * (c + 1)) / PCHUNK);
    float m = -INFINITY;
    for (int n = cb; n < ce; ++n) m = fmaxf(m, bfu(ho2b[(size_t)n * 256 + t]));
    part[((size_t)g * PCHUNK + c) * 256 + t] = m;
}

// ---------------- FC head (+pool stage 2) + log_softmax ----------------
__global__ __launch_bounds__(64) void head_kernel(const float* __restrict__ part,
                                                  const float* __restrict__ fc1w,
                                                  const float* __restrict__ fc1b,
                                                  const float* __restrict__ fc2w,
                                                  const float* __restrict__ fc2b,
                                                  float* __restrict__ out) {
    __shared__ float gr[256];
    __shared__ float hid[64];
    __shared__ float o10[NCLS];
    int g = blockIdx.x, t = threadIdx.x;
    for (int i = t; i < 256; i += 64) {
        float m = -INFINITY;
        #pragma unroll
        for (int c = 0; c < PCHUNK; ++c)
            m = fmaxf(m, part[((size_t)g * PCHUNK + c) * 256 + i]);
        gr[i] = m;
    }
    __syncthreads();
    float s = fc1b[t];
    for (int k = 0; k < 256; ++k) s += gr[k] * fc1w[k * 64 + t];
    hid[t] = s > 0.f ? s : 0.f;
    __syncthreads();
    if (t < NCLS) {
        float s2 = fc2b[t];
        for (int k = 0; k < 64; ++k) s2 += hid[k] * fc2w[k * NCLS + t];
        o10[t] = s2;
    }
    __syncthreads();
    if (t == 0) {
        float mx = -INFINITY;
        for (int c = 0; c < NCLS; ++c) mx = fmaxf(mx, o10[c]);
        float se = 0.f;
        for (int c = 0; c < NCLS; ++c) se += __expf(o10[c] - mx);
        float lse = mx + logf(se);
        for (int c = 0; c < NCLS; ++c) out[g * NCLS + c] = o10[c] - lse;
    }
}

extern "C" void kernel_launch(void* const* d_in, const int* in_sizes, int n_in,
                              void* d_out, int out_size, void* d_ws, size_t ws_size,
                              hipStream_t stream) {
    (void)n_in; (void)out_size; (void)ws_size;
    const float* x        = (const float*)d_in[0];
    const int*   ei       = (const int*)d_in[1];
    const int*   batch    = (const int*)d_in[2];
    const float* W1       = (const float*)d_in[3];
    const float* att_src1 = (const float*)d_in[4];
    const float* att_dst1 = (const float*)d_in[5];
    const float* b1       = (const float*)d_in[6];
    const float* W2       = (const float*)d_in[7];
    const float* att_src2 = (const float*)d_in[8];
    const float* att_dst2 = (const float*)d_in[9];
    const float* b2       = (const float*)d_in[10];
    const float* fc1w     = (const float*)d_in[11];
    const float* fc1b     = (const float*)d_in[12];
    const float* fc2w     = (const float*)d_in[13];
    const float* fc2b     = (const float*)d_in[14];

    const int N = in_sizes[2];
    const int E = in_sizes[1] / 2;
    const int tot = 2 * E;

    char* base = (char*)d_ws;
    size_t off = 0;
    auto alloc = [&](size_t bytes) -> void* {
        void* p = base + off;
        off = (off + bytes + 255) & ~(size_t)255;
        return p;
    };
    int*   ofs    = (int*)alloc((size_t)(N + 1) * 4);
    int*   cursor = (int*)alloc((size_t)N * 4);
    int*   esrc   = (int*)alloc((size_t)tot * 4);
    int*   edst   = (int*)alloc((size_t)tot * 4);
    float* as1    = (float*)alloc((size_t)N * HEADS * 4);
    float* ad1    = (float*)alloc((size_t)N * HEADS * 4);
    float* as2    = (float*)alloc((size_t)N * 4);
    float* ad2    = (float*)alloc((size_t)N * 4);
    float* wexp1  = (float*)alloc((size_t)tot * HEADS * 4);
    float* wexp2  = (float*)alloc((size_t)tot * 4);
    unsigned short* xb   = (unsigned short*)alloc((size_t)N * FDIM * 2);
    unsigned short* W1t  = (unsigned short*)alloc((size_t)512 * 128 * 2);
    unsigned short* W2t  = (unsigned short*)alloc((size_t)256 * 512 * 2);
    unsigned short* h1b  = (unsigned short*)alloc((size_t)N * 512 * 2);
    unsigned short* ho1b = (unsigned short*)alloc((size_t)N * 512 * 2);
    unsigned short* h2b  = (unsigned short*)alloc((size_t)N * 256 * 2);
    unsigned short* ho2b = (unsigned short*)alloc((size_t)N * 256 * 2);
    float* ppart  = (float*)alloc((size_t)NGRAPH * PCHUNK * 256 * 4);

    // CSR build
    hipMemsetAsync(cursor, 0, (size_t)N * 4, stream);
    hist_kernel<<<(tot + 255) / 256, 256, 0, stream>>>(ei, E, cursor);
    scan_kernel<<<1, 1024, 0, stream>>>(cursor, ofs, N);
    scatter_kernel<<<(tot + 255) / 256, 256, 0, stream>>>(ei, E, cursor, esrc, edst);

    // bf16 conversions
    cvt_kernel<<<(N * FDIM / 4 + 255) / 256, 256, 0, stream>>>(x, xb, N * FDIM / 4);
    tconv_kernel<<<dim3(512 / 32, 128 / 32), dim3(32, 8), 0, stream>>>(W1, W1t, 128, 512);
    tconv_kernel<<<dim3(256 / 32, 512 / 32), dim3(32, 8), 0, stream>>>(W2, W2t, 512, 256);

    // Layer 1: h1 = x @ W1  (M=N, N=512, K=128)
    bgemm_kernel<<<dim3(512 / 128, (N + 127) / 128), 256, 0, stream>>>(xb, W1t, h1b, N, 512, 128);
    att1_kernel<<<(N + 3) / 4, 256, 0, stream>>>(h1b, att_src1, att_dst1, as1, ad1, N);
    wcalc1_kernel<<<(tot + 255) / 256, 256, 0, stream>>>((const float4*)as1, (const float4*)ad1,
                                                         esrc, edst, (float4*)wexp1, tot);
    edge_agg1_kernel<<<(N + 1) / 2, 256, 0, stream>>>(h1b, (const float4*)as1, (const float4*)ad1,
                                                      ofs, esrc, wexp1, b1, ho1b, N);

    // Layer 2: h2 = ho1 @ W2  (M=N, N=256, K=512)
    bgemm_kernel<<<dim3(256 / 128, (N + 127) / 128), 256, 0, stream>>>(ho1b, W2t, h2b, N, 256, 512);
    att2_kernel<<<(N + 3) / 4, 256, 0, stream>>>(h2b, att_src2, att_dst2, as2, ad2, N);
    wcalc2_kernel<<<(tot + 255) / 256, 256, 0, stream>>>(as2, ad2, esrc, edst, wexp2, tot);
    edge_agg2_kernel<<<(N + 1) / 2, 256, 0, stream>>>(h2b, as2, ad2, ofs, esrc, wexp2, b2, ho2b, N);

    // Pool stage 1 + fused (pool stage 2 + head)
    pool1_kernel<<<dim3(NGRAPH, PCHUNK), 256, 0, stream>>>(ho2b, batch, N, ppart);
    head_kernel<<<NGRAPH, 64, 0, stream>>>(ppart, fc1w, fc1b, fc2w, fc2b, (float*)d_out);
}

// Round 9
// 292.146 us; speedup vs baseline: 1.3254x; 1.0700x over previous
//
#include <hip/hip_runtime.h>
#include <math.h>

// Problem constants (reference: N=20000, E=160000, F=128, H=4, C1=128, C2=256, G=64, NCLS=10)
#define FDIM 128
#define HEADS 4
#define C1DIM 128
#define C2DIM 256
#define NGRAPH 64
#define NCLS 10
#define PCHUNK 8

typedef __attribute__((ext_vector_type(8))) short short8;   // 8 bf16 (4 VGPRs)
typedef __attribute__((ext_vector_type(4))) float float4v;  // 4 fp32 acc

__device__ __forceinline__ unsigned short f2bf(float f) {
    unsigned u = __builtin_bit_cast(unsigned, f);
    unsigned r = (u + 0x7FFFu + ((u >> 16) & 1u)) >> 16;   // RNE
    return (unsigned short)r;
}
__device__ __forceinline__ float bflo(int u) { return __builtin_bit_cast(float, (unsigned)u << 16); }
__device__ __forceinline__ float bfhi(int u) { return __builtin_bit_cast(float, (unsigned)u & 0xffff0000u); }
__device__ __forceinline__ float bfu(unsigned short u) { return __builtin_bit_cast(float, (unsigned)u << 16); }
__device__ __forceinline__ float lrelu(float x) { return x > 0.f ? x : 0.2f * x; }
__device__ __forceinline__ float sel4(float a, float b, float c, float d, int hd) {
    return hd == 0 ? a : hd == 1 ? b : hd == 2 ? c : d;
}

// ---------------- CSR build ----------------
__global__ void hist_kernel(const int* __restrict__ ei, int E, int* __restrict__ counts) {
    int i = blockIdx.x * blockDim.x + threadIdx.x;
    if (i >= 2 * E) return;
    int dst = (i < E) ? ei[E + i] : ei[i - E];
    atomicAdd(&counts[dst], 1);
}

__global__ __launch_bounds__(1024) void scan_kernel(int* __restrict__ counts_cursor,
                                                    int* __restrict__ ofs, int N) {
    __shared__ int part[1024];
    int t = threadIdx.x;
    int chunk = (N + 1023) / 1024;
    int b = t * chunk;
    int e = b + chunk; if (e > N) e = N;
    int s = 0;
    for (int i = b; i < e; ++i) s += counts_cursor[i];
    part[t] = s;
    __syncthreads();
    for (int o = 1; o < 1024; o <<= 1) {
        int v = (t >= o) ? part[t - o] : 0;
        __syncthreads();
        part[t] += v;
        __syncthreads();
    }
    int run = part[t] - s;
    for (int i = b; i < e; ++i) {
        int c = counts_cursor[i];
        ofs[i] = run;
        counts_cursor[i] = run;
        run += c;
    }
    if (t == 1023) ofs[N] = part[1023];
}

__global__ void scatter_kernel(const int* __restrict__ ei, int E,
                               int* __restrict__ cursor, int* __restrict__ esrc) {
    int i = blockIdx.x * blockDim.x + threadIdx.x;
    if (i >= 2 * E) return;
    int src = ei[i];
    int dst = (i < E) ? ei[E + i] : ei[i - E];
    int pos = atomicAdd(&cursor[dst], 1);
    esrc[pos] = src;
}

// ---------------- fp32 -> bf16 conversions ----------------
__global__ void cvt_kernel(const float* __restrict__ src, unsigned short* __restrict__ dst, int n4) {
    int i = blockIdx.x * blockDim.x + threadIdx.x;
    if (i >= n4) return;
    float4 v = ((const float4*)src)[i];
    ushort4 o;
    o.x = f2bf(v.x); o.y = f2bf(v.y); o.z = f2bf(v.z); o.w = f2bf(v.w);
    ((ushort4*)dst)[i] = o;
}

// Transpose-convert weights: W[K,N] fp32 -> Wt[N,K] bf16. Grid (N/32, K/32), block (32,8).
__global__ void tconv_kernel(const float* __restrict__ W, unsigned short* __restrict__ Wt,
                             int K, int N_) {
    __shared__ float tile[32][33];
    int bx = blockIdx.x * 32;
    int by = blockIdx.y * 32;
    int tx = threadIdx.x, ty = threadIdx.y;
    #pragma unroll
    for (int r = 0; r < 32; r += 8)
        tile[ty + r][tx] = W[(size_t)(by + ty + r) * N_ + bx + tx];
    __syncthreads();
    #pragma unroll
    for (int r = 0; r < 32; r += 8)
        Wt[(size_t)(bx + ty + r) * K + by + tx] = f2bf(tile[tx][ty + r]);
}

// ---------------- bf16 MFMA GEMM with fused attention-score epilogue ----------------
// C[M,N] = A[M,K] @ Bt[N,K]^T, bf16 out.
// MODE 1: one col-tile == one head (N_=512): write as/ad[r*4+blockIdx.x] directly.
// MODE 2: att spans both col-tiles (N_=256): atomicAdd partials into as/ad[r] (pre-zeroed).
template<int MODE>
__global__ __launch_bounds__(256) void bgemm_kernel(
        const unsigned short* __restrict__ A,   // [M,K] bf16
        const unsigned short* __restrict__ Bt,  // [N,K] bf16
        unsigned short* __restrict__ C,         // [M,N] bf16
        const float* __restrict__ att_src,      // [N_] fp32
        const float* __restrict__ att_dst,      // [N_] fp32
        float* __restrict__ as_out,
        float* __restrict__ ad_out,
        int M, int N_, int K) {
    __shared__ unsigned short As[128 * 32];
    __shared__ unsigned short Bs[128 * 32];
    __shared__ float sd_s[4][64];
    __shared__ float sd_d[4][64];
    const int t = threadIdx.x;
    const int lane = t & 63;
    const int wave = t >> 6;
    const int row0 = blockIdx.y * 128, col0 = blockIdx.x * 128;
    const int wr = (wave >> 1) * 64, wc = (wave & 1) * 64;
    float4v acc[4][4] = {};
    for (int k0 = 0; k0 < K; k0 += 32) {
        #pragma unroll
        for (int c = 0; c < 2; ++c) {
            int i = c * 256 + t;
            int gr = row0 + (i >> 2); if (gr >= M) gr = M - 1;
            const unsigned short* gp = A + (size_t)gr * K + k0 + ((i & 3) << 3);
            __builtin_amdgcn_global_load_lds(
                (const __attribute__((address_space(1))) unsigned int*)gp,
                (__attribute__((address_space(3))) unsigned int*)&As[i * 8], 16, 0, 0);
        }
        #pragma unroll
        for (int c = 0; c < 2; ++c) {
            int i = c * 256 + t;
            int gn = col0 + (i >> 2);
            const unsigned short* gp = Bt + (size_t)gn * K + k0 + ((i & 3) << 3);
            __builtin_amdgcn_global_load_lds(
                (const __attribute__((address_space(1))) unsigned int*)gp,
                (__attribute__((address_space(3))) unsigned int*)&Bs[i * 8], 16, 0, 0);
        }
        __syncthreads();
        short8 af[4], bfr[4];
        #pragma unroll
        for (int i = 0; i < 4; ++i)
            af[i] = *(const short8*)&As[(wr + i * 16 + (lane & 15)) * 32 + (lane >> 4) * 8];
        #pragma unroll
        for (int j = 0; j < 4; ++j)
            bfr[j] = *(const short8*)&Bs[(wc + j * 16 + (lane & 15)) * 32 + (lane >> 4) * 8];
        #pragma unroll
        for (int i = 0; i < 4; ++i)
            #pragma unroll
            for (int j = 0; j < 4; ++j)
                acc[i][j] = __builtin_amdgcn_mfma_f32_16x16x32_bf16(af[i], bfr[j], acc[i][j], 0, 0, 0);
        __syncthreads();
    }
    // C write (bf16)
    #pragma unroll
    for (int i = 0; i < 4; ++i) {
        int rbase = row0 + wr + i * 16 + (lane >> 4) * 4;
        #pragma unroll
        for (int j = 0; j < 4; ++j) {
            int cc = col0 + wc + j * 16 + (lane & 15);
            #pragma unroll
            for (int p = 0; p < 4; ++p) {
                int r = rbase + p;
                if (r < M) C[(size_t)r * N_ + cc] = f2bf(acc[i][j][p]);
            }
        }
    }
    // attention-score epilogue: rowdot over this block's 128 cols
    float asv[4], adv[4];
    #pragma unroll
    for (int j = 0; j < 4; ++j) {
        int cc = col0 + wc + j * 16 + (lane & 15);
        asv[j] = att_src[cc];
        adv[j] = att_dst[cc];
    }
    #pragma unroll
    for (int i = 0; i < 4; ++i) {
        #pragma unroll
        for (int p = 0; p < 4; ++p) {
            float s = acc[i][0][p] * asv[0] + acc[i][1][p] * asv[1]
                    + acc[i][2][p] * asv[2] + acc[i][3][p] * asv[3];
            float d = acc[i][0][p] * adv[0] + acc[i][1][p] * adv[1]
                    + acc[i][2][p] * adv[2] + acc[i][3][p] * adv[3];
            #pragma unroll
            for (int o = 1; o <= 8; o <<= 1) { s += __shfl_xor(s, o); d += __shfl_xor(d, o); }
            if ((lane & 15) == 0) {
                int ridx = i * 16 + (lane >> 4) * 4 + p;
                sd_s[wave][ridx] = s;
                sd_d[wave][ridx] = d;
            }
        }
    }
    __syncthreads();
    if ((wave & 1) == 0) {   // wc==0 waves combine the two col-half partials
        float s = sd_s[wave][lane] + sd_s[wave + 1][lane];
        float d = sd_d[wave][lane] + sd_d[wave + 1][lane];
        int r = row0 + wr + lane;
        if (r < M) {
            if (MODE == 1) {
                as_out[r * 4 + blockIdx.x] = s;
                ad_out[r * 4 + blockIdx.x] = d;
            } else {
                atomicAdd(&as_out[r], s);
                atomicAdd(&ad_out[r], d);
            }
        }
    }
}

// ---------------- edge aggregate (R5 shape + in-chunk weight compute, shfl handoff) ----
// Layer 1: one wave per node; lane = 8 ch of 512; head = lane>>4. Per chunk of 64 edges,
// lane computes the edge's 4-head exp-weight once (16B as14 gather); serial loop gets
// (src, w) via __shfl — no wcalc kernel, no wexp array, no LDS, no barriers.
__global__ __launch_bounds__(256) void edge_agg1_kernel(
        const unsigned short* __restrict__ h1b,   // [N,512] bf16
        const float4* __restrict__ as14,
        const float4* __restrict__ ad14,
        const int* __restrict__ ofs,
        const int* __restrict__ esrc,
        const float* __restrict__ b1,
        unsigned short* __restrict__ ho1b, int N) {
    int wave = threadIdx.x >> 6, lane = threadIdx.x & 63;
    int node = blockIdx.x * 4 + wave;
    if (node >= N) return;
    int beg = ofs[node], end = ofs[node + 1];
    float4 asn = as14[node], adn = ad14[node];
    float w0 = __expf(lrelu(asn.x + adn.x));
    float w1 = __expf(lrelu(asn.y + adn.y));
    float w2 = __expf(lrelu(asn.z + adn.z));
    float w3 = __expf(lrelu(asn.w + adn.w));
    int hd = lane >> 4;
    int c0 = lane * 8;
    float wsh = sel4(w0, w1, w2, w3, hd);
    float acc[8];
    {
        int4 r = *(const int4*)&h1b[(size_t)node * 512 + c0];
        acc[0] = wsh * bflo(r.x); acc[1] = wsh * bfhi(r.x);
        acc[2] = wsh * bflo(r.y); acc[3] = wsh * bfhi(r.y);
        acc[4] = wsh * bflo(r.z); acc[5] = wsh * bfhi(r.z);
        acc[6] = wsh * bflo(r.w); acc[7] = wsh * bfhi(r.w);
    }
    float d0 = 0.f, d1 = 0.f, d2 = 0.f, d3 = 0.f;
    for (int cb = beg; cb < end; cb += 64) {
        int idx = cb + lane;
        int sl = esrc[idx < end ? idx : end - 1];
        float4 wl = make_float4(0.f, 0.f, 0.f, 0.f);
        if (idx < end) {
            float4 a = as14[sl];
            wl.x = __expf(lrelu(a.x + adn.x));
            wl.y = __expf(lrelu(a.y + adn.y));
            wl.z = __expf(lrelu(a.z + adn.z));
            wl.w = __expf(lrelu(a.w + adn.w));
            d0 += wl.x; d1 += wl.y; d2 += wl.z; d3 += wl.w;
        }
        int jmax = end - cb; if (jmax > 64) jmax = 64;
        int j = 0;
        for (; j + 4 <= jmax; j += 4) {
            int s0 = __shfl(sl, j), s1 = __shfl(sl, j + 1);
            int s2 = __shfl(sl, j + 2), s3 = __shfl(sl, j + 3);
            float u0 = sel4(__shfl(wl.x, j), __shfl(wl.y, j), __shfl(wl.z, j), __shfl(wl.w, j), hd);
            float u1 = sel4(__shfl(wl.x, j + 1), __shfl(wl.y, j + 1), __shfl(wl.z, j + 1), __shfl(wl.w, j + 1), hd);
            float u2 = sel4(__shfl(wl.x, j + 2), __shfl(wl.y, j + 2), __shfl(wl.z, j + 2), __shfl(wl.w, j + 2), hd);
            float u3 = sel4(__shfl(wl.x, j + 3), __shfl(wl.y, j + 3), __shfl(wl.z, j + 3), __shfl(wl.w, j + 3), hd);
            int4 r0 = *(const int4*)&h1b[(size_t)s0 * 512 + c0];
            int4 r1 = *(const int4*)&h1b[(size_t)s1 * 512 + c0];
            int4 r2 = *(const int4*)&h1b[(size_t)s2 * 512 + c0];
            int4 r3 = *(const int4*)&h1b[(size_t)s3 * 512 + c0];
            acc[0] += u0 * bflo(r0.x); acc[1] += u0 * bfhi(r0.x);
            acc[2] += u0 * bflo(r0.y); acc[3] += u0 * bfhi(r0.y);
            acc[4] += u0 * bflo(r0.z); acc[5] += u0 * bfhi(r0.z);
            acc[6] += u0 * bflo(r0.w); acc[7] += u0 * bfhi(r0.w);
            acc[0] += u1 * bflo(r1.x); acc[1] += u1 * bfhi(r1.x);
            acc[2] += u1 * bflo(r1.y); acc[3] += u1 * bfhi(r1.y);
            acc[4] += u1 * bflo(r1.z); acc[5] += u1 * bfhi(r1.z);
            acc[6] += u1 * bflo(r1.w); acc[7] += u1 * bfhi(r1.w);
            acc[0] += u2 * bflo(r2.x); acc[1] += u2 * bfhi(r2.x);
            acc[2] += u2 * bflo(r2.y); acc[3] += u2 * bfhi(r2.y);
            acc[4] += u2 * bflo(r2.z); acc[5] += u2 * bfhi(r2.z);
            acc[6] += u2 * bflo(r2.w); acc[7] += u2 * bfhi(r2.w);
            acc[0] += u3 * bflo(r3.x); acc[1] += u3 * bfhi(r3.x);
            acc[2] += u3 * bflo(r3.y); acc[3] += u3 * bfhi(r3.y);
            acc[4] += u3 * bflo(r3.z); acc[5] += u3 * bfhi(r3.z);
            acc[6] += u3 * bflo(r3.w); acc[7] += u3 * bfhi(r3.w);
        }
        for (; j < jmax; ++j) {
            int s = __shfl(sl, j);
            float u = sel4(__shfl(wl.x, j), __shfl(wl.y, j), __shfl(wl.z, j), __shfl(wl.w, j), hd);
            int4 r = *(const int4*)&h1b[(size_t)s * 512 + c0];
            acc[0] += u * bflo(r.x); acc[1] += u * bfhi(r.x);
            acc[2] += u * bflo(r.y); acc[3] += u * bfhi(r.y);
            acc[4] += u * bflo(r.z); acc[5] += u * bfhi(r.z);
            acc[6] += u * bflo(r.w); acc[7] += u * bfhi(r.w);
        }
    }
    #pragma unroll
    for (int o = 32; o > 0; o >>= 1) {
        d0 += __shfl_xor(d0, o); d1 += __shfl_xor(d1, o);
        d2 += __shfl_xor(d2, o); d3 += __shfl_xor(d3, o);
    }
    d0 += w0; d1 += w1; d2 += w2; d3 += w3;
    float dh = sel4(d0, d1, d2, d3, hd);
    float inv = 1.f / dh;
    float4 bA = *(const float4*)&b1[c0], bB = *(const float4*)&b1[c0 + 4];
    float v0 = fmaxf(acc[0] * inv + bA.x, 0.f), v1 = fmaxf(acc[1] * inv + bA.y, 0.f);
    float v2 = fmaxf(acc[2] * inv + bA.z, 0.f), v3 = fmaxf(acc[3] * inv + bA.w, 0.f);
    float v4 = fmaxf(acc[4] * inv + bB.x, 0.f), v5 = fmaxf(acc[5] * inv + bB.y, 0.f);
    float v6 = fmaxf(acc[6] * inv + bB.z, 0.f), v7 = fmaxf(acc[7] * inv + bB.w, 0.f);
    int4 o;
    o.x = (int)((unsigned)f2bf(v0) | ((unsigned)f2bf(v1) << 16));
    o.y = (int)((unsigned)f2bf(v2) | ((unsigned)f2bf(v3) << 16));
    o.z = (int)((unsigned)f2bf(v4) | ((unsigned)f2bf(v5) << 16));
    o.w = (int)((unsigned)f2bf(v6) | ((unsigned)f2bf(v7) << 16));
    *(int4*)&ho1b[(size_t)node * 512 + c0] = o;
}

// Layer 2: one wave per node; lane = 4 ch of 256 (int2 gathers); scalar weight via shfl.
__global__ __launch_bounds__(256) void edge_agg2_kernel(
        const unsigned short* __restrict__ h2b,   // [N,256] bf16
        const float* __restrict__ as2,
        const float* __restrict__ ad2,
        const int* __restrict__ ofs,
        const int* __restrict__ esrc,
        const float* __restrict__ b2,
        unsigned short* __restrict__ ho2b, int N) {
    int wave = threadIdx.x >> 6, lane = threadIdx.x & 63;
    int node = blockIdx.x * 4 + wave;
    if (node >= N) return;
    int beg = ofs[node], end = ofs[node + 1];
    float adn = ad2[node];
    float wself = __expf(lrelu(as2[node] + adn));
    int c0 = lane * 4;
    float a0, a1, a2, a3;
    {
        int2 r = *(const int2*)&h2b[(size_t)node * 256 + c0];
        a0 = wself * bflo(r.x); a1 = wself * bfhi(r.x);
        a2 = wself * bflo(r.y); a3 = wself * bfhi(r.y);
    }
    float dsum = 0.f;
    for (int cb = beg; cb < end; cb += 64) {
        int idx = cb + lane;
        int sl = esrc[idx < end ? idx : end - 1];
        float wl = 0.f;
        if (idx < end) {
            wl = __expf(lrelu(as2[sl] + adn));
            dsum += wl;
        }
        int jmax = end - cb; if (jmax > 64) jmax = 64;
        int j = 0;
        for (; j + 4 <= jmax; j += 4) {
            int s0 = __shfl(sl, j), s1 = __shfl(sl, j + 1);
            int s2 = __shfl(sl, j + 2), s3 = __shfl(sl, j + 3);
            float u0 = __shfl(wl, j), u1 = __shfl(wl, j + 1);
            float u2 = __shfl(wl, j + 2), u3 = __shfl(wl, j + 3);
            int2 r0 = *(const int2*)&h2b[(size_t)s0 * 256 + c0];
            int2 r1 = *(const int2*)&h2b[(size_t)s1 * 256 + c0];
            int2 r2 = *(const int2*)&h2b[(size_t)s2 * 256 + c0];
            int2 r3 = *(const int2*)&h2b[(size_t)s3 * 256 + c0];
            a0 += u0 * bflo(r0.x); a1 += u0 * bfhi(r0.x);
            a2 += u0 * bflo(r0.y); a3 += u0 * bfhi(r0.y);
            a0 += u1 * bflo(r1.x); a1 += u1 * bfhi(r1.x);
            a2 += u1 * bflo(r1.y); a3 += u1 * bfhi(r1.y);
            a0 += u2 * bflo(r2.x); a1 += u2 * bfhi(r2.x);
            a2 += u2 * bflo(r2.y); a3 += u2 * bfhi(r2.y);
            a0 += u3 * bflo(r3.x); a1 += u3 * bfhi(r3.x);
            a2 += u3 * bflo(r3.y); a3 += u3 * bfhi(r3.y);
        }
        for (; j < jmax; ++j) {
            int s = __shfl(sl, j);
            float u = __shfl(wl, j);
            int2 r = *(const int2*)&h2b[(size_t)s * 256 + c0];
            a0 += u * bflo(r.x); a1 += u * bfhi(r.x);
            a2 += u * bflo(r.y); a3 += u * bfhi(r.y);
        }
    }
    #pragma unroll
    for (int o = 32; o > 0; o >>= 1) dsum += __shfl_xor(dsum, o);
    dsum += wself;
    float inv = 1.f / dsum;
    float4 bv = *(const float4*)&b2[c0];
    float v0 = a0 * inv + bv.x, v1 = a1 * inv + bv.y;
    float v2 = a2 * inv + bv.z, v3 = a3 * inv + bv.w;
    int2 o;
    o.x = (int)((unsigned)f2bf(v0) | ((unsigned)f2bf(v1) << 16));
    o.y = (int)((unsigned)f2bf(v2) | ((unsigned)f2bf(v3) << 16));
    *(int2*)&ho2b[(size_t)node * 256 + c0] = o;
}

// ---------------- global max pool, stage 1 (batch is sorted; bf16 input) ----------------
__global__ __launch_bounds__(256) void pool1_kernel(const unsigned short* __restrict__ ho2b,
                                                    const int* __restrict__ batch,
                                                    int N, float* __restrict__ part) {
    int g = blockIdx.x, c = blockIdx.y, t = threadIdx.x;
    int lo = 0, hi = N;
    while (lo < hi) { int mid = (lo + hi) >> 1; if (batch[mid] < g) lo = mid + 1; else hi = mid; }
    int start = lo;
    lo = 0; hi = N;
    while (lo < hi) { int mid = (lo + hi) >> 1; if (batch[mid] < g + 1) lo = mid + 1; else hi = mid; }
    int end = lo;
    int len = end - start;
    int cb = start + (int)(((long long)len * c) / PCHUNK);
    int ce = start + (int)(((long long)len * (c + 1)) / PCHUNK);
    float m = -INFINITY;
    for (int n = cb; n < ce; ++n) m = fmaxf(m, bfu(ho2b[(size_t)n * 256 + t]));
    part[((size_t)g * PCHUNK + c) * 256 + t] = m;
}

// ---------------- FC head (+pool stage 2) + log_softmax ----------------
__global__ __launch_bounds__(64) void head_kernel(const float* __restrict__ part,
                                                  const float* __restrict__ fc1w,
                                                  const float* __restrict__ fc1b,
                                                  const float* __restrict__ fc2w,
                                                  const float* __restrict__ fc2b,
                                                  float* __restrict__ out) {
    __shared__ float gr[256];
    __shared__ float hid[64];
    __shared__ float o10[NCLS];
    int g = blockIdx.x, t = threadIdx.x;
    for (int i = t; i < 256; i += 64) {
        float m = -INFINITY;
        #pragma unroll
        for (int c = 0; c < PCHUNK; ++c)
            m = fmaxf(m, part[((size_t)g * PCHUNK + c) * 256 + i]);
        gr[i] = m;
    }
    __syncthreads();
    float s = fc1b[t];
    for (int k = 0; k < 256; ++k) s += gr[k] * fc1w[k * 64 + t];
    hid[t] = s > 0.f ? s : 0.f;
    __syncthreads();
    if (t < NCLS) {
        float s2 = fc2b[t];
        for (int k = 0; k < 64; ++k) s2 += hid[k] * fc2w[k * NCLS + t];
        o10[t] = s2;
    }
    __syncthreads();
    if (t == 0) {
        float mx = -INFINITY;
        for (int c = 0; c < NCLS; ++c) mx = fmaxf(mx, o10[c]);
        float se = 0.f;
        for (int c = 0; c < NCLS; ++c) se += __expf(o10[c] - mx);
        float lse = mx + logf(se);
        for (int c = 0; c < NCLS; ++c) out[g * NCLS + c] = o10[c] - lse;
    }
}

extern "C" void kernel_launch(void* const* d_in, const int* in_sizes, int n_in,
                              void* d_out, int out_size, void* d_ws, size_t ws_size,
                              hipStream_t stream) {
    (void)n_in; (void)out_size; (void)ws_size;
    const float* x        = (const float*)d_in[0];
    const int*   ei       = (const int*)d_in[1];
    const int*   batch    = (const int*)d_in[2];
    const float* W1       = (const float*)d_in[3];
    const float* att_src1 = (const float*)d_in[4];
    const float* att_dst1 = (const float*)d_in[5];
    const float* b1       = (const float*)d_in[6];
    const float* W2       = (const float*)d_in[7];
    const float* att_src2 = (const float*)d_in[8];
    const float* att_dst2 = (const float*)d_in[9];
    const float* b2       = (const float*)d_in[10];
    const float* fc1w     = (const float*)d_in[11];
    const float* fc1b     = (const float*)d_in[12];
    const float* fc2w     = (const float*)d_in[13];
    const float* fc2b     = (const float*)d_in[14];

    const int N = in_sizes[2];
    const int E = in_sizes[1] / 2;
    const int tot = 2 * E;

    char* base = (char*)d_ws;
    size_t off = 0;
    auto alloc = [&](size_t bytes) -> void* {
        void* p = base + off;
        off = (off + bytes + 255) & ~(size_t)255;
        return p;
    };
    int*   ofs    = (int*)alloc((size_t)(N + 1) * 4);
    int*   cursor = (int*)alloc((size_t)N * 4);    // cursor, as2, ad2 zeroed by one memset
    float* as2    = (float*)alloc((size_t)N * 4);
    float* ad2    = (float*)alloc((size_t)N * 4);
    int*   esrc   = (int*)alloc((size_t)tot * 4);
    float* as1    = (float*)alloc((size_t)N * HEADS * 4);
    float* ad1    = (float*)alloc((size_t)N * HEADS * 4);
    unsigned short* xb   = (unsigned short*)alloc((size_t)N * FDIM * 2);
    unsigned short* W1t  = (unsigned short*)alloc((size_t)512 * 128 * 2);
    unsigned short* W2t  = (unsigned short*)alloc((size_t)256 * 512 * 2);
    unsigned short* h1b  = (unsigned short*)alloc((size_t)N * 512 * 2);
    unsigned short* ho1b = (unsigned short*)alloc((size_t)N * 512 * 2);
    unsigned short* h2b  = (unsigned short*)alloc((size_t)N * 256 * 2);
    unsigned short* ho2b = (unsigned short*)alloc((size_t)N * 256 * 2);
    float* ppart  = (float*)alloc((size_t)NGRAPH * PCHUNK * 256 * 4);

    // one memset covers cursor + as2 + ad2 (contiguous allocations)
    size_t zbytes = (size_t)((char*)ad2 - (char*)cursor) + (size_t)N * 4;
    hipMemsetAsync(cursor, 0, zbytes, stream);

    // CSR build
    hist_kernel<<<(tot + 255) / 256, 256, 0, stream>>>(ei, E, cursor);
    scan_kernel<<<1, 1024, 0, stream>>>(cursor, ofs, N);
    scatter_kernel<<<(tot + 255) / 256, 256, 0, stream>>>(ei, E, cursor, esrc);

    // bf16 conversions
    cvt_kernel<<<(N * FDIM / 4 + 255) / 256, 256, 0, stream>>>(x, xb, N * FDIM / 4);
    tconv_kernel<<<dim3(512 / 32, 128 / 32), dim3(32, 8), 0, stream>>>(W1, W1t, 128, 512);
    tconv_kernel<<<dim3(256 / 32, 512 / 32), dim3(32, 8), 0, stream>>>(W2, W2t, 512, 256);

    // Layer 1: h1 = x @ W1 (M=N, N=512, K=128); att1 fused into epilogue
    bgemm_kernel<1><<<dim3(512 / 128, (N + 127) / 128), 256, 0, stream>>>(
        xb, W1t, h1b, att_src1, att_dst1, as1, ad1, N, 512, 128);
    edge_agg1_kernel<<<(N + 3) / 4, 256, 0, stream>>>(h1b, (const float4*)as1, (const float4*)ad1,
                                                      ofs, esrc, b1, ho1b, N);

    // Layer 2: h2 = ho1 @ W2 (M=N, N=256, K=512); att2 fused (atomic partials)
    bgemm_kernel<2><<<dim3(256 / 128, (N + 127) / 128), 256, 0, stream>>>(
        ho1b, W2t, h2b, att_src2, att_dst2, as2, ad2, N, 256, 512);
    edge_agg2_kernel<<<(N + 3) / 4, 256, 0, stream>>>(h2b, as2, ad2, ofs, esrc, b2, ho2b, N);

    // Pool stage 1 + fused (pool stage 2 + head)
    pool1_kernel<<<dim3(NGRAPH, PCHUNK), 256, 0, stream>>>(ho2b, batch, N, ppart);
    head_kernel<<<NGRAPH, 64, 0, stream>>>(ppart, fc1w, fc1b, fc2w, fc2b, (float*)d_out);
}

// Round 10
// 287.560 us; speedup vs baseline: 1.3465x; 1.0160x over previous
//
#include <hip/hip_runtime.h>
#include <math.h>

// Problem constants (reference: N=20000, E=160000, F=128, H=4, C1=128, C2=256, G=64, NCLS=10)
#define FDIM 128
#define HEADS 4
#define C1DIM 128
#define C2DIM 256
#define NGRAPH 64
#define NCLS 10
#define PCHUNK 8

typedef __attribute__((ext_vector_type(8))) short short8;   // 8 bf16 (4 VGPRs)
typedef __attribute__((ext_vector_type(4))) float float4v;  // 4 fp32 acc

__device__ __forceinline__ unsigned short f2bf(float f) {
    unsigned u = __builtin_bit_cast(unsigned, f);
    unsigned r = (u + 0x7FFFu + ((u >> 16) & 1u)) >> 16;   // RNE
    return (unsigned short)r;
}
__device__ __forceinline__ float bflo(int u) { return __builtin_bit_cast(float, (unsigned)u << 16); }
__device__ __forceinline__ float bfhi(int u) { return __builtin_bit_cast(float, (unsigned)u & 0xffff0000u); }
__device__ __forceinline__ float bfu(unsigned short u) { return __builtin_bit_cast(float, (unsigned)u << 16); }
__device__ __forceinline__ float lrelu(float x) { return x > 0.f ? x : 0.2f * x; }
__device__ __forceinline__ float sel4(float a, float b, float c, float d, int hd) {
    return hd == 0 ? a : hd == 1 ? b : hd == 2 ? c : d;
}

// ---------------- CSR build ----------------
__global__ void hist_kernel(const int* __restrict__ ei, int E, int* __restrict__ counts) {
    int i = blockIdx.x * blockDim.x + threadIdx.x;
    if (i >= 2 * E) return;
    int dst = (i < E) ? ei[E + i] : ei[i - E];
    atomicAdd(&counts[dst], 1);
}

__global__ __launch_bounds__(1024) void scan_kernel(int* __restrict__ counts_cursor,
                                                    int* __restrict__ ofs, int N) {
    __shared__ int part[1024];
    int t = threadIdx.x;
    int chunk = (N + 1023) / 1024;
    int b = t * chunk;
    int e = b + chunk; if (e > N) e = N;
    int s = 0;
    for (int i = b; i < e; ++i) s += counts_cursor[i];
    part[t] = s;
    __syncthreads();
    for (int o = 1; o < 1024; o <<= 1) {
        int v = (t >= o) ? part[t - o] : 0;
        __syncthreads();
        part[t] += v;
        __syncthreads();
    }
    int run = part[t] - s;
    for (int i = b; i < e; ++i) {
        int c = counts_cursor[i];
        ofs[i] = run;
        counts_cursor[i] = run;
        run += c;
    }
    if (t == 1023) ofs[N] = part[1023];
}

__global__ void scatter_kernel(const int* __restrict__ ei, int E,
                               int* __restrict__ cursor, int* __restrict__ esrc) {
    int i = blockIdx.x * blockDim.x + threadIdx.x;
    if (i >= 2 * E) return;
    int src = ei[i];
    int dst = (i < E) ? ei[E + i] : ei[i - E];
    int pos = atomicAdd(&cursor[dst], 1);
    esrc[pos] = src;
}

// ---------------- fp32 -> bf16 conversions ----------------
__global__ void cvt_kernel(const float* __restrict__ src, unsigned short* __restrict__ dst, int n4) {
    int i = blockIdx.x * blockDim.x + threadIdx.x;
    if (i >= n4) return;
    float4 v = ((const float4*)src)[i];
    ushort4 o;
    o.x = f2bf(v.x); o.y = f2bf(v.y); o.z = f2bf(v.z); o.w = f2bf(v.w);
    ((ushort4*)dst)[i] = o;
}

// Transpose-convert weights: W[K,N] fp32 -> Wt[N,K] bf16. Grid (N/32, K/32), block (32,8).
__global__ void tconv_kernel(const float* __restrict__ W, unsigned short* __restrict__ Wt,
                             int K, int N_) {
    __shared__ float tile[32][33];
    int bx = blockIdx.x * 32;
    int by = blockIdx.y * 32;
    int tx = threadIdx.x, ty = threadIdx.y;
    #pragma unroll
    for (int r = 0; r < 32; r += 8)
        tile[ty + r][tx] = W[(size_t)(by + ty + r) * N_ + bx + tx];
    __syncthreads();
    #pragma unroll
    for (int r = 0; r < 32; r += 8)
        Wt[(size_t)(bx + ty + r) * K + by + tx] = f2bf(tile[tx][ty + r]);
}

// ---------------- bf16 MFMA GEMM (64x128 tile) + fused attention epilogue ----------------
// C[M,N] = A[M,K] @ Bt[N,K]^T, bf16 out via LDS-repacked coalesced int4 stores.
// 64-row tiles: 2-5x more blocks than 128-row -> enough resident waves to hide the
// K-loop barrier drain (bgemm2 was 314 blocks = ~1.2 waves/SIMD).
// MODE 1: one col-tile == one head (N_=512): as/ad[r*4+blockIdx.x] direct.
// MODE 2: att spans both col-tiles (N_=256): atomicAdd partials (pre-zeroed).
template<int MODE>
__global__ __launch_bounds__(256) void bgemm_kernel(
        const unsigned short* __restrict__ A,   // [M,K] bf16
        const unsigned short* __restrict__ Bt,  // [N,K] bf16
        unsigned short* __restrict__ C,         // [M,N] bf16
        const float* __restrict__ att_src,      // [N_] fp32
        const float* __restrict__ att_dst,      // [N_] fp32
        float* __restrict__ as_out,
        float* __restrict__ ad_out,
        int M, int N_, int K) {
    __shared__ unsigned short As[64 * 32];       // 4 KB
    __shared__ unsigned short Bs[128 * 32];      // 8 KB
    __shared__ unsigned short Cs[64 * 136];      // 17 KB, +8 pad (rows shift 4 banks)
    __shared__ float sd_s[4][32];
    __shared__ float sd_d[4][32];
    const int t = threadIdx.x;
    const int lane = t & 63;
    const int wave = t >> 6;
    const int row0 = blockIdx.y * 64, col0 = blockIdx.x * 128;
    const int wr = (wave >> 1) * 32, wc = (wave & 1) * 64;
    float4v acc[2][4] = {};
    for (int k0 = 0; k0 < K; k0 += 32) {
        {
            int i = t;                          // 256 x 16B = 4 KB A-tile
            int gr = row0 + (i >> 2); if (gr >= M) gr = M - 1;
            const unsigned short* gp = A + (size_t)gr * K + k0 + ((i & 3) << 3);
            __builtin_amdgcn_global_load_lds(
                (const __attribute__((address_space(1))) unsigned int*)gp,
                (__attribute__((address_space(3))) unsigned int*)&As[i * 8], 16, 0, 0);
        }
        #pragma unroll
        for (int c = 0; c < 2; ++c) {
            int i = c * 256 + t;
            int gn = col0 + (i >> 2);
            const unsigned short* gp = Bt + (size_t)gn * K + k0 + ((i & 3) << 3);
            __builtin_amdgcn_global_load_lds(
                (const __attribute__((address_space(1))) unsigned int*)gp,
                (__attribute__((address_space(3))) unsigned int*)&Bs[i * 8], 16, 0, 0);
        }
        __syncthreads();
        short8 af[2], bfr[4];
        #pragma unroll
        for (int i = 0; i < 2; ++i)
            af[i] = *(const short8*)&As[(wr + i * 16 + (lane & 15)) * 32 + (lane >> 4) * 8];
        #pragma unroll
        for (int j = 0; j < 4; ++j)
            bfr[j] = *(const short8*)&Bs[(wc + j * 16 + (lane & 15)) * 32 + (lane >> 4) * 8];
        #pragma unroll
        for (int i = 0; i < 2; ++i)
            #pragma unroll
            for (int j = 0; j < 4; ++j)
                acc[i][j] = __builtin_amdgcn_mfma_f32_16x16x32_bf16(af[i], bfr[j], acc[i][j], 0, 0, 0);
        __syncthreads();
    }
    // stage C into LDS (bf16) + attention row-dots
    float asv[4], adv[4];
    #pragma unroll
    for (int j = 0; j < 4; ++j) {
        int cc = col0 + wc + j * 16 + (lane & 15);
        asv[j] = att_src[cc];
        adv[j] = att_dst[cc];
    }
    #pragma unroll
    for (int i = 0; i < 2; ++i) {
        #pragma unroll
        for (int p = 0; p < 4; ++p) {
            int rr = wr + i * 16 + (lane >> 4) * 4 + p;
            #pragma unroll
            for (int j = 0; j < 4; ++j)
                Cs[rr * 136 + wc + j * 16 + (lane & 15)] = f2bf(acc[i][j][p]);
            float s = acc[i][0][p] * asv[0] + acc[i][1][p] * asv[1]
                    + acc[i][2][p] * asv[2] + acc[i][3][p] * asv[3];
            float d = acc[i][0][p] * adv[0] + acc[i][1][p] * adv[1]
                    + acc[i][2][p] * adv[2] + acc[i][3][p] * adv[3];
            #pragma unroll
            for (int o = 1; o <= 8; o <<= 1) { s += __shfl_xor(s, o); d += __shfl_xor(d, o); }
            if ((lane & 15) == 0) {
                int ridx = i * 16 + (lane >> 4) * 4 + p;
                sd_s[wave][ridx] = s;
                sd_d[wave][ridx] = d;
            }
        }
    }
    __syncthreads();
    // coalesced C store: 1024 int4 rows-major, 16 B/lane
    #pragma unroll
    for (int it = 0; it < 4; ++it) {
        int idx = it * 256 + t;
        int row = idx >> 4, c8 = (idx & 15) * 8;
        int gr = row0 + row;
        if (gr < M)
            *(int4*)&C[(size_t)gr * N_ + col0 + c8] = *(const int4*)&Cs[row * 136 + c8];
    }
    // attention combine (col-halves)
    if ((wave & 1) == 0 && lane < 32) {
        float s = sd_s[wave][lane] + sd_s[wave + 1][lane];
        float d = sd_d[wave][lane] + sd_d[wave + 1][lane];
        int r = row0 + wr + lane;
        if (r < M) {
            if (MODE == 1) {
                as_out[r * 4 + blockIdx.x] = s;
                ad_out[r * 4 + blockIdx.x] = d;
            } else {
                atomicAdd(&as_out[r], s);
                atomicAdd(&ad_out[r], d);
            }
        }
    }
}

// ---------------- edge aggregate (R9 shape — unchanged anchor) ----------------
__global__ __launch_bounds__(256) void edge_agg1_kernel(
        const unsigned short* __restrict__ h1b,   // [N,512] bf16
        const float4* __restrict__ as14,
        const float4* __restrict__ ad14,
        const int* __restrict__ ofs,
        const int* __restrict__ esrc,
        const float* __restrict__ b1,
        unsigned short* __restrict__ ho1b, int N) {
    int wave = threadIdx.x >> 6, lane = threadIdx.x & 63;
    int node = blockIdx.x * 4 + wave;
    if (node >= N) return;
    int beg = ofs[node], end = ofs[node + 1];
    float4 asn = as14[node], adn = ad14[node];
    float w0 = __expf(lrelu(asn.x + adn.x));
    float w1 = __expf(lrelu(asn.y + adn.y));
    float w2 = __expf(lrelu(asn.z + adn.z));
    float w3 = __expf(lrelu(asn.w + adn.w));
    int hd = lane >> 4;
    int c0 = lane * 8;
    float wsh = sel4(w0, w1, w2, w3, hd);
    float acc[8];
    {
        int4 r = *(const int4*)&h1b[(size_t)node * 512 + c0];
        acc[0] = wsh * bflo(r.x); acc[1] = wsh * bfhi(r.x);
        acc[2] = wsh * bflo(r.y); acc[3] = wsh * bfhi(r.y);
        acc[4] = wsh * bflo(r.z); acc[5] = wsh * bfhi(r.z);
        acc[6] = wsh * bflo(r.w); acc[7] = wsh * bfhi(r.w);
    }
    float d0 = 0.f, d1 = 0.f, d2 = 0.f, d3 = 0.f;
    for (int cb = beg; cb < end; cb += 64) {
        int idx = cb + lane;
        int sl = esrc[idx < end ? idx : end - 1];
        float4 wl = make_float4(0.f, 0.f, 0.f, 0.f);
        if (idx < end) {
            float4 a = as14[sl];
            wl.x = __expf(lrelu(a.x + adn.x));
            wl.y = __expf(lrelu(a.y + adn.y));
            wl.z = __expf(lrelu(a.z + adn.z));
            wl.w = __expf(lrelu(a.w + adn.w));
            d0 += wl.x; d1 += wl.y; d2 += wl.z; d3 += wl.w;
        }
        int jmax = end - cb; if (jmax > 64) jmax = 64;
        int j = 0;
        for (; j + 4 <= jmax; j += 4) {
            int s0 = __shfl(sl, j), s1 = __shfl(sl, j + 1);
            int s2 = __shfl(sl, j + 2), s3 = __shfl(sl, j + 3);
            float u0 = sel4(__shfl(wl.x, j), __shfl(wl.y, j), __shfl(wl.z, j), __shfl(wl.w, j), hd);
            float u1 = sel4(__shfl(wl.x, j + 1), __shfl(wl.y, j + 1), __shfl(wl.z, j + 1), __shfl(wl.w, j + 1), hd);
            float u2 = sel4(__shfl(wl.x, j + 2), __shfl(wl.y, j + 2), __shfl(wl.z, j + 2), __shfl(wl.w, j + 2), hd);
            float u3 = sel4(__shfl(wl.x, j + 3), __shfl(wl.y, j + 3), __shfl(wl.z, j + 3), __shfl(wl.w, j + 3), hd);
            int4 r0 = *(const int4*)&h1b[(size_t)s0 * 512 + c0];
            int4 r1 = *(const int4*)&h1b[(size_t)s1 * 512 + c0];
            int4 r2 = *(const int4*)&h1b[(size_t)s2 * 512 + c0];
            int4 r3 = *(const int4*)&h1b[(size_t)s3 * 512 + c0];
            acc[0] += u0 * bflo(r0.x); acc[1] += u0 * bfhi(r0.x);
            acc[2] += u0 * bflo(r0.y); acc[3] += u0 * bfhi(r0.y);
            acc[4] += u0 * bflo(r0.z); acc[5] += u0 * bfhi(r0.z);
            acc[6] += u0 * bflo(r0.w); acc[7] += u0 * bfhi(r0.w);
            acc[0] += u1 * bflo(r1.x); acc[1] += u1 * bfhi(r1.x);
            acc[2] += u1 * bflo(r1.y); acc[3] += u1 * bfhi(r1.y);
            acc[4] += u1 * bflo(r1.z); acc[5] += u1 * bfhi(r1.z);
            acc[6] += u1 * bflo(r1.w); acc[7] += u1 * bfhi(r1.w);
            acc[0] += u2 * bflo(r2.x); acc[1] += u2 * bfhi(r2.x);
            acc[2] += u2 * bflo(r2.y); acc[3] += u2 * bfhi(r2.y);
            acc[4] += u2 * bflo(r2.z); acc[5] += u2 * bfhi(r2.z);
            acc[6] += u2 * bflo(r2.w); acc[7] += u2 * bfhi(r2.w);
            acc[0] += u3 * bflo(r3.x); acc[1] += u3 * bfhi(r3.x);
            acc[2] += u3 * bflo(r3.y); acc[3] += u3 * bfhi(r3.y);
            acc[4] += u3 * bflo(r3.z); acc[5] += u3 * bfhi(r3.z);
            acc[6] += u3 * bflo(r3.w); acc[7] += u3 * bfhi(r3.w);
        }
        for (; j < jmax; ++j) {
            int s = __shfl(sl, j);
            float u = sel4(__shfl(wl.x, j), __shfl(wl.y, j), __shfl(wl.z, j), __shfl(wl.w, j), hd);
            int4 r = *(const int4*)&h1b[(size_t)s * 512 + c0];
            acc[0] += u * bflo(r.x); acc[1] += u * bfhi(r.x);
            acc[2] += u * bflo(r.y); acc[3] += u * bfhi(r.y);
            acc[4] += u * bflo(r.z); acc[5] += u * bfhi(r.z);
            acc[6] += u * bflo(r.w); acc[7] += u * bfhi(r.w);
        }
    }
    #pragma unroll
    for (int o = 32; o > 0; o >>= 1) {
        d0 += __shfl_xor(d0, o); d1 += __shfl_xor(d1, o);
        d2 += __shfl_xor(d2, o); d3 += __shfl_xor(d3, o);
    }
    d0 += w0; d1 += w1; d2 += w2; d3 += w3;
    float dh = sel4(d0, d1, d2, d3, hd);
    float inv = 1.f / dh;
    float4 bA = *(const float4*)&b1[c0], bB = *(const float4*)&b1[c0 + 4];
    float v0 = fmaxf(acc[0] * inv + bA.x, 0.f), v1 = fmaxf(acc[1] * inv + bA.y, 0.f);
    float v2 = fmaxf(acc[2] * inv + bA.z, 0.f), v3 = fmaxf(acc[3] * inv + bA.w, 0.f);
    float v4 = fmaxf(acc[4] * inv + bB.x, 0.f), v5 = fmaxf(acc[5] * inv + bB.y, 0.f);
    float v6 = fmaxf(acc[6] * inv + bB.z, 0.f), v7 = fmaxf(acc[7] * inv + bB.w, 0.f);
    int4 o;
    o.x = (int)((unsigned)f2bf(v0) | ((unsigned)f2bf(v1) << 16));
    o.y = (int)((unsigned)f2bf(v2) | ((unsigned)f2bf(v3) << 16));
    o.z = (int)((unsigned)f2bf(v4) | ((unsigned)f2bf(v5) << 16));
    o.w = (int)((unsigned)f2bf(v6) | ((unsigned)f2bf(v7) << 16));
    *(int4*)&ho1b[(size_t)node * 512 + c0] = o;
}

__global__ __launch_bounds__(256) void edge_agg2_kernel(
        const unsigned short* __restrict__ h2b,   // [N,256] bf16
        const float* __restrict__ as2,
        const float* __restrict__ ad2,
        const int* __restrict__ ofs,
        const int* __restrict__ esrc,
        const float* __restrict__ b2,
        unsigned short* __restrict__ ho2b, int N) {
    int wave = threadIdx.x >> 6, lane = threadIdx.x & 63;
    int node = blockIdx.x * 4 + wave;
    if (node >= N) return;
    int beg = ofs[node], end = ofs[node + 1];
    float adn = ad2[node];
    float wself = __expf(lrelu(as2[node] + adn));
    int c0 = lane * 4;
    float a0, a1, a2, a3;
    {
        int2 r = *(const int2*)&h2b[(size_t)node * 256 + c0];
        a0 = wself * bflo(r.x); a1 = wself * bfhi(r.x);
        a2 = wself * bflo(r.y); a3 = wself * bfhi(r.y);
    }
    float dsum = 0.f;
    for (int cb = beg; cb < end; cb += 64) {
        int idx = cb + lane;
        int sl = esrc[idx < end ? idx : end - 1];
        float wl = 0.f;
        if (idx < end) {
            wl = __expf(lrelu(as2[sl] + adn));
            dsum += wl;
        }
        int jmax = end - cb; if (jmax > 64) jmax = 64;
        int j = 0;
        for (; j + 4 <= jmax; j += 4) {
            int s0 = __shfl(sl, j), s1 = __shfl(sl, j + 1);
            int s2 = __shfl(sl, j + 2), s3 = __shfl(sl, j + 3);
            float u0 = __shfl(wl, j), u1 = __shfl(wl, j + 1);
            float u2 = __shfl(wl, j + 2), u3 = __shfl(wl, j + 3);
            int2 r0 = *(const int2*)&h2b[(size_t)s0 * 256 + c0];
            int2 r1 = *(const int2*)&h2b[(size_t)s1 * 256 + c0];
            int2 r2 = *(const int2*)&h2b[(size_t)s2 * 256 + c0];
            int2 r3 = *(const int2*)&h2b[(size_t)s3 * 256 + c0];
            a0 += u0 * bflo(r0.x); a1 += u0 * bfhi(r0.x);
            a2 += u0 * bflo(r0.y); a3 += u0 * bfhi(r0.y);
            a0 += u1 * bflo(r1.x); a1 += u1 * bfhi(r1.x);
            a2 += u1 * bflo(r1.y); a3 += u1 * bfhi(r1.y);
            a0 += u2 * bflo(r2.x); a1 += u2 * bfhi(r2.x);
            a2 += u2 * bflo(r2.y); a3 += u2 * bfhi(r2.y);
            a0 += u3 * bflo(r3.x); a1 += u3 * bfhi(r3.x);
            a2 += u3 * bflo(r3.y); a3 += u3 * bfhi(r3.y);
        }
        for (; j < jmax; ++j) {
            int s = __shfl(sl, j);
            float u = __shfl(wl, j);
            int2 r = *(const int2*)&h2b[(size_t)s * 256 + c0];
            a0 += u * bflo(r.x); a1 += u * bfhi(r.x);
            a2 += u * bflo(r.y); a3 += u * bfhi(r.y);
        }
    }
    #pragma unroll
    for (int o = 32; o > 0; o >>= 1) dsum += __shfl_xor(dsum, o);
    dsum += wself;
    float inv = 1.f / dsum;
    float4 bv = *(const float4*)&b2[c0];
    float v0 = a0 * inv + bv.x, v1 = a1 * inv + bv.y;
    float v2 = a2 * inv + bv.z, v3 = a3 * inv + bv.w;
    int2 o;
    o.x = (int)((unsigned)f2bf(v0) | ((unsigned)f2bf(v1) << 16));
    o.y = (int)((unsigned)f2bf(v2) | ((unsigned)f2bf(v3) << 16));
    *(int2*)&ho2b[(size_t)node * 256 + c0] = o;
}

// ---------------- global max pool, stage 1 (batch is sorted; bf16 input) ----------------
__global__ __launch_bounds__(256) void pool1_kernel(const unsigned short* __restrict__ ho2b,
                                                    const int* __restrict__ batch,
                                                    int N, float* __restrict__ part) {
    int g = blockIdx.x, c = blockIdx.y, t = threadIdx.x;
    int lo = 0, hi = N;
    while (lo < hi) { int mid = (lo + hi) >> 1; if (batch[mid] < g) lo = mid + 1; else hi = mid; }
    int start = lo;
    lo = 0; hi = N;
    while (lo < hi) { int mid = (lo + hi) >> 1; if (batch[mid] < g + 1) lo = mid + 1; else hi = mid; }
    int end = lo;
    int len = end - start;
    int cb = start + (int)(((long long)len * c) / PCHUNK);
    int ce = start + (int)(((long long)len * (c + 1)) / PCHUNK);
    float m = -INFINITY;
    for (int n = cb; n < ce; ++n) m = fmaxf(m, bfu(ho2b[(size_t)n * 256 + t]));
    part[((size_t)g * PCHUNK + c) * 256 + t] = m;
}

// ---------------- FC head (+pool stage 2) + log_softmax ----------------
__global__ __launch_bounds__(64) void head_kernel(const float* __restrict__ part,
                                                  const float* __restrict__ fc1w,
                                                  const float* __restrict__ fc1b,
                                                  const float* __restrict__ fc2w,
                                                  const float* __restrict__ fc2b,
                                                  float* __restrict__ out) {
    __shared__ float gr[256];
    __shared__ float hid[64];
    __shared__ float o10[NCLS];
    int g = blockIdx.x, t = threadIdx.x;
    for (int i = t; i < 256; i += 64) {
        float m = -INFINITY;
        #pragma unroll
        for (int c = 0; c < PCHUNK; ++c)
            m = fmaxf(m, part[((size_t)g * PCHUNK + c) * 256 + i]);
        gr[i] = m;
    }
    __syncthreads();
    float s = fc1b[t];
    for (int k = 0; k < 256; ++k) s += gr[k] * fc1w[k * 64 + t];
    hid[t] = s > 0.f ? s : 0.f;
    __syncthreads();
    if (t < NCLS) {
        float s2 = fc2b[t];
        for (int k = 0; k < 64; ++k) s2 += hid[k] * fc2w[k * NCLS + t];
        o10[t] = s2;
    }
    __syncthreads();
    if (t == 0) {
        float mx = -INFINITY;
        for (int c = 0; c < NCLS; ++c) mx = fmaxf(mx, o10[c]);
        float se = 0.f;
        for (int c = 0; c < NCLS; ++c) se += __expf(o10[c] - mx);
        float lse = mx + logf(se);
        for (int c = 0; c < NCLS; ++c) out[g * NCLS + c] = o10[c] - lse;
    }
}

extern "C" void kernel_launch(void* const* d_in, const int* in_sizes, int n_in,
                              void* d_out, int out_size, void* d_ws, size_t ws_size,
                              hipStream_t stream) {
    (void)n_in; (void)out_size; (void)ws_size;
    const float* x        = (const float*)d_in[0];
    const int*   ei       = (const int*)d_in[1];
    const int*   batch    = (const int*)d_in[2];
    const float* W1       = (const float*)d_in[3];
    const float* att_src1 = (const float*)d_in[4];
    const float* att_dst1 = (const float*)d_in[5];
    const float* b1       = (const float*)d_in[6];
    const float* W2       = (const float*)d_in[7];
    const float* att_src2 = (const float*)d_in[8];
    const float* att_dst2 = (const float*)d_in[9];
    const float* b2       = (const float*)d_in[10];
    const float* fc1w     = (const float*)d_in[11];
    const float* fc1b     = (const float*)d_in[12];
    const float* fc2w     = (const float*)d_in[13];
    const float* fc2b     = (const float*)d_in[14];

    const int N = in_sizes[2];
    const int E = in_sizes[1] / 2;
    const int tot = 2 * E;

    char* base = (char*)d_ws;
    size_t off = 0;
    auto alloc = [&](size_t bytes) -> void* {
        void* p = base + off;
        off = (off + bytes + 255) & ~(size_t)255;
        return p;
    };
    int*   ofs    = (int*)alloc((size_t)(N + 1) * 4);
    int*   cursor = (int*)alloc((size_t)N * 4);    // cursor, as2, ad2 zeroed by one memset
    float* as2    = (float*)alloc((size_t)N * 4);
    float* ad2    = (float*)alloc((size_t)N * 4);
    int*   esrc   = (int*)alloc((size_t)tot * 4);
    float* as1    = (float*)alloc((size_t)N * HEADS * 4);
    float* ad1    = (float*)alloc((size_t)N * HEADS * 4);
    unsigned short* xb   = (unsigned short*)alloc((size_t)N * FDIM * 2);
    unsigned short* W1t  = (unsigned short*)alloc((size_t)512 * 128 * 2);
    unsigned short* W2t  = (unsigned short*)alloc((size_t)256 * 512 * 2);
    unsigned short* h1b  = (unsigned short*)alloc((size_t)N * 512 * 2);
    unsigned short* ho1b = (unsigned short*)alloc((size_t)N * 512 * 2);
    unsigned short* h2b  = (unsigned short*)alloc((size_t)N * 256 * 2);
    unsigned short* ho2b = (unsigned short*)alloc((size_t)N * 256 * 2);
    float* ppart  = (float*)alloc((size_t)NGRAPH * PCHUNK * 256 * 4);

    // one memset covers cursor + as2 + ad2 (contiguous allocations)
    size_t zbytes = (size_t)((char*)ad2 - (char*)cursor) + (size_t)N * 4;
    hipMemsetAsync(cursor, 0, zbytes, stream);

    // CSR build
    hist_kernel<<<(tot + 255) / 256, 256, 0, stream>>>(ei, E, cursor);
    scan_kernel<<<1, 1024, 0, stream>>>(cursor, ofs, N);
    scatter_kernel<<<(tot + 255) / 256, 256, 0, stream>>>(ei, E, cursor, esrc);

    // bf16 conversions
    cvt_kernel<<<(N * FDIM / 4 + 255) / 256, 256, 0, stream>>>(x, xb, N * FDIM / 4);
    tconv_kernel<<<dim3(512 / 32, 128 / 32), dim3(32, 8), 0, stream>>>(W1, W1t, 128, 512);
    tconv_kernel<<<dim3(256 / 32, 512 / 32), dim3(32, 8), 0, stream>>>(W2, W2t, 512, 256);

    // Layer 1: h1 = x @ W1 (M=N, N=512, K=128); att1 fused into epilogue
    bgemm_kernel<1><<<dim3(512 / 128, (N + 63) / 64), 256, 0, stream>>>(
        xb, W1t, h1b, att_src1, att_dst1, as1, ad1, N, 512, 128);
    edge_agg1_kernel<<<(N + 3) / 4, 256, 0, stream>>>(h1b, (const float4*)as1, (const float4*)ad1,
                                                      ofs, esrc, b1, ho1b, N);

    // Layer 2: h2 = ho1 @ W2 (M=N, N=256, K=512); att2 fused (atomic partials)
    bgemm_kernel<2><<<dim3(256 / 128, (N + 63) / 64), 256, 0, stream>>>(
        ho1b, W2t, h2b, att_src2, att_dst2, as2, ad2, N, 256, 512);
    edge_agg2_kernel<<<(N + 3) / 4, 256, 0, stream>>>(h2b, as2, ad2, ofs, esrc, b2, ho2b, N);

    // Pool stage 1 + fused (pool stage 2 + head)
    pool1_kernel<<<dim3(NGRAPH, PCHUNK), 256, 0, stream>>>(ho2b, batch, N, ppart);
    head_kernel<<<NGRAPH, 64, 0, stream>>>(ppart, fc1w, fc1b, fc2w, fc2b, (float*)d_out);
}

// Round 11
// 268.846 us; speedup vs baseline: 1.4402x; 1.0696x over previous
//
#include <hip/hip_runtime.h>
#include <math.h>

// Problem constants (reference: N=20000, E=160000, F=128, H=4, C1=128, C2=256, G=64, NCLS=10)
#define FDIM 128
#define HEADS 4
#define C1DIM 128
#define C2DIM 256
#define NGRAPH 64
#define NCLS 10
#define PCHUNK 8

typedef __attribute__((ext_vector_type(8))) short short8;   // 8 bf16 (4 VGPRs)
typedef __attribute__((ext_vector_type(4))) float float4v;  // 4 fp32 acc

__device__ __forceinline__ unsigned short f2bf(float f) {
    unsigned u = __builtin_bit_cast(unsigned, f);
    unsigned r = (u + 0x7FFFu + ((u >> 16) & 1u)) >> 16;   // RNE
    return (unsigned short)r;
}
__device__ __forceinline__ float bflo(int u) { return __builtin_bit_cast(float, (unsigned)u << 16); }
__device__ __forceinline__ float bfhi(int u) { return __builtin_bit_cast(float, (unsigned)u & 0xffff0000u); }
__device__ __forceinline__ float bfu(unsigned short u) { return __builtin_bit_cast(float, (unsigned)u << 16); }
__device__ __forceinline__ float lrelu(float x) { return x > 0.f ? x : 0.2f * x; }
__device__ __forceinline__ float sel4(float a, float b, float c, float d, int hd) {
    return hd == 0 ? a : hd == 1 ? b : hd == 2 ? c : d;
}

// ---------------- CSR build ----------------
__global__ void hist_kernel(const int* __restrict__ ei, int E, int* __restrict__ counts) {
    int i = blockIdx.x * blockDim.x + threadIdx.x;
    if (i >= 2 * E) return;
    int dst = (i < E) ? ei[E + i] : ei[i - E];
    atomicAdd(&counts[dst], 1);
}

__global__ __launch_bounds__(1024) void scan_kernel(int* __restrict__ counts_cursor,
                                                    int* __restrict__ ofs, int N) {
    __shared__ int part[1024];
    int t = threadIdx.x;
    int chunk = (N + 1023) / 1024;
    int b = t * chunk;
    int e = b + chunk; if (e > N) e = N;
    int s = 0;
    int i = b;
    if ((chunk & 3) == 0) {                       // aligned int4 fast path
        for (; i + 4 <= e; i += 4) {
            int4 v = *(const int4*)&counts_cursor[i];
            s += v.x + v.y + v.z + v.w;
        }
    }
    for (; i < e; ++i) s += counts_cursor[i];
    part[t] = s;
    __syncthreads();
    for (int o = 1; o < 1024; o <<= 1) {
        int v = (t >= o) ? part[t - o] : 0;
        __syncthreads();
        part[t] += v;
        __syncthreads();
    }
    int run = part[t] - s;
    i = b;
    if ((chunk & 3) == 0) {
        for (; i + 4 <= e; i += 4) {
            int4 c = *(const int4*)&counts_cursor[i];
            int4 o4;
            o4.x = run; run += c.x;
            o4.y = run; run += c.y;
            o4.z = run; run += c.z;
            o4.w = run; run += c.w;
            *(int4*)&ofs[i] = o4;
            counts_cursor[i]     = o4.x;
            counts_cursor[i + 1] = o4.y;
            counts_cursor[i + 2] = o4.z;
            counts_cursor[i + 3] = o4.w;
        }
    }
    for (; i < e; ++i) {
        int c = counts_cursor[i];
        ofs[i] = run;
        counts_cursor[i] = run;
        run += c;
    }
    if (t == 1023) ofs[N] = part[1023];
}

__global__ void scatter_kernel(const int* __restrict__ ei, int E,
                               int* __restrict__ cursor, int* __restrict__ esrc) {
    int i = blockIdx.x * blockDim.x + threadIdx.x;
    if (i >= 2 * E) return;
    int src = ei[i];
    int dst = (i < E) ? ei[E + i] : ei[i - E];
    int pos = atomicAdd(&cursor[dst], 1);
    esrc[pos] = src;
}

// ---------------- fp32 -> bf16 conversions ----------------
__global__ void cvt_kernel(const float* __restrict__ src, unsigned short* __restrict__ dst, int n4) {
    int i = blockIdx.x * blockDim.x + threadIdx.x;
    if (i >= n4) return;
    float4 v = ((const float4*)src)[i];
    ushort4 o;
    o.x = f2bf(v.x); o.y = f2bf(v.y); o.z = f2bf(v.z); o.w = f2bf(v.w);
    ((ushort4*)dst)[i] = o;
}

// Transpose-convert weights: W[K,N] fp32 -> Wt[N,K] bf16. Grid (N/32, K/32), block (32,8).
__global__ void tconv_kernel(const float* __restrict__ W, unsigned short* __restrict__ Wt,
                             int K, int N_) {
    __shared__ float tile[32][33];
    int bx = blockIdx.x * 32;
    int by = blockIdx.y * 32;
    int tx = threadIdx.x, ty = threadIdx.y;
    #pragma unroll
    for (int r = 0; r < 32; r += 8)
        tile[ty + r][tx] = W[(size_t)(by + ty + r) * N_ + bx + tx];
    __syncthreads();
    #pragma unroll
    for (int r = 0; r < 32; r += 8)
        Wt[(size_t)(bx + ty + r) * K + by + tx] = f2bf(tile[tx][ty + r]);
}

// ---------------- bf16 MFMA GEMM (64x128 tile) + fused attention epilogue ----------------
template<int MODE>
__global__ __launch_bounds__(256) void bgemm_kernel(
        const unsigned short* __restrict__ A,   // [M,K] bf16
        const unsigned short* __restrict__ Bt,  // [N,K] bf16
        unsigned short* __restrict__ C,         // [M,N] bf16
        const float* __restrict__ att_src,      // [N_] fp32
        const float* __restrict__ att_dst,      // [N_] fp32
        float* __restrict__ as_out,
        float* __restrict__ ad_out,
        int M, int N_, int K) {
    __shared__ unsigned short As[64 * 32];       // 4 KB
    __shared__ unsigned short Bs[128 * 32];      // 8 KB
    __shared__ unsigned short Cs[64 * 136];      // 17 KB, +8 pad
    __shared__ float sd_s[4][32];
    __shared__ float sd_d[4][32];
    const int t = threadIdx.x;
    const int lane = t & 63;
    const int wave = t >> 6;
    const int row0 = blockIdx.y * 64, col0 = blockIdx.x * 128;
    const int wr = (wave >> 1) * 32, wc = (wave & 1) * 64;
    float4v acc[2][4] = {};
    for (int k0 = 0; k0 < K; k0 += 32) {
        {
            int i = t;
            int gr = row0 + (i >> 2); if (gr >= M) gr = M - 1;
            const unsigned short* gp = A + (size_t)gr * K + k0 + ((i & 3) << 3);
            __builtin_amdgcn_global_load_lds(
                (const __attribute__((address_space(1))) unsigned int*)gp,
                (__attribute__((address_space(3))) unsigned int*)&As[i * 8], 16, 0, 0);
        }
        #pragma unroll
        for (int c = 0; c < 2; ++c) {
            int i = c * 256 + t;
            int gn = col0 + (i >> 2);
            const unsigned short* gp = Bt + (size_t)gn * K + k0 + ((i & 3) << 3);
            __builtin_amdgcn_global_load_lds(
                (const __attribute__((address_space(1))) unsigned int*)gp,
                (__attribute__((address_space(3))) unsigned int*)&Bs[i * 8], 16, 0, 0);
        }
        __syncthreads();
        short8 af[2], bfr[4];
        #pragma unroll
        for (int i = 0; i < 2; ++i)
            af[i] = *(const short8*)&As[(wr + i * 16 + (lane & 15)) * 32 + (lane >> 4) * 8];
        #pragma unroll
        for (int j = 0; j < 4; ++j)
            bfr[j] = *(const short8*)&Bs[(wc + j * 16 + (lane & 15)) * 32 + (lane >> 4) * 8];
        #pragma unroll
        for (int i = 0; i < 2; ++i)
            #pragma unroll
            for (int j = 0; j < 4; ++j)
                acc[i][j] = __builtin_amdgcn_mfma_f32_16x16x32_bf16(af[i], bfr[j], acc[i][j], 0, 0, 0);
        __syncthreads();
    }
    float asv[4], adv[4];
    #pragma unroll
    for (int j = 0; j < 4; ++j) {
        int cc = col0 + wc + j * 16 + (lane & 15);
        asv[j] = att_src[cc];
        adv[j] = att_dst[cc];
    }
    #pragma unroll
    for (int i = 0; i < 2; ++i) {
        #pragma unroll
        for (int p = 0; p < 4; ++p) {
            int rr = wr + i * 16 + (lane >> 4) * 4 + p;
            #pragma unroll
            for (int j = 0; j < 4; ++j)
                Cs[rr * 136 + wc + j * 16 + (lane & 15)] = f2bf(acc[i][j][p]);
            float s = acc[i][0][p] * asv[0] + acc[i][1][p] * asv[1]
                    + acc[i][2][p] * asv[2] + acc[i][3][p] * asv[3];
            float d = acc[i][0][p] * adv[0] + acc[i][1][p] * adv[1]
                    + acc[i][2][p] * adv[2] + acc[i][3][p] * adv[3];
            #pragma unroll
            for (int o = 1; o <= 8; o <<= 1) { s += __shfl_xor(s, o); d += __shfl_xor(d, o); }
            if ((lane & 15) == 0) {
                int ridx = i * 16 + (lane >> 4) * 4 + p;
                sd_s[wave][ridx] = s;
                sd_d[wave][ridx] = d;
            }
        }
    }
    __syncthreads();
    #pragma unroll
    for (int it = 0; it < 4; ++it) {
        int idx = it * 256 + t;
        int row = idx >> 4, c8 = (idx & 15) * 8;
        int gr = row0 + row;
        if (gr < M)
            *(int4*)&C[(size_t)gr * N_ + col0 + c8] = *(const int4*)&Cs[row * 136 + c8];
    }
    if ((wave & 1) == 0 && lane < 32) {
        float s = sd_s[wave][lane] + sd_s[wave + 1][lane];
        float d = sd_d[wave][lane] + sd_d[wave + 1][lane];
        int r = row0 + wr + lane;
        if (r < M) {
            if (MODE == 1) {
                as_out[r * 4 + blockIdx.x] = s;
                ad_out[r * 4 + blockIdx.x] = d;
            } else {
                atomicAdd(&as_out[r], s);
                atomicAdd(&ad_out[r], d);
            }
        }
    }
}

// ---------------- edge aggregate (R9 shape, gather unroll x8 for MLP) ----------------
__global__ __launch_bounds__(256) void edge_agg1_kernel(
        const unsigned short* __restrict__ h1b,   // [N,512] bf16
        const float4* __restrict__ as14,
        const float4* __restrict__ ad14,
        const int* __restrict__ ofs,
        const int* __restrict__ esrc,
        const float* __restrict__ b1,
        unsigned short* __restrict__ ho1b, int N) {
    int wave = threadIdx.x >> 6, lane = threadIdx.x & 63;
    int node = blockIdx.x * 4 + wave;
    if (node >= N) return;
    int beg = ofs[node], end = ofs[node + 1];
    float4 asn = as14[node], adn = ad14[node];
    float w0 = __expf(lrelu(asn.x + adn.x));
    float w1 = __expf(lrelu(asn.y + adn.y));
    float w2 = __expf(lrelu(asn.z + adn.z));
    float w3 = __expf(lrelu(asn.w + adn.w));
    int hd = lane >> 4;
    int c0 = lane * 8;
    float wsh = sel4(w0, w1, w2, w3, hd);
    float acc[8];
    {
        int4 r = *(const int4*)&h1b[(size_t)node * 512 + c0];
        acc[0] = wsh * bflo(r.x); acc[1] = wsh * bfhi(r.x);
        acc[2] = wsh * bflo(r.y); acc[3] = wsh * bfhi(r.y);
        acc[4] = wsh * bflo(r.z); acc[5] = wsh * bfhi(r.z);
        acc[6] = wsh * bflo(r.w); acc[7] = wsh * bfhi(r.w);
    }
    float d0 = 0.f, d1 = 0.f, d2 = 0.f, d3 = 0.f;
    for (int cb = beg; cb < end; cb += 64) {
        int idx = cb + lane;
        int sl = esrc[idx < end ? idx : end - 1];
        float4 wl = make_float4(0.f, 0.f, 0.f, 0.f);
        if (idx < end) {
            float4 a = as14[sl];
            wl.x = __expf(lrelu(a.x + adn.x));
            wl.y = __expf(lrelu(a.y + adn.y));
            wl.z = __expf(lrelu(a.z + adn.z));
            wl.w = __expf(lrelu(a.w + adn.w));
            d0 += wl.x; d1 += wl.y; d2 += wl.z; d3 += wl.w;
        }
        int jmax = end - cb; if (jmax > 64) jmax = 64;
        int j = 0;
        for (; j + 8 <= jmax; j += 8) {        // 8 gathers in flight per wave
            int ss[8]; float u[8]; int4 r[8];
            #pragma unroll
            for (int q = 0; q < 8; ++q) {
                ss[q] = __shfl(sl, j + q);
                u[q] = sel4(__shfl(wl.x, j + q), __shfl(wl.y, j + q),
                            __shfl(wl.z, j + q), __shfl(wl.w, j + q), hd);
            }
            #pragma unroll
            for (int q = 0; q < 8; ++q) r[q] = *(const int4*)&h1b[(size_t)ss[q] * 512 + c0];
            #pragma unroll
            for (int q = 0; q < 8; ++q) {
                acc[0] += u[q] * bflo(r[q].x); acc[1] += u[q] * bfhi(r[q].x);
                acc[2] += u[q] * bflo(r[q].y); acc[3] += u[q] * bfhi(r[q].y);
                acc[4] += u[q] * bflo(r[q].z); acc[5] += u[q] * bfhi(r[q].z);
                acc[6] += u[q] * bflo(r[q].w); acc[7] += u[q] * bfhi(r[q].w);
            }
        }
        for (; j < jmax; ++j) {
            int s = __shfl(sl, j);
            float u = sel4(__shfl(wl.x, j), __shfl(wl.y, j), __shfl(wl.z, j), __shfl(wl.w, j), hd);
            int4 r = *(const int4*)&h1b[(size_t)s * 512 + c0];
            acc[0] += u * bflo(r.x); acc[1] += u * bfhi(r.x);
            acc[2] += u * bflo(r.y); acc[3] += u * bfhi(r.y);
            acc[4] += u * bflo(r.z); acc[5] += u * bfhi(r.z);
            acc[6] += u * bflo(r.w); acc[7] += u * bfhi(r.w);
        }
    }
    #pragma unroll
    for (int o = 32; o > 0; o >>= 1) {
        d0 += __shfl_xor(d0, o); d1 += __shfl_xor(d1, o);
        d2 += __shfl_xor(d2, o); d3 += __shfl_xor(d3, o);
    }
    d0 += w0; d1 += w1; d2 += w2; d3 += w3;
    float dh = sel4(d0, d1, d2, d3, hd);
    float inv = 1.f / dh;
    float4 bA = *(const float4*)&b1[c0], bB = *(const float4*)&b1[c0 + 4];
    float v0 = fmaxf(acc[0] * inv + bA.x, 0.f), v1 = fmaxf(acc[1] * inv + bA.y, 0.f);
    float v2 = fmaxf(acc[2] * inv + bA.z, 0.f), v3 = fmaxf(acc[3] * inv + bA.w, 0.f);
    float v4 = fmaxf(acc[4] * inv + bB.x, 0.f), v5 = fmaxf(acc[5] * inv + bB.y, 0.f);
    float v6 = fmaxf(acc[6] * inv + bB.z, 0.f), v7 = fmaxf(acc[7] * inv + bB.w, 0.f);
    int4 o;
    o.x = (int)((unsigned)f2bf(v0) | ((unsigned)f2bf(v1) << 16));
    o.y = (int)((unsigned)f2bf(v2) | ((unsigned)f2bf(v3) << 16));
    o.z = (int)((unsigned)f2bf(v4) | ((unsigned)f2bf(v5) << 16));
    o.w = (int)((unsigned)f2bf(v6) | ((unsigned)f2bf(v7) << 16));
    *(int4*)&ho1b[(size_t)node * 512 + c0] = o;
}

__global__ __launch_bounds__(256) void edge_agg2_kernel(
        const unsigned short* __restrict__ h2b,   // [N,256] bf16
        const float* __restrict__ as2,
        const float* __restrict__ ad2,
        const int* __restrict__ ofs,
        const int* __restrict__ esrc,
        const float* __restrict__ b2,
        unsigned short* __restrict__ ho2b, int N) {
    int wave = threadIdx.x >> 6, lane = threadIdx.x & 63;
    int node = blockIdx.x * 4 + wave;
    if (node >= N) return;
    int beg = ofs[node], end = ofs[node + 1];
    float adn = ad2[node];
    float wself = __expf(lrelu(as2[node] + adn));
    int c0 = lane * 4;
    float a0, a1, a2, a3;
    {
        int2 r = *(const int2*)&h2b[(size_t)node * 256 + c0];
        a0 = wself * bflo(r.x); a1 = wself * bfhi(r.x);
        a2 = wself * bflo(r.y); a3 = wself * bfhi(r.y);
    }
    float dsum = 0.f;
    for (int cb = beg; cb < end; cb += 64) {
        int idx = cb + lane;
        int sl = esrc[idx < end ? idx : end - 1];
        float wl = 0.f;
        if (idx < end) {
            wl = __expf(lrelu(as2[sl] + adn));
            dsum += wl;
        }
        int jmax = end - cb; if (jmax > 64) jmax = 64;
        int j = 0;
        for (; j + 8 <= jmax; j += 8) {        // 8 gathers in flight per wave
            int ss[8]; float u[8]; int2 r[8];
            #pragma unroll
            for (int q = 0; q < 8; ++q) {
                ss[q] = __shfl(sl, j + q);
                u[q] = __shfl(wl, j + q);
            }
            #pragma unroll
            for (int q = 0; q < 8; ++q) r[q] = *(const int2*)&h2b[(size_t)ss[q] * 256 + c0];
            #pragma unroll
            for (int q = 0; q < 8; ++q) {
                a0 += u[q] * bflo(r[q].x); a1 += u[q] * bfhi(r[q].x);
                a2 += u[q] * bflo(r[q].y); a3 += u[q] * bfhi(r[q].y);
            }
        }
        for (; j < jmax; ++j) {
            int s = __shfl(sl, j);
            float u = __shfl(wl, j);
            int2 r = *(const int2*)&h2b[(size_t)s * 256 + c0];
            a0 += u * bflo(r.x); a1 += u * bfhi(r.x);
            a2 += u * bflo(r.y); a3 += u * bfhi(r.y);
        }
    }
    #pragma unroll
    for (int o = 32; o > 0; o >>= 1) dsum += __shfl_xor(dsum, o);
    dsum += wself;
    float inv = 1.f / dsum;
    float4 bv = *(const float4*)&b2[c0];
    float v0 = a0 * inv + bv.x, v1 = a1 * inv + bv.y;
    float v2 = a2 * inv + bv.z, v3 = a3 * inv + bv.w;
    int2 o;
    o.x = (int)((unsigned)f2bf(v0) | ((unsigned)f2bf(v1) << 16));
    o.y = (int)((unsigned)f2bf(v2) | ((unsigned)f2bf(v3) << 16));
    *(int2*)&ho2b[(size_t)node * 256 + c0] = o;
}

// ---------------- global max pool, stage 1 (batch is sorted; bf16 input) ----------------
__global__ __launch_bounds__(256) void pool1_kernel(const unsigned short* __restrict__ ho2b,
                                                    const int* __restrict__ batch,
                                                    int N, float* __restrict__ part) {
    int g = blockIdx.x, c = blockIdx.y, t = threadIdx.x;
    int lo = 0, hi = N;
    while (lo < hi) { int mid = (lo + hi) >> 1; if (batch[mid] < g) lo = mid + 1; else hi = mid; }
    int start = lo;
    lo = 0; hi = N;
    while (lo < hi) { int mid = (lo + hi) >> 1; if (batch[mid] < g + 1) lo = mid + 1; else hi = mid; }
    int end = lo;
    int len = end - start;
    int cb = start + (int)(((long long)len * c) / PCHUNK);
    int ce = start + (int)(((long long)len * (c + 1)) / PCHUNK);
    float m = -INFINITY;
    for (int n = cb; n < ce; ++n) m = fmaxf(m, bfu(ho2b[(size_t)n * 256 + t]));
    part[((size_t)g * PCHUNK + c) * 256 + t] = m;
}

// ---------------- FC head (+pool stage 2) + log_softmax ----------------
__global__ __launch_bounds__(64) void head_kernel(const float* __restrict__ part,
                                                  const float* __restrict__ fc1w,
                                                  const float* __restrict__ fc1b,
                                                  const float* __restrict__ fc2w,
                                                  const float* __restrict__ fc2b,
                                                  float* __restrict__ out) {
    __shared__ float gr[256];
    __shared__ float hid[64];
    __shared__ float o10[NCLS];
    int g = blockIdx.x, t = threadIdx.x;
    for (int i = t; i < 256; i += 64) {
        float m = -INFINITY;
        #pragma unroll
        for (int c = 0; c < PCHUNK; ++c)
            m = fmaxf(m, part[((size_t)g * PCHUNK + c) * 256 + i]);
        gr[i] = m;
    }
    __syncthreads();
    float s = fc1b[t];
    for (int k = 0; k < 256; ++k) s += gr[k] * fc1w[k * 64 + t];
    hid[t] = s > 0.f ? s : 0.f;
    __syncthreads();
    if (t < NCLS) {
        float s2 = fc2b[t];
        for (int k = 0; k < 64; ++k) s2 += hid[k] * fc2w[k * NCLS + t];
        o10[t] = s2;
    }
    __syncthreads();
    if (t == 0) {
        float mx = -INFINITY;
        for (int c = 0; c < NCLS; ++c) mx = fmaxf(mx, o10[c]);
        float se = 0.f;
        for (int c = 0; c < NCLS; ++c) se += __expf(o10[c] - mx);
        float lse = mx + logf(se);
        for (int c = 0; c < NCLS; ++c) out[g * NCLS + c] = o10[c] - lse;
    }
}

extern "C" void kernel_launch(void* const* d_in, const int* in_sizes, int n_in,
                              void* d_out, int out_size, void* d_ws, size_t ws_size,
                              hipStream_t stream) {
    (void)n_in; (void)out_size; (void)ws_size;
    const float* x        = (const float*)d_in[0];
    const int*   ei       = (const int*)d_in[1];
    const int*   batch    = (const int*)d_in[2];
    const float* W1       = (const float*)d_in[3];
    const float* att_src1 = (const float*)d_in[4];
    const float* att_dst1 = (const float*)d_in[5];
    const float* b1       = (const float*)d_in[6];
    const float* W2       = (const float*)d_in[7];
    const float* att_src2 = (const float*)d_in[8];
    const float* att_dst2 = (const float*)d_in[9];
    const float* b2       = (const float*)d_in[10];
    const float* fc1w     = (const float*)d_in[11];
    const float* fc1b     = (const float*)d_in[12];
    const float* fc2w     = (const float*)d_in[13];
    const float* fc2b     = (const float*)d_in[14];

    const int N = in_sizes[2];
    const int E = in_sizes[1] / 2;
    const int tot = 2 * E;

    char* base = (char*)d_ws;
    size_t off = 0;
    auto alloc = [&](size_t bytes) -> void* {
        void* p = base + off;
        off = (off + bytes + 255) & ~(size_t)255;
        return p;
    };
    int*   ofs    = (int*)alloc((size_t)(N + 1) * 4);
    int*   cursor = (int*)alloc((size_t)N * 4);    // cursor, as2, ad2 zeroed by one memset
    float* as2    = (float*)alloc((size_t)N * 4);
    float* ad2    = (float*)alloc((size_t)N * 4);
    int*   esrc   = (int*)alloc((size_t)tot * 4);
    float* as1    = (float*)alloc((size_t)N * HEADS * 4);
    float* ad1    = (float*)alloc((size_t)N * HEADS * 4);
    unsigned short* xb   = (unsigned short*)alloc((size_t)N * FDIM * 2);
    unsigned short* W1t  = (unsigned short*)alloc((size_t)512 * 128 * 2);
    unsigned short* W2t  = (unsigned short*)alloc((size_t)256 * 512 * 2);
    unsigned short* h1b  = (unsigned short*)alloc((size_t)N * 512 * 2);
    unsigned short* ho1b = (unsigned short*)alloc((size_t)N * 512 * 2);
    unsigned short* h2b  = (unsigned short*)alloc((size_t)N * 256 * 2);
    unsigned short* ho2b = (unsigned short*)alloc((size_t)N * 256 * 2);
    float* ppart  = (float*)alloc((size_t)NGRAPH * PCHUNK * 256 * 4);

    size_t zbytes = (size_t)((char*)ad2 - (char*)cursor) + (size_t)N * 4;
    hipMemsetAsync(cursor, 0, zbytes, stream);

    // CSR build
    hist_kernel<<<(tot + 255) / 256, 256, 0, stream>>>(ei, E, cursor);
    scan_kernel<<<1, 1024, 0, stream>>>(cursor, ofs, N);
    scatter_kernel<<<(tot + 255) / 256, 256, 0, stream>>>(ei, E, cursor, esrc);

    // bf16 conversions
    cvt_kernel<<<(N * FDIM / 4 + 255) / 256, 256, 0, stream>>>(x, xb, N * FDIM / 4);
    tconv_kernel<<<dim3(512 / 32, 128 / 32), dim3(32, 8), 0, stream>>>(W1, W1t, 128, 512);
    tconv_kernel<<<dim3(256 / 32, 512 / 32), dim3(32, 8), 0, stream>>>(W2, W2t, 512, 256);

    // Layer 1: h1 = x @ W1 (M=N, N=512, K=128); att1 fused into epilogue
    bgemm_kernel<1><<<dim3(512 / 128, (N + 63) / 64), 256, 0, stream>>>(
        xb, W1t, h1b, att_src1, att_dst1, as1, ad1, N, 512, 128);
    edge_agg1_kernel<<<(N + 3) / 4, 256, 0, stream>>>(h1b, (const float4*)as1, (const float4*)ad1,
                                                      ofs, esrc, b1, ho1b, N);

    // Layer 2: h2 = ho1 @ W2 (M=N, N=256, K=512); att2 fused (atomic partials)
    bgemm_kernel<2><<<dim3(256 / 128, (N + 63) / 64), 256, 0, stream>>>(
        ho1b, W2t, h2b, att_src2, att_dst2, as2, ad2, N, 256, 512);
    edge_agg2_kernel<<<(N + 3) / 4, 256, 0, stream>>>(h2b, as2, ad2, ofs, esrc, b2, ho2b, N);

    // Pool stage 1 + fused (pool stage 2 + head)
    pool1_kernel<<<dim3(NGRAPH, PCHUNK), 256, 0, stream>>>(ho2b, batch, N, ppart);
    head_kernel<<<NGRAPH, 64, 0, stream>>>(ppart, fc1w, fc1b, fc2w, fc2b, (float*)d_out);
}

// Round 12
// 259.772 us; speedup vs baseline: 1.4905x; 1.0349x over previous
//
#include <hip/hip_runtime.h>
#include <math.h>

// Problem constants (reference: N=20000, E=160000, F=128, H=4, C1=128, C2=256, G=64, NCLS=10)
#define FDIM 128
#define HEADS 4
#define C1DIM 128
#define C2DIM 256
#define NGRAPH 64
#define NCLS 10
#define PCHUNK 8

typedef __attribute__((ext_vector_type(8))) short short8;   // 8 bf16 (4 VGPRs)
typedef __attribute__((ext_vector_type(4))) float float4v;  // 4 fp32 acc

__device__ __forceinline__ unsigned short f2bf(float f) {
    unsigned u = __builtin_bit_cast(unsigned, f);
    unsigned r = (u + 0x7FFFu + ((u >> 16) & 1u)) >> 16;   // RNE
    return (unsigned short)r;
}
__device__ __forceinline__ float bflo(int u) { return __builtin_bit_cast(float, (unsigned)u << 16); }
__device__ __forceinline__ float bfhi(int u) { return __builtin_bit_cast(float, (unsigned)u & 0xffff0000u); }
__device__ __forceinline__ float bfu(unsigned short u) { return __builtin_bit_cast(float, (unsigned)u << 16); }
__device__ __forceinline__ float lrelu(float x) { return x > 0.f ? x : 0.2f * x; }
__device__ __forceinline__ float sel4(float a, float b, float c, float d, int hd) {
    return hd == 0 ? a : hd == 1 ? b : hd == 2 ? c : d;
}

// ---------------- fused prep: zero scratch + cvt(x) + tconv(W1) + tconv(W2) ----------------
// Horizontal fusion of all launch-independent prep into one kernel (fewer graph nodes).
// Block ranges: [0,ZB) zero | [ZB,ZB+CB) cvt | [..+64) tconv W1 | [..+128) tconv W2.
__global__ __launch_bounds__(256) void prep_kernel(
        int* __restrict__ zero_base, int nzero_words,            // cursor+as2+ad2
        const float* __restrict__ x, unsigned short* __restrict__ xb, int n4,
        const float* __restrict__ W1, unsigned short* __restrict__ W1t,
        const float* __restrict__ W2, unsigned short* __restrict__ W2t,
        int ZB, int CB) {
    __shared__ float tile[32][33];
    int blk = blockIdx.x;
    if (blk < ZB) {
        int i = blk * 256 + threadIdx.x;
        if (i < nzero_words) zero_base[i] = 0;
        return;
    }
    blk -= ZB;
    if (blk < CB) {
        int i = blk * 256 + threadIdx.x;
        if (i < n4) {
            float4 v = ((const float4*)x)[i];
            ushort4 o;
            o.x = f2bf(v.x); o.y = f2bf(v.y); o.z = f2bf(v.z); o.w = f2bf(v.w);
            ((ushort4*)xb)[i] = o;
        }
        return;
    }
    blk -= CB;
    // transpose-convert: W[K,Nc] -> Wt[Nc,K]
    const float* W; unsigned short* Wt; int K, Nc, bx, by;
    if (blk < 64) {            // W1: K=128, N=512 -> grid 16 x 4
        W = W1; Wt = W1t; K = 128; Nc = 512;
        bx = (blk & 15) * 32; by = (blk >> 4) * 32;
    } else {                   // W2: K=512, N=256 -> grid 8 x 16
        blk -= 64;
        W = W2; Wt = W2t; K = 512; Nc = 256;
        bx = (blk & 7) * 32; by = (blk >> 3) * 32;
    }
    int tx = threadIdx.x & 31, ty = threadIdx.x >> 5;
    #pragma unroll
    for (int r = 0; r < 32; r += 8)
        tile[ty + r][tx] = W[(size_t)(by + ty + r) * Nc + bx + tx];
    __syncthreads();
    #pragma unroll
    for (int r = 0; r < 32; r += 8)
        Wt[(size_t)(bx + ty + r) * K + by + tx] = f2bf(tile[tx][ty + r]);
}

// ---------------- CSR build ----------------
__global__ void hist_kernel(const int* __restrict__ ei, int E, int* __restrict__ counts) {
    int i = blockIdx.x * blockDim.x + threadIdx.x;
    if (i >= 2 * E) return;
    int dst = (i < E) ? ei[E + i] : ei[i - E];
    atomicAdd(&counts[dst], 1);
}

__global__ __launch_bounds__(1024) void scan_kernel(int* __restrict__ counts_cursor,
                                                    int* __restrict__ ofs, int N) {
    __shared__ int part[1024];
    int t = threadIdx.x;
    int chunk = (N + 1023) / 1024;
    int b = t * chunk;
    int e = b + chunk; if (e > N) e = N;
    int s = 0;
    int i = b;
    if ((chunk & 3) == 0) {
        for (; i + 4 <= e; i += 4) {
            int4 v = *(const int4*)&counts_cursor[i];
            s += v.x + v.y + v.z + v.w;
        }
    }
    for (; i < e; ++i) s += counts_cursor[i];
    part[t] = s;
    __syncthreads();
    for (int o = 1; o < 1024; o <<= 1) {
        int v = (t >= o) ? part[t - o] : 0;
        __syncthreads();
        part[t] += v;
        __syncthreads();
    }
    int run = part[t] - s;
    i = b;
    if ((chunk & 3) == 0) {
        for (; i + 4 <= e; i += 4) {
            int4 c = *(const int4*)&counts_cursor[i];
            int4 o4;
            o4.x = run; run += c.x;
            o4.y = run; run += c.y;
            o4.z = run; run += c.z;
            o4.w = run; run += c.w;
            *(int4*)&ofs[i] = o4;
            counts_cursor[i]     = o4.x;
            counts_cursor[i + 1] = o4.y;
            counts_cursor[i + 2] = o4.z;
            counts_cursor[i + 3] = o4.w;
        }
    }
    for (; i < e; ++i) {
        int c = counts_cursor[i];
        ofs[i] = run;
        counts_cursor[i] = run;
        run += c;
    }
    if (t == 1023) ofs[N] = part[1023];
}

__global__ void scatter_kernel(const int* __restrict__ ei, int E,
                               int* __restrict__ cursor, int* __restrict__ esrc) {
    int i = blockIdx.x * blockDim.x + threadIdx.x;
    if (i >= 2 * E) return;
    int src = ei[i];
    int dst = (i < E) ? ei[E + i] : ei[i - E];
    int pos = atomicAdd(&cursor[dst], 1);
    esrc[pos] = src;
}

// ---------------- bf16 MFMA GEMM (64x128 tile) + fused attention epilogue ----------------
template<int MODE>
__global__ __launch_bounds__(256) void bgemm_kernel(
        const unsigned short* __restrict__ A,   // [M,K] bf16
        const unsigned short* __restrict__ Bt,  // [N,K] bf16
        unsigned short* __restrict__ C,         // [M,N] bf16
        const float* __restrict__ att_src,      // [N_] fp32
        const float* __restrict__ att_dst,      // [N_] fp32
        float* __restrict__ as_out,
        float* __restrict__ ad_out,
        int M, int N_, int K) {
    __shared__ unsigned short As[64 * 32];       // 4 KB
    __shared__ unsigned short Bs[128 * 32];      // 8 KB
    __shared__ unsigned short Cs[64 * 136];      // 17 KB, +8 pad
    __shared__ float sd_s[4][32];
    __shared__ float sd_d[4][32];
    const int t = threadIdx.x;
    const int lane = t & 63;
    const int wave = t >> 6;
    const int row0 = blockIdx.y * 64, col0 = blockIdx.x * 128;
    const int wr = (wave >> 1) * 32, wc = (wave & 1) * 64;
    float4v acc[2][4] = {};
    for (int k0 = 0; k0 < K; k0 += 32) {
        {
            int i = t;
            int gr = row0 + (i >> 2); if (gr >= M) gr = M - 1;
            const unsigned short* gp = A + (size_t)gr * K + k0 + ((i & 3) << 3);
            __builtin_amdgcn_global_load_lds(
                (const __attribute__((address_space(1))) unsigned int*)gp,
                (__attribute__((address_space(3))) unsigned int*)&As[i * 8], 16, 0, 0);
        }
        #pragma unroll
        for (int c = 0; c < 2; ++c) {
            int i = c * 256 + t;
            int gn = col0 + (i >> 2);
            const unsigned short* gp = Bt + (size_t)gn * K + k0 + ((i & 3) << 3);
            __builtin_amdgcn_global_load_lds(
                (const __attribute__((address_space(1))) unsigned int*)gp,
                (__attribute__((address_space(3))) unsigned int*)&Bs[i * 8], 16, 0, 0);
        }
        __syncthreads();
        short8 af[2], bfr[4];
        #pragma unroll
        for (int i = 0; i < 2; ++i)
            af[i] = *(const short8*)&As[(wr + i * 16 + (lane & 15)) * 32 + (lane >> 4) * 8];
        #pragma unroll
        for (int j = 0; j < 4; ++j)
            bfr[j] = *(const short8*)&Bs[(wc + j * 16 + (lane & 15)) * 32 + (lane >> 4) * 8];
        #pragma unroll
        for (int i = 0; i < 2; ++i)
            #pragma unroll
            for (int j = 0; j < 4; ++j)
                acc[i][j] = __builtin_amdgcn_mfma_f32_16x16x32_bf16(af[i], bfr[j], acc[i][j], 0, 0, 0);
        __syncthreads();
    }
    float asv[4], adv[4];
    #pragma unroll
    for (int j = 0; j < 4; ++j) {
        int cc = col0 + wc + j * 16 + (lane & 15);
        asv[j] = att_src[cc];
        adv[j] = att_dst[cc];
    }
    #pragma unroll
    for (int i = 0; i < 2; ++i) {
        #pragma unroll
        for (int p = 0; p < 4; ++p) {
            int rr = wr + i * 16 + (lane >> 4) * 4 + p;
            #pragma unroll
            for (int j = 0; j < 4; ++j)
                Cs[rr * 136 + wc + j * 16 + (lane & 15)] = f2bf(acc[i][j][p]);
            float s = acc[i][0][p] * asv[0] + acc[i][1][p] * asv[1]
                    + acc[i][2][p] * asv[2] + acc[i][3][p] * asv[3];
            float d = acc[i][0][p] * adv[0] + acc[i][1][p] * adv[1]
                    + acc[i][2][p] * adv[2] + acc[i][3][p] * adv[3];
            #pragma unroll
            for (int o = 1; o <= 8; o <<= 1) { s += __shfl_xor(s, o); d += __shfl_xor(d, o); }
            if ((lane & 15) == 0) {
                int ridx = i * 16 + (lane >> 4) * 4 + p;
                sd_s[wave][ridx] = s;
                sd_d[wave][ridx] = d;
            }
        }
    }
    __syncthreads();
    #pragma unroll
    for (int it = 0; it < 4; ++it) {
        int idx = it * 256 + t;
        int row = idx >> 4, c8 = (idx & 15) * 8;
        int gr = row0 + row;
        if (gr < M)
            *(int4*)&C[(size_t)gr * N_ + col0 + c8] = *(const int4*)&Cs[row * 136 + c8];
    }
    if ((wave & 1) == 0 && lane < 32) {
        float s = sd_s[wave][lane] + sd_s[wave + 1][lane];
        float d = sd_d[wave][lane] + sd_d[wave + 1][lane];
        int r = row0 + wr + lane;
        if (r < M) {
            if (MODE == 1) {
                as_out[r * 4 + blockIdx.x] = s;
                ad_out[r * 4 + blockIdx.x] = d;
            } else {
                atomicAdd(&as_out[r], s);
                atomicAdd(&ad_out[r], d);
            }
        }
    }
}

// ---------------- edge aggregate (R9 unroll-4 form — measured 48.5 us, structural) ----------
__global__ __launch_bounds__(256) void edge_agg1_kernel(
        const unsigned short* __restrict__ h1b,   // [N,512] bf16
        const float4* __restrict__ as14,
        const float4* __restrict__ ad14,
        const int* __restrict__ ofs,
        const int* __restrict__ esrc,
        const float* __restrict__ b1,
        unsigned short* __restrict__ ho1b, int N) {
    int wave = threadIdx.x >> 6, lane = threadIdx.x & 63;
    int node = blockIdx.x * 4 + wave;
    if (node >= N) return;
    int beg = ofs[node], end = ofs[node + 1];
    float4 asn = as14[node], adn = ad14[node];
    float w0 = __expf(lrelu(asn.x + adn.x));
    float w1 = __expf(lrelu(asn.y + adn.y));
    float w2 = __expf(lrelu(asn.z + adn.z));
    float w3 = __expf(lrelu(asn.w + adn.w));
    int hd = lane >> 4;
    int c0 = lane * 8;
    float wsh = sel4(w0, w1, w2, w3, hd);
    float acc[8];
    {
        int4 r = *(const int4*)&h1b[(size_t)node * 512 + c0];
        acc[0] = wsh * bflo(r.x); acc[1] = wsh * bfhi(r.x);
        acc[2] = wsh * bflo(r.y); acc[3] = wsh * bfhi(r.y);
        acc[4] = wsh * bflo(r.z); acc[5] = wsh * bfhi(r.z);
        acc[6] = wsh * bflo(r.w); acc[7] = wsh * bfhi(r.w);
    }
    float d0 = 0.f, d1 = 0.f, d2 = 0.f, d3 = 0.f;
    for (int cb = beg; cb < end; cb += 64) {
        int idx = cb + lane;
        int sl = esrc[idx < end ? idx : end - 1];
        float4 wl = make_float4(0.f, 0.f, 0.f, 0.f);
        if (idx < end) {
            float4 a = as14[sl];
            wl.x = __expf(lrelu(a.x + adn.x));
            wl.y = __expf(lrelu(a.y + adn.y));
            wl.z = __expf(lrelu(a.z + adn.z));
            wl.w = __expf(lrelu(a.w + adn.w));
            d0 += wl.x; d1 += wl.y; d2 += wl.z; d3 += wl.w;
        }
        int jmax = end - cb; if (jmax > 64) jmax = 64;
        int j = 0;
        for (; j + 4 <= jmax; j += 4) {
            int s0 = __shfl(sl, j), s1 = __shfl(sl, j + 1);
            int s2 = __shfl(sl, j + 2), s3 = __shfl(sl, j + 3);
            float u0 = sel4(__shfl(wl.x, j), __shfl(wl.y, j), __shfl(wl.z, j), __shfl(wl.w, j), hd);
            float u1 = sel4(__shfl(wl.x, j + 1), __shfl(wl.y, j + 1), __shfl(wl.z, j + 1), __shfl(wl.w, j + 1), hd);
            float u2 = sel4(__shfl(wl.x, j + 2), __shfl(wl.y, j + 2), __shfl(wl.z, j + 2), __shfl(wl.w, j + 2), hd);
            float u3 = sel4(__shfl(wl.x, j + 3), __shfl(wl.y, j + 3), __shfl(wl.z, j + 3), __shfl(wl.w, j + 3), hd);
            int4 r0 = *(const int4*)&h1b[(size_t)s0 * 512 + c0];
            int4 r1 = *(const int4*)&h1b[(size_t)s1 * 512 + c0];
            int4 r2 = *(const int4*)&h1b[(size_t)s2 * 512 + c0];
            int4 r3 = *(const int4*)&h1b[(size_t)s3 * 512 + c0];
            acc[0] += u0 * bflo(r0.x); acc[1] += u0 * bfhi(r0.x);
            acc[2] += u0 * bflo(r0.y); acc[3] += u0 * bfhi(r0.y);
            acc[4] += u0 * bflo(r0.z); acc[5] += u0 * bfhi(r0.z);
            acc[6] += u0 * bflo(r0.w); acc[7] += u0 * bfhi(r0.w);
            acc[0] += u1 * bflo(r1.x); acc[1] += u1 * bfhi(r1.x);
            acc[2] += u1 * bflo(r1.y); acc[3] += u1 * bfhi(r1.y);
            acc[4] += u1 * bflo(r1.z); acc[5] += u1 * bfhi(r1.z);
            acc[6] += u1 * bflo(r1.w); acc[7] += u1 * bfhi(r1.w);
            acc[0] += u2 * bflo(r2.x); acc[1] += u2 * bfhi(r2.x);
            acc[2] += u2 * bflo(r2.y); acc[3] += u2 * bfhi(r2.y);
            acc[4] += u2 * bflo(r2.z); acc[5] += u2 * bfhi(r2.z);
            acc[6] += u2 * bflo(r2.w); acc[7] += u2 * bfhi(r2.w);
            acc[0] += u3 * bflo(r3.x); acc[1] += u3 * bfhi(r3.x);
            acc[2] += u3 * bflo(r3.y); acc[3] += u3 * bfhi(r3.y);
            acc[4] += u3 * bflo(r3.z); acc[5] += u3 * bfhi(r3.z);
            acc[6] += u3 * bflo(r3.w); acc[7] += u3 * bfhi(r3.w);
        }
        for (; j < jmax; ++j) {
            int s = __shfl(sl, j);
            float u = sel4(__shfl(wl.x, j), __shfl(wl.y, j), __shfl(wl.z, j), __shfl(wl.w, j), hd);
            int4 r = *(const int4*)&h1b[(size_t)s * 512 + c0];
            acc[0] += u * bflo(r.x); acc[1] += u * bfhi(r.x);
            acc[2] += u * bflo(r.y); acc[3] += u * bfhi(r.y);
            acc[4] += u * bflo(r.z); acc[5] += u * bfhi(r.z);
            acc[6] += u * bflo(r.w); acc[7] += u * bfhi(r.w);
        }
    }
    #pragma unroll
    for (int o = 32; o > 0; o >>= 1) {
        d0 += __shfl_xor(d0, o); d1 += __shfl_xor(d1, o);
        d2 += __shfl_xor(d2, o); d3 += __shfl_xor(d3, o);
    }
    d0 += w0; d1 += w1; d2 += w2; d3 += w3;
    float dh = sel4(d0, d1, d2, d3, hd);
    float inv = 1.f / dh;
    float4 bA = *(const float4*)&b1[c0], bB = *(const float4*)&b1[c0 + 4];
    float v0 = fmaxf(acc[0] * inv + bA.x, 0.f), v1 = fmaxf(acc[1] * inv + bA.y, 0.f);
    float v2 = fmaxf(acc[2] * inv + bA.z, 0.f), v3 = fmaxf(acc[3] * inv + bA.w, 0.f);
    float v4 = fmaxf(acc[4] * inv + bB.x, 0.f), v5 = fmaxf(acc[5] * inv + bB.y, 0.f);
    float v6 = fmaxf(acc[6] * inv + bB.z, 0.f), v7 = fmaxf(acc[7] * inv + bB.w, 0.f);
    int4 o;
    o.x = (int)((unsigned)f2bf(v0) | ((unsigned)f2bf(v1) << 16));
    o.y = (int)((unsigned)f2bf(v2) | ((unsigned)f2bf(v3) << 16));
    o.z = (int)((unsigned)f2bf(v4) | ((unsigned)f2bf(v5) << 16));
    o.w = (int)((unsigned)f2bf(v6) | ((unsigned)f2bf(v7) << 16));
    *(int4*)&ho1b[(size_t)node * 512 + c0] = o;
}

// Layer 2: unroll-8 (int2 gathers — mild VGPR cost; part of R11's win).
__global__ __launch_bounds__(256) void edge_agg2_kernel(
        const unsigned short* __restrict__ h2b,   // [N,256] bf16
        const float* __restrict__ as2,
        const float* __restrict__ ad2,
        const int* __restrict__ ofs,
        const int* __restrict__ esrc,
        const float* __restrict__ b2,
        unsigned short* __restrict__ ho2b, int N) {
    int wave = threadIdx.x >> 6, lane = threadIdx.x & 63;
    int node = blockIdx.x * 4 + wave;
    if (node >= N) return;
    int beg = ofs[node], end = ofs[node + 1];
    float adn = ad2[node];
    float wself = __expf(lrelu(as2[node] + adn));
    int c0 = lane * 4;
    float a0, a1, a2, a3;
    {
        int2 r = *(const int2*)&h2b[(size_t)node * 256 + c0];
        a0 = wself * bflo(r.x); a1 = wself * bfhi(r.x);
        a2 = wself * bflo(r.y); a3 = wself * bfhi(r.y);
    }
    float dsum = 0.f;
    for (int cb = beg; cb < end; cb += 64) {
        int idx = cb + lane;
        int sl = esrc[idx < end ? idx : end - 1];
        float wl = 0.f;
        if (idx < end) {
            wl = __expf(lrelu(as2[sl] + adn));
            dsum += wl;
        }
        int jmax = end - cb; if (jmax > 64) jmax = 64;
        int j = 0;
        for (; j + 8 <= jmax; j += 8) {
            int ss[8]; float u[8]; int2 r[8];
            #pragma unroll
            for (int q = 0; q < 8; ++q) {
                ss[q] = __shfl(sl, j + q);
                u[q] = __shfl(wl, j + q);
            }
            #pragma unroll
            for (int q = 0; q < 8; ++q) r[q] = *(const int2*)&h2b[(size_t)ss[q] * 256 + c0];
            #pragma unroll
            for (int q = 0; q < 8; ++q) {
                a0 += u[q] * bflo(r[q].x); a1 += u[q] * bfhi(r[q].x);
                a2 += u[q] * bflo(r[q].y); a3 += u[q] * bfhi(r[q].y);
            }
        }
        for (; j < jmax; ++j) {
            int s = __shfl(sl, j);
            float u = __shfl(wl, j);
            int2 r = *(const int2*)&h2b[(size_t)s * 256 + c0];
            a0 += u * bflo(r.x); a1 += u * bfhi(r.x);
            a2 += u * bflo(r.y); a3 += u * bfhi(r.y);
        }
    }
    #pragma unroll
    for (int o = 32; o > 0; o >>= 1) dsum += __shfl_xor(dsum, o);
    dsum += wself;
    float inv = 1.f / dsum;
    float4 bv = *(const float4*)&b2[c0];
    float v0 = a0 * inv + bv.x, v1 = a1 * inv + bv.y;
    float v2 = a2 * inv + bv.z, v3 = a3 * inv + bv.w;
    int2 o;
    o.x = (int)((unsigned)f2bf(v0) | ((unsigned)f2bf(v1) << 16));
    o.y = (int)((unsigned)f2bf(v2) | ((unsigned)f2bf(v3) << 16));
    *(int2*)&ho2b[(size_t)node * 256 + c0] = o;
}

// ---------------- global max pool, stage 1 (batch is sorted; bf16 input) ----------------
__global__ __launch_bounds__(256) void pool1_kernel(const unsigned short* __restrict__ ho2b,
                                                    const int* __restrict__ batch,
                                                    int N, float* __restrict__ part) {
    int g = blockIdx.x, c = blockIdx.y, t = threadIdx.x;
    int lo = 0, hi = N;
    while (lo < hi) { int mid = (lo + hi) >> 1; if (batch[mid] < g) lo = mid + 1; else hi = mid; }
    int start = lo;
    lo = 0; hi = N;
    while (lo < hi) { int mid = (lo + hi) >> 1; if (batch[mid] < g + 1) lo = mid + 1; else hi = mid; }
    int end = lo;
    int len = end - start;
    int cb = start + (int)(((long long)len * c) / PCHUNK);
    int ce = start + (int)(((long long)len * (c + 1)) / PCHUNK);
    float m = -INFINITY;
    for (int n = cb; n < ce; ++n) m = fmaxf(m, bfu(ho2b[(size_t)n * 256 + t]));
    part[((size_t)g * PCHUNK + c) * 256 + t] = m;
}

// ---------------- FC head (+pool stage 2) + log_softmax ----------------
__global__ __launch_bounds__(64) void head_kernel(const float* __restrict__ part,
                                                  const float* __restrict__ fc1w,
                                                  const float* __restrict__ fc1b,
                                                  const float* __restrict__ fc2w,
                                                  const float* __restrict__ fc2b,
                                                  float* __restrict__ out) {
    __shared__ float gr[256];
    __shared__ float hid[64];
    __shared__ float o10[NCLS];
    int g = blockIdx.x, t = threadIdx.x;
    for (int i = t; i < 256; i += 64) {
        float m = -INFINITY;
        #pragma unroll
        for (int c = 0; c < PCHUNK; ++c)
            m = fmaxf(m, part[((size_t)g * PCHUNK + c) * 256 + i]);
        gr[i] = m;
    }
    __syncthreads();
    float s = fc1b[t];
    for (int k = 0; k < 256; ++k) s += gr[k] * fc1w[k * 64 + t];
    hid[t] = s > 0.f ? s : 0.f;
    __syncthreads();
    if (t < NCLS) {
        float s2 = fc2b[t];
        for (int k = 0; k < 64; ++k) s2 += hid[k] * fc2w[k * NCLS + t];
        o10[t] = s2;
    }
    __syncthreads();
    if (t == 0) {
        float mx = -INFINITY;
        for (int c = 0; c < NCLS; ++c) mx = fmaxf(mx, o10[c]);
        float se = 0.f;
        for (int c = 0; c < NCLS; ++c) se += __expf(o10[c] - mx);
        float lse = mx + logf(se);
        for (int c = 0; c < NCLS; ++c) out[g * NCLS + c] = o10[c] - lse;
    }
}

extern "C" void kernel_launch(void* const* d_in, const int* in_sizes, int n_in,
                              void* d_out, int out_size, void* d_ws, size_t ws_size,
                              hipStream_t stream) {
    (void)n_in; (void)out_size; (void)ws_size;
    const float* x        = (const float*)d_in[0];
    const int*   ei       = (const int*)d_in[1];
    const int*   batch    = (const int*)d_in[2];
    const float* W1       = (const float*)d_in[3];
    const float* att_src1 = (const float*)d_in[4];
    const float* att_dst1 = (const float*)d_in[5];
    const float* b1       = (const float*)d_in[6];
    const float* W2       = (const float*)d_in[7];
    const float* att_src2 = (const float*)d_in[8];
    const float* att_dst2 = (const float*)d_in[9];
    const float* b2       = (const float*)d_in[10];
    const float* fc1w     = (const float*)d_in[11];
    const float* fc1b     = (const float*)d_in[12];
    const float* fc2w     = (const float*)d_in[13];
    const float* fc2b     = (const float*)d_in[14];

    const int N = in_sizes[2];
    const int E = in_sizes[1] / 2;
    const int tot = 2 * E;

    char* base = (char*)d_ws;
    size_t off = 0;
    auto alloc = [&](size_t bytes) -> void* {
        void* p = base + off;
        off = (off + bytes + 255) & ~(size_t)255;
        return p;
    };
    int*   ofs    = (int*)alloc((size_t)(N + 1) * 4);
    int*   cursor = (int*)alloc((size_t)N * 4);    // cursor, as2, ad2 zeroed by prep
    float* as2    = (float*)alloc((size_t)N * 4);
    float* ad2    = (float*)alloc((size_t)N * 4);
    int*   esrc   = (int*)alloc((size_t)tot * 4);
    float* as1    = (float*)alloc((size_t)N * HEADS * 4);
    float* ad1    = (float*)alloc((size_t)N * HEADS * 4);
    unsigned short* xb   = (unsigned short*)alloc((size_t)N * FDIM * 2);
    unsigned short* W1t  = (unsigned short*)alloc((size_t)512 * 128 * 2);
    unsigned short* W2t  = (unsigned short*)alloc((size_t)256 * 512 * 2);
    unsigned short* h1b  = (unsigned short*)alloc((size_t)N * 512 * 2);
    unsigned short* ho1b = (unsigned short*)alloc((size_t)N * 512 * 2);
    unsigned short* h2b  = (unsigned short*)alloc((size_t)N * 256 * 2);
    unsigned short* ho2b = (unsigned short*)alloc((size_t)N * 256 * 2);
    float* ppart  = (float*)alloc((size_t)NGRAPH * PCHUNK * 256 * 4);

    // fused prep: zero (cursor..ad2) + cvt(x) + tconv(W1) + tconv(W2)
    int nzero = (int)(((size_t)((char*)ad2 - (char*)cursor) + (size_t)N * 4) / 4);
    int ZB = (nzero + 255) / 256;
    int n4 = N * FDIM / 4;
    int CB = (n4 + 255) / 256;
    prep_kernel<<<ZB + CB + 64 + 128, 256, 0, stream>>>(
        cursor, nzero, x, xb, n4, W1, W1t, W2, W2t, ZB, CB);

    // CSR build
    hist_kernel<<<(tot + 255) / 256, 256, 0, stream>>>(ei, E, cursor);
    scan_kernel<<<1, 1024, 0, stream>>>(cursor, ofs, N);
    scatter_kernel<<<(tot + 255) / 256, 256, 0, stream>>>(ei, E, cursor, esrc);

    // Layer 1: h1 = x @ W1 (M=N, N=512, K=128); att1 fused into epilogue
    bgemm_kernel<1><<<dim3(512 / 128, (N + 63) / 64), 256, 0, stream>>>(
        xb, W1t, h1b, att_src1, att_dst1, as1, ad1, N, 512, 128);
    edge_agg1_kernel<<<(N + 3) / 4, 256, 0, stream>>>(h1b, (const float4*)as1, (const float4*)ad1,
                                                      ofs, esrc, b1, ho1b, N);

    // Layer 2: h2 = ho1 @ W2 (M=N, N=256, K=512); att2 fused (atomic partials)
    bgemm_kernel<2><<<dim3(256 / 128, (N + 63) / 64), 256, 0, stream>>>(
        ho1b, W2t, h2b, att_src2, att_dst2, as2, ad2, N, 256, 512);
    edge_agg2_kernel<<<(N + 3) / 4, 256, 0, stream>>>(h2b, as2, ad2, ofs, esrc, b2, ho2b, N);

    // Pool stage 1 + fused (pool stage 2 + head)
    pool1_kernel<<<dim3(NGRAPH, PCHUNK), 256, 0, stream>>>(ho2b, batch, N, ppart);
    head_kernel<<<NGRAPH, 64, 0, stream>>>(ppart, fc1w, fc1b, fc2w, fc2b, (float*)d_out);
}

// Round 13
// 245.459 us; speedup vs baseline: 1.5775x; 1.0583x over previous
//
#include <hip/hip_runtime.h>
#include <math.h>

// Problem constants (reference: N=20000, E=160000, F=128, H=4, C1=128, C2=256, G=64, NCLS=10)
#define FDIM 128
#define HEADS 4
#define C1DIM 128
#define C2DIM 256
#define NGRAPH 64
#define NCLS 10
#define PCHUNK 8

typedef __attribute__((ext_vector_type(8))) short short8;   // 8 bf16 (4 VGPRs)
typedef __attribute__((ext_vector_type(4))) float float4v;  // 4 fp32 acc
typedef __attribute__((ext_vector_type(2))) float floatx2;

__device__ __forceinline__ unsigned short f2bf(float f) {
    unsigned u = __builtin_bit_cast(unsigned, f);
    unsigned r = (u + 0x7FFFu + ((u >> 16) & 1u)) >> 16;   // RNE
    return (unsigned short)r;
}
__device__ __forceinline__ float bflo(int u) { return __builtin_bit_cast(float, (unsigned)u << 16); }
__device__ __forceinline__ float bfhi(int u) { return __builtin_bit_cast(float, (unsigned)u & 0xffff0000u); }
__device__ __forceinline__ float bfu(unsigned short u) { return __builtin_bit_cast(float, (unsigned)u << 16); }
__device__ __forceinline__ float lrelu(float x) { return x > 0.f ? x : 0.2f * x; }
__device__ __forceinline__ float sel4(float a, float b, float c, float d, int hd) {
    return hd == 0 ? a : hd == 1 ? b : hd == 2 ? c : d;
}
// fp8 e4m3 (OCP) encode/decode via gfx950 HW converts
__device__ __forceinline__ unsigned char f2fp8(float f) {
    return (unsigned char)(__builtin_amdgcn_cvt_pk_fp8_f32(f, f, 0, false) & 0xff);
}
__device__ __forceinline__ void fp8x8_dec(int2 r, float* f) {
    floatx2 p0 = __builtin_amdgcn_cvt_pk_f32_fp8(r.x, false);
    floatx2 p1 = __builtin_amdgcn_cvt_pk_f32_fp8(r.x, true);
    floatx2 p2 = __builtin_amdgcn_cvt_pk_f32_fp8(r.y, false);
    floatx2 p3 = __builtin_amdgcn_cvt_pk_f32_fp8(r.y, true);
    f[0] = p0.x; f[1] = p0.y; f[2] = p1.x; f[3] = p1.y;
    f[4] = p2.x; f[5] = p2.y; f[6] = p3.x; f[7] = p3.y;
}

// ---------------- fused prep: zero scratch + cvt(x) + tconv(W1) + tconv(W2) ----------------
__global__ __launch_bounds__(256) void prep_kernel(
        int* __restrict__ zero_base, int nzero_words,
        const float* __restrict__ x, unsigned short* __restrict__ xb, int n4,
        const float* __restrict__ W1, unsigned short* __restrict__ W1t,
        const float* __restrict__ W2, unsigned short* __restrict__ W2t,
        int ZB, int CB) {
    __shared__ float tile[32][33];
    int blk = blockIdx.x;
    if (blk < ZB) {
        int i = blk * 256 + threadIdx.x;
        if (i < nzero_words) zero_base[i] = 0;
        return;
    }
    blk -= ZB;
    if (blk < CB) {
        int i = blk * 256 + threadIdx.x;
        if (i < n4) {
            float4 v = ((const float4*)x)[i];
            ushort4 o;
            o.x = f2bf(v.x); o.y = f2bf(v.y); o.z = f2bf(v.z); o.w = f2bf(v.w);
            ((ushort4*)xb)[i] = o;
        }
        return;
    }
    blk -= CB;
    const float* W; unsigned short* Wt; int K, Nc, bx, by;
    if (blk < 64) {            // W1: K=128, N=512 -> 16 x 4
        W = W1; Wt = W1t; K = 128; Nc = 512;
        bx = (blk & 15) * 32; by = (blk >> 4) * 32;
    } else {                   // W2: K=512, N=256 -> 8 x 16
        blk -= 64;
        W = W2; Wt = W2t; K = 512; Nc = 256;
        bx = (blk & 7) * 32; by = (blk >> 3) * 32;
    }
    int tx = threadIdx.x & 31, ty = threadIdx.x >> 5;
    #pragma unroll
    for (int r = 0; r < 32; r += 8)
        tile[ty + r][tx] = W[(size_t)(by + ty + r) * Nc + bx + tx];
    __syncthreads();
    #pragma unroll
    for (int r = 0; r < 32; r += 8)
        Wt[(size_t)(bx + ty + r) * K + by + tx] = f2bf(tile[tx][ty + r]);
}

// ---------------- CSR build ----------------
__global__ void hist_kernel(const int* __restrict__ ei, int E, int* __restrict__ counts) {
    int i = blockIdx.x * blockDim.x + threadIdx.x;
    if (i >= 2 * E) return;
    int dst = (i < E) ? ei[E + i] : ei[i - E];
    atomicAdd(&counts[dst], 1);
}

__global__ __launch_bounds__(1024) void scan_kernel(int* __restrict__ counts_cursor,
                                                    int* __restrict__ ofs, int N) {
    __shared__ int part[1024];
    int t = threadIdx.x;
    int chunk = (N + 1023) / 1024;
    int b = t * chunk;
    int e = b + chunk; if (e > N) e = N;
    int s = 0;
    int i = b;
    if ((chunk & 3) == 0) {
        for (; i + 4 <= e; i += 4) {
            int4 v = *(const int4*)&counts_cursor[i];
            s += v.x + v.y + v.z + v.w;
        }
    }
    for (; i < e; ++i) s += counts_cursor[i];
    part[t] = s;
    __syncthreads();
    for (int o = 1; o < 1024; o <<= 1) {
        int v = (t >= o) ? part[t - o] : 0;
        __syncthreads();
        part[t] += v;
        __syncthreads();
    }
    int run = part[t] - s;
    i = b;
    if ((chunk & 3) == 0) {
        for (; i + 4 <= e; i += 4) {
            int4 c = *(const int4*)&counts_cursor[i];
            int4 o4;
            o4.x = run; run += c.x;
            o4.y = run; run += c.y;
            o4.z = run; run += c.z;
            o4.w = run; run += c.w;
            *(int4*)&ofs[i] = o4;
            counts_cursor[i]     = o4.x;
            counts_cursor[i + 1] = o4.y;
            counts_cursor[i + 2] = o4.z;
            counts_cursor[i + 3] = o4.w;
        }
    }
    for (; i < e; ++i) {
        int c = counts_cursor[i];
        ofs[i] = run;
        counts_cursor[i] = run;
        run += c;
    }
    if (t == 1023) ofs[N] = part[1023];
}

__global__ void scatter_kernel(const int* __restrict__ ei, int E,
                               int* __restrict__ cursor, int* __restrict__ esrc) {
    int i = blockIdx.x * blockDim.x + threadIdx.x;
    if (i >= 2 * E) return;
    int src = ei[i];
    int dst = (i < E) ? ei[E + i] : ei[i - E];
    int pos = atomicAdd(&cursor[dst], 1);
    esrc[pos] = src;
}

// ---------------- bf16 MFMA GEMM (64x128 tile) + fused attention epilogue ----------------
// MODE 1: C out = fp8 e4m3 [M,512] (consumed only by edge_agg1 gathers); att direct write.
// MODE 2: C out = bf16 [M,256]; att atomicAdd partials (pre-zeroed).
// Cs (epilogue staging) aliases As/Bs — safe: K-loop ends with __syncthreads.
template<int MODE>
__global__ __launch_bounds__(256) void bgemm_kernel(
        const unsigned short* __restrict__ A,   // [M,K] bf16
        const unsigned short* __restrict__ Bt,  // [N,K] bf16
        void* __restrict__ Cout,
        const float* __restrict__ att_src,
        const float* __restrict__ att_dst,
        float* __restrict__ as_out,
        float* __restrict__ ad_out,
        int M, int N_, int K) {
    constexpr int CPADB = (MODE == 1) ? 144 : 272;           // Cs row stride (bytes)
    constexpr int CSB = 64 * CPADB;
    constexpr int SMEMSZ = (CSB > 12288) ? CSB : 12288;
    __shared__ __align__(16) unsigned char smem[SMEMSZ];
    unsigned short* As = (unsigned short*)smem;              // 4 KB
    unsigned short* Bs = (unsigned short*)(smem + 4096);     // 8 KB
    __shared__ float sd_s[4][32];
    __shared__ float sd_d[4][32];
    const int t = threadIdx.x;
    const int lane = t & 63;
    const int wave = t >> 6;
    const int row0 = blockIdx.y * 64, col0 = blockIdx.x * 128;
    const int wr = (wave >> 1) * 32, wc = (wave & 1) * 64;
    float4v acc[2][4] = {};
    for (int k0 = 0; k0 < K; k0 += 32) {
        {
            int i = t;
            int gr = row0 + (i >> 2); if (gr >= M) gr = M - 1;
            const unsigned short* gp = A + (size_t)gr * K + k0 + ((i & 3) << 3);
            __builtin_amdgcn_global_load_lds(
                (const __attribute__((address_space(1))) unsigned int*)gp,
                (__attribute__((address_space(3))) unsigned int*)&As[i * 8], 16, 0, 0);
        }
        #pragma unroll
        for (int c = 0; c < 2; ++c) {
            int i = c * 256 + t;
            int gn = col0 + (i >> 2);
            const unsigned short* gp = Bt + (size_t)gn * K + k0 + ((i & 3) << 3);
            __builtin_amdgcn_global_load_lds(
                (const __attribute__((address_space(1))) unsigned int*)gp,
                (__attribute__((address_space(3))) unsigned int*)&Bs[i * 8], 16, 0, 0);
        }
        __syncthreads();
        short8 af[2], bfr[4];
        #pragma unroll
        for (int i = 0; i < 2; ++i)
            af[i] = *(const short8*)&As[(wr + i * 16 + (lane & 15)) * 32 + (lane >> 4) * 8];
        #pragma unroll
        for (int j = 0; j < 4; ++j)
            bfr[j] = *(const short8*)&Bs[(wc + j * 16 + (lane & 15)) * 32 + (lane >> 4) * 8];
        #pragma unroll
        for (int i = 0; i < 2; ++i)
            #pragma unroll
            for (int j = 0; j < 4; ++j)
                acc[i][j] = __builtin_amdgcn_mfma_f32_16x16x32_bf16(af[i], bfr[j], acc[i][j], 0, 0, 0);
        __syncthreads();
    }
    // epilogue: stage C into (aliased) LDS + attention row-dots
    float asv[4], adv[4];
    #pragma unroll
    for (int j = 0; j < 4; ++j) {
        int cc = col0 + wc + j * 16 + (lane & 15);
        asv[j] = att_src[cc];
        adv[j] = att_dst[cc];
    }
    #pragma unroll
    for (int i = 0; i < 2; ++i) {
        #pragma unroll
        for (int p = 0; p < 4; ++p) {
            int rr = wr + i * 16 + (lane >> 4) * 4 + p;
            if (MODE == 1) {
                unsigned char* Cs = smem;
                #pragma unroll
                for (int j = 0; j < 4; ++j)
                    Cs[rr * CPADB + wc + j * 16 + (lane & 15)] = f2fp8(acc[i][j][p]);
            } else {
                unsigned short* Cs = (unsigned short*)smem;
                #pragma unroll
                for (int j = 0; j < 4; ++j)
                    Cs[rr * (CPADB / 2) + wc + j * 16 + (lane & 15)] = f2bf(acc[i][j][p]);
            }
            float s = acc[i][0][p] * asv[0] + acc[i][1][p] * asv[1]
                    + acc[i][2][p] * asv[2] + acc[i][3][p] * asv[3];
            float d = acc[i][0][p] * adv[0] + acc[i][1][p] * adv[1]
                    + acc[i][2][p] * adv[2] + acc[i][3][p] * adv[3];
            #pragma unroll
            for (int o = 1; o <= 8; o <<= 1) { s += __shfl_xor(s, o); d += __shfl_xor(d, o); }
            if ((lane & 15) == 0) {
                int ridx = i * 16 + (lane >> 4) * 4 + p;
                sd_s[wave][ridx] = s;
                sd_d[wave][ridx] = d;
            }
        }
    }
    __syncthreads();
    // coalesced C store
    if (MODE == 1) {
        unsigned char* C8 = (unsigned char*)Cout;
        const unsigned char* Cs = smem;
        #pragma unroll
        for (int it = 0; it < 2; ++it) {           // 64 rows x 128 B = 512 int4
            int idx = it * 256 + t;
            int row = idx >> 3, c16 = (idx & 7) * 16;
            int gr = row0 + row;
            if (gr < M)
                *(int4*)&C8[(size_t)gr * N_ + col0 + c16] = *(const int4*)&Cs[row * CPADB + c16];
        }
    } else {
        unsigned short* C = (unsigned short*)Cout;
        const unsigned short* Cs = (const unsigned short*)smem;
        #pragma unroll
        for (int it = 0; it < 4; ++it) {           // 64 rows x 128 cols bf16 = 1024 int4
            int idx = it * 256 + t;
            int row = idx >> 4, c8 = (idx & 15) * 8;
            int gr = row0 + row;
            if (gr < M)
                *(int4*)&C[(size_t)gr * N_ + col0 + c8] = *(const int4*)&Cs[row * (CPADB / 2) + c8];
        }
    }
    if ((wave & 1) == 0 && lane < 32) {
        float s = sd_s[wave][lane] + sd_s[wave + 1][lane];
        float d = sd_d[wave][lane] + sd_d[wave + 1][lane];
        int r = row0 + wr + lane;
        if (r < M) {
            if (MODE == 1) {
                as_out[r * 4 + blockIdx.x] = s;
                ad_out[r * 4 + blockIdx.x] = d;
            } else {
                atomicAdd(&as_out[r], s);
                atomicAdd(&ad_out[r], d);
            }
        }
    }
}

// ---------------- edge aggregate L1: fp8 gathers (half the compulsory bytes) ------------
__global__ __launch_bounds__(256) void edge_agg1_kernel(
        const unsigned char* __restrict__ h1f8,   // [N,512] fp8 e4m3
        const float4* __restrict__ as14,
        const float4* __restrict__ ad14,
        const int* __restrict__ ofs,
        const int* __restrict__ esrc,
        const float* __restrict__ b1,
        unsigned short* __restrict__ ho1b, int N) {
    int wave = threadIdx.x >> 6, lane = threadIdx.x & 63;
    int node = blockIdx.x * 4 + wave;
    if (node >= N) return;
    int beg = ofs[node], end = ofs[node + 1];
    float4 asn = as14[node], adn = ad14[node];
    float w0 = __expf(lrelu(asn.x + adn.x));
    float w1 = __expf(lrelu(asn.y + adn.y));
    float w2 = __expf(lrelu(asn.z + adn.z));
    float w3 = __expf(lrelu(asn.w + adn.w));
    int hd = lane >> 4;
    int c0 = lane * 8;                      // channel == byte offset (fp8)
    float wsh = sel4(w0, w1, w2, w3, hd);
    float acc[8];
    {
        int2 rs = *(const int2*)&h1f8[(size_t)node * 512 + c0];
        float f[8]; fp8x8_dec(rs, f);
        #pragma unroll
        for (int k = 0; k < 8; ++k) acc[k] = wsh * f[k];
    }
    float d0 = 0.f, d1 = 0.f, d2 = 0.f, d3 = 0.f;
    for (int cb = beg; cb < end; cb += 64) {
        int idx = cb + lane;
        int sl = esrc[idx < end ? idx : end - 1];
        float4 wl = make_float4(0.f, 0.f, 0.f, 0.f);
        if (idx < end) {
            float4 a = as14[sl];
            wl.x = __expf(lrelu(a.x + adn.x));
            wl.y = __expf(lrelu(a.y + adn.y));
            wl.z = __expf(lrelu(a.z + adn.z));
            wl.w = __expf(lrelu(a.w + adn.w));
            d0 += wl.x; d1 += wl.y; d2 += wl.z; d3 += wl.w;
        }
        int jmax = end - cb; if (jmax > 64) jmax = 64;
        int j = 0;
        for (; j + 4 <= jmax; j += 4) {
            int s0 = __shfl(sl, j), s1 = __shfl(sl, j + 1);
            int s2 = __shfl(sl, j + 2), s3 = __shfl(sl, j + 3);
            float u0 = sel4(__shfl(wl.x, j), __shfl(wl.y, j), __shfl(wl.z, j), __shfl(wl.w, j), hd);
            float u1 = sel4(__shfl(wl.x, j + 1), __shfl(wl.y, j + 1), __shfl(wl.z, j + 1), __shfl(wl.w, j + 1), hd);
            float u2 = sel4(__shfl(wl.x, j + 2), __shfl(wl.y, j + 2), __shfl(wl.z, j + 2), __shfl(wl.w, j + 2), hd);
            float u3 = sel4(__shfl(wl.x, j + 3), __shfl(wl.y, j + 3), __shfl(wl.z, j + 3), __shfl(wl.w, j + 3), hd);
            int2 r0 = *(const int2*)&h1f8[(size_t)s0 * 512 + c0];
            int2 r1 = *(const int2*)&h1f8[(size_t)s1 * 512 + c0];
            int2 r2 = *(const int2*)&h1f8[(size_t)s2 * 512 + c0];
            int2 r3 = *(const int2*)&h1f8[(size_t)s3 * 512 + c0];
            float f0[8], f1[8], f2[8], f3[8];
            fp8x8_dec(r0, f0); fp8x8_dec(r1, f1); fp8x8_dec(r2, f2); fp8x8_dec(r3, f3);
            #pragma unroll
            for (int k = 0; k < 8; ++k)
                acc[k] += u0 * f0[k] + u1 * f1[k] + u2 * f2[k] + u3 * f3[k];
        }
        for (; j < jmax; ++j) {
            int s = __shfl(sl, j);
            float u = sel4(__shfl(wl.x, j), __shfl(wl.y, j), __shfl(wl.z, j), __shfl(wl.w, j), hd);
            int2 r = *(const int2*)&h1f8[(size_t)s * 512 + c0];
            float f[8]; fp8x8_dec(r, f);
            #pragma unroll
            for (int k = 0; k < 8; ++k) acc[k] += u * f[k];
        }
    }
    #pragma unroll
    for (int o = 32; o > 0; o >>= 1) {
        d0 += __shfl_xor(d0, o); d1 += __shfl_xor(d1, o);
        d2 += __shfl_xor(d2, o); d3 += __shfl_xor(d3, o);
    }
    d0 += w0; d1 += w1; d2 += w2; d3 += w3;
    float dh = sel4(d0, d1, d2, d3, hd);
    float inv = 1.f / dh;
    float4 bA = *(const float4*)&b1[c0], bB = *(const float4*)&b1[c0 + 4];
    float v0 = fmaxf(acc[0] * inv + bA.x, 0.f), v1 = fmaxf(acc[1] * inv + bA.y, 0.f);
    float v2 = fmaxf(acc[2] * inv + bA.z, 0.f), v3 = fmaxf(acc[3] * inv + bA.w, 0.f);
    float v4 = fmaxf(acc[4] * inv + bB.x, 0.f), v5 = fmaxf(acc[5] * inv + bB.y, 0.f);
    float v6 = fmaxf(acc[6] * inv + bB.z, 0.f), v7 = fmaxf(acc[7] * inv + bB.w, 0.f);
    int4 o;
    o.x = (int)((unsigned)f2bf(v0) | ((unsigned)f2bf(v1) << 16));
    o.y = (int)((unsigned)f2bf(v2) | ((unsigned)f2bf(v3) << 16));
    o.z = (int)((unsigned)f2bf(v4) | ((unsigned)f2bf(v5) << 16));
    o.w = (int)((unsigned)f2bf(v6) | ((unsigned)f2bf(v7) << 16));
    *(int4*)&ho1b[(size_t)node * 512 + c0] = o;
}

// Layer 2: unchanged bf16 (accuracy margin), unroll-8.
__global__ __launch_bounds__(256) void edge_agg2_kernel(
        const unsigned short* __restrict__ h2b,   // [N,256] bf16
        const float* __restrict__ as2,
        const float* __restrict__ ad2,
        const int* __restrict__ ofs,
        const int* __restrict__ esrc,
        const float* __restrict__ b2,
        unsigned short* __restrict__ ho2b, int N) {
    int wave = threadIdx.x >> 6, lane = threadIdx.x & 63;
    int node = blockIdx.x * 4 + wave;
    if (node >= N) return;
    int beg = ofs[node], end = ofs[node + 1];
    float adn = ad2[node];
    float wself = __expf(lrelu(as2[node] + adn));
    int c0 = lane * 4;
    float a0, a1, a2, a3;
    {
        int2 r = *(const int2*)&h2b[(size_t)node * 256 + c0];
        a0 = wself * bflo(r.x); a1 = wself * bfhi(r.x);
        a2 = wself * bflo(r.y); a3 = wself * bfhi(r.y);
    }
    float dsum = 0.f;
    for (int cb = beg; cb < end; cb += 64) {
        int idx = cb + lane;
        int sl = esrc[idx < end ? idx : end - 1];
        float wl = 0.f;
        if (idx < end) {
            wl = __expf(lrelu(as2[sl] + adn));
            dsum += wl;
        }
        int jmax = end - cb; if (jmax > 64) jmax = 64;
        int j = 0;
        for (; j + 8 <= jmax; j += 8) {
            int ss[8]; float u[8]; int2 r[8];
            #pragma unroll
            for (int q = 0; q < 8; ++q) {
                ss[q] = __shfl(sl, j + q);
                u[q] = __shfl(wl, j + q);
            }
            #pragma unroll
            for (int q = 0; q < 8; ++q) r[q] = *(const int2*)&h2b[(size_t)ss[q] * 256 + c0];
            #pragma unroll
            for (int q = 0; q < 8; ++q) {
                a0 += u[q] * bflo(r[q].x); a1 += u[q] * bfhi(r[q].x);
                a2 += u[q] * bflo(r[q].y); a3 += u[q] * bfhi(r[q].y);
            }
        }
        for (; j < jmax; ++j) {
            int s = __shfl(sl, j);
            float u = __shfl(wl, j);
            int2 r = *(const int2*)&h2b[(size_t)s * 256 + c0];
            a0 += u * bflo(r.x); a1 += u * bfhi(r.x);
            a2 += u * bflo(r.y); a3 += u * bfhi(r.y);
        }
    }
    #pragma unroll
    for (int o = 32; o > 0; o >>= 1) dsum += __shfl_xor(dsum, o);
    dsum += wself;
    float inv = 1.f / dsum;
    float4 bv = *(const float4*)&b2[c0];
    float v0 = a0 * inv + bv.x, v1 = a1 * inv + bv.y;
    float v2 = a2 * inv + bv.z, v3 = a3 * inv + bv.w;
    int2 o;
    o.x = (int)((unsigned)f2bf(v0) | ((unsigned)f2bf(v1) << 16));
    o.y = (int)((unsigned)f2bf(v2) | ((unsigned)f2bf(v3) << 16));
    *(int2*)&ho2b[(size_t)node * 256 + c0] = o;
}

// ---------------- global max pool, stage 1 (batch is sorted; bf16 input) ----------------
__global__ __launch_bounds__(256) void pool1_kernel(const unsigned short* __restrict__ ho2b,
                                                    const int* __restrict__ batch,
                                                    int N, float* __restrict__ part) {
    int g = blockIdx.x, c = blockIdx.y, t = threadIdx.x;
    int lo = 0, hi = N;
    while (lo < hi) { int mid = (lo + hi) >> 1; if (batch[mid] < g) lo = mid + 1; else hi = mid; }
    int start = lo;
    lo = 0; hi = N;
    while (lo < hi) { int mid = (lo + hi) >> 1; if (batch[mid] < g + 1) lo = mid + 1; else hi = mid; }
    int end = lo;
    int len = end - start;
    int cb = start + (int)(((long long)len * c) / PCHUNK);
    int ce = start + (int)(((long long)len * (c + 1)) / PCHUNK);
    float m = -INFINITY;
    for (int n = cb; n < ce; ++n) m = fmaxf(m, bfu(ho2b[(size_t)n * 256 + t]));
    part[((size_t)g * PCHUNK + c) * 256 + t] = m;
}

// ---------------- FC head (+pool stage 2) + log_softmax ----------------
__global__ __launch_bounds__(64) void head_kernel(const float* __restrict__ part,
                                                  const float* __restrict__ fc1w,
                                                  const float* __restrict__ fc1b,
                                                  const float* __restrict__ fc2w,
                                                  const float* __restrict__ fc2b,
                                                  float* __restrict__ out) {
    __shared__ float gr[256];
    __shared__ float hid[64];
    __shared__ float o10[NCLS];
    int g = blockIdx.x, t = threadIdx.x;
    for (int i = t; i < 256; i += 64) {
        float m = -INFINITY;
        #pragma unroll
        for (int c = 0; c < PCHUNK; ++c)
            m = fmaxf(m, part[((size_t)g * PCHUNK + c) * 256 + i]);
        gr[i] = m;
    }
    __syncthreads();
    float s = fc1b[t];
    for (int k = 0; k < 256; ++k) s += gr[k] * fc1w[k * 64 + t];
    hid[t] = s > 0.f ? s : 0.f;
    __syncthreads();
    if (t < NCLS) {
        float s2 = fc2b[t];
        for (int k = 0; k < 64; ++k) s2 += hid[k] * fc2w[k * NCLS + t];
        o10[t] = s2;
    }
    __syncthreads();
    if (t == 0) {
        float mx = -INFINITY;
        for (int c = 0; c < NCLS; ++c) mx = fmaxf(mx, o10[c]);
        float se = 0.f;
        for (int c = 0; c < NCLS; ++c) se += __expf(o10[c] - mx);
        float lse = mx + logf(se);
        for (int c = 0; c < NCLS; ++c) out[g * NCLS + c] = o10[c] - lse;
    }
}

extern "C" void kernel_launch(void* const* d_in, const int* in_sizes, int n_in,
                              void* d_out, int out_size, void* d_ws, size_t ws_size,
                              hipStream_t stream) {
    (void)n_in; (void)out_size; (void)ws_size;
    const float* x        = (const float*)d_in[0];
    const int*   ei       = (const int*)d_in[1];
    const int*   batch    = (const int*)d_in[2];
    const float* W1       = (const float*)d_in[3];
    const float* att_src1 = (const float*)d_in[4];
    const float* att_dst1 = (const float*)d_in[5];
    const float* b1       = (const float*)d_in[6];
    const float* W2       = (const float*)d_in[7];
    const float* att_src2 = (const float*)d_in[8];
    const float* att_dst2 = (const float*)d_in[9];
    const float* b2       = (const float*)d_in[10];
    const float* fc1w     = (const float*)d_in[11];
    const float* fc1b     = (const float*)d_in[12];
    const float* fc2w     = (const float*)d_in[13];
    const float* fc2b     = (const float*)d_in[14];

    const int N = in_sizes[2];
    const int E = in_sizes[1] / 2;
    const int tot = 2 * E;

    char* base = (char*)d_ws;
    size_t off = 0;
    auto alloc = [&](size_t bytes) -> void* {
        void* p = base + off;
        off = (off + bytes + 255) & ~(size_t)255;
        return p;
    };
    int*   ofs    = (int*)alloc((size_t)(N + 1) * 4);
    int*   cursor = (int*)alloc((size_t)N * 4);    // cursor, as2, ad2 zeroed by prep
    float* as2    = (float*)alloc((size_t)N * 4);
    float* ad2    = (float*)alloc((size_t)N * 4);
    int*   esrc   = (int*)alloc((size_t)tot * 4);
    float* as1    = (float*)alloc((size_t)N * HEADS * 4);
    float* ad1    = (float*)alloc((size_t)N * HEADS * 4);
    unsigned short* xb   = (unsigned short*)alloc((size_t)N * FDIM * 2);
    unsigned short* W1t  = (unsigned short*)alloc((size_t)512 * 128 * 2);
    unsigned short* W2t  = (unsigned short*)alloc((size_t)256 * 512 * 2);
    unsigned char*  h1f8 = (unsigned char*)alloc((size_t)N * 512);
    unsigned short* ho1b = (unsigned short*)alloc((size_t)N * 512 * 2);
    unsigned short* h2b  = (unsigned short*)alloc((size_t)N * 256 * 2);
    unsigned short* ho2b = (unsigned short*)alloc((size_t)N * 256 * 2);
    float* ppart  = (float*)alloc((size_t)NGRAPH * PCHUNK * 256 * 4);

    // fused prep: zero (cursor..ad2) + cvt(x) + tconv(W1) + tconv(W2)
    int nzero = (int)(((size_t)((char*)ad2 - (char*)cursor) + (size_t)N * 4) / 4);
    int ZB = (nzero + 255) / 256;
    int n4 = N * FDIM / 4;
    int CB = (n4 + 255) / 256;
    prep_kernel<<<ZB + CB + 64 + 128, 256, 0, stream>>>(
        cursor, nzero, x, xb, n4, W1, W1t, W2, W2t, ZB, CB);

    // CSR build
    hist_kernel<<<(tot + 255) / 256, 256, 0, stream>>>(ei, E, cursor);
    scan_kernel<<<1, 1024, 0, stream>>>(cursor, ofs, N);
    scatter_kernel<<<(tot + 255) / 256, 256, 0, stream>>>(ei, E, cursor, esrc);

    // Layer 1: h1 = x @ W1 (fp8 out); att1 fused into epilogue
    bgemm_kernel<1><<<dim3(512 / 128, (N + 63) / 64), 256, 0, stream>>>(
        xb, W1t, h1f8, att_src1, att_dst1, as1, ad1, N, 512, 128);
    edge_agg1_kernel<<<(N + 3) / 4, 256, 0, stream>>>(h1f8, (const float4*)as1, (const float4*)ad1,
                                                      ofs, esrc, b1, ho1b, N);

    // Layer 2: h2 = ho1 @ W2 (bf16 out); att2 fused (atomic partials)
    bgemm_kernel<2><<<dim3(256 / 128, (N + 63) / 64), 256, 0, stream>>>(
        ho1b, W2t, h2b, att_src2, att_dst2, as2, ad2, N, 256, 512);
    edge_agg2_kernel<<<(N + 3) / 4, 256, 0, stream>>>(h2b, as2, ad2, ofs, esrc, b2, ho2b, N);

    // Pool stage 1 + fused (pool stage 2 + head)
    pool1_kernel<<<dim3(NGRAPH, PCHUNK), 256, 0, stream>>>(ho2b, batch, N, ppart);
    head_kernel<<<NGRAPH, 64, 0, stream>>>(ppart, fc1w, fc1b, fc2w, fc2b, (float*)d_out);
}

// Round 14
// 241.788 us; speedup vs baseline: 1.6014x; 1.0152x over previous
//
#include <hip/hip_runtime.h>
#include <math.h>

// Problem constants (reference: N=20000, E=160000, F=128, H=4, C1=128, C2=256, G=64, NCLS=10)
#define FDIM 128
#define HEADS 4
#define C1DIM 128
#define C2DIM 256
#define NGRAPH 64
#define NCLS 10
#define PCHUNK 8

typedef __attribute__((ext_vector_type(8))) short short8;   // 8 bf16 (4 VGPRs)
typedef __attribute__((ext_vector_type(4))) float float4v;  // 4 fp32 acc
typedef __attribute__((ext_vector_type(2))) float floatx2;

__device__ __forceinline__ unsigned short f2bf(float f) {
    unsigned u = __builtin_bit_cast(unsigned, f);
    unsigned r = (u + 0x7FFFu + ((u >> 16) & 1u)) >> 16;   // RNE
    return (unsigned short)r;
}
__device__ __forceinline__ float bflo(int u) { return __builtin_bit_cast(float, (unsigned)u << 16); }
__device__ __forceinline__ float bfhi(int u) { return __builtin_bit_cast(float, (unsigned)u & 0xffff0000u); }
__device__ __forceinline__ float bfu(unsigned short u) { return __builtin_bit_cast(float, (unsigned)u << 16); }
__device__ __forceinline__ float lrelu(float x) { return x > 0.f ? x : 0.2f * x; }
__device__ __forceinline__ float sel4(float a, float b, float c, float d, int hd) {
    return hd == 0 ? a : hd == 1 ? b : hd == 2 ? c : d;
}
// fp8 e4m3 (OCP) encode/decode via gfx950 HW converts
__device__ __forceinline__ unsigned char f2fp8(float f) {
    return (unsigned char)(__builtin_amdgcn_cvt_pk_fp8_f32(f, f, 0, false) & 0xff);
}
__device__ __forceinline__ void fp8x8_dec(int2 r, float* f) {
    floatx2 p0 = __builtin_amdgcn_cvt_pk_f32_fp8(r.x, false);
    floatx2 p1 = __builtin_amdgcn_cvt_pk_f32_fp8(r.x, true);
    floatx2 p2 = __builtin_amdgcn_cvt_pk_f32_fp8(r.y, false);
    floatx2 p3 = __builtin_amdgcn_cvt_pk_f32_fp8(r.y, true);
    f[0] = p0.x; f[1] = p0.y; f[2] = p1.x; f[3] = p1.y;
    f[4] = p2.x; f[5] = p2.y; f[6] = p3.x; f[7] = p3.y;
}
__device__ __forceinline__ void fp8x4_dec(int r, float* f) {
    floatx2 p0 = __builtin_amdgcn_cvt_pk_f32_fp8(r, false);
    floatx2 p1 = __builtin_amdgcn_cvt_pk_f32_fp8(r, true);
    f[0] = p0.x; f[1] = p0.y; f[2] = p1.x; f[3] = p1.y;
}

// ---------------- fused prep: zero scratch + cvt(x) + tconv(W1) + tconv(W2) ----------------
__global__ __launch_bounds__(256) void prep_kernel(
        int* __restrict__ zero_base, int nzero_words,
        const float* __restrict__ x, unsigned short* __restrict__ xb, int n4,
        const float* __restrict__ W1, unsigned short* __restrict__ W1t,
        const float* __restrict__ W2, unsigned short* __restrict__ W2t,
        int ZB, int CB) {
    __shared__ float tile[32][33];
    int blk = blockIdx.x;
    if (blk < ZB) {
        int i = blk * 256 + threadIdx.x;
        if (i < nzero_words) zero_base[i] = 0;
        return;
    }
    blk -= ZB;
    if (blk < CB) {
        int i = blk * 256 + threadIdx.x;
        if (i < n4) {
            float4 v = ((const float4*)x)[i];
            ushort4 o;
            o.x = f2bf(v.x); o.y = f2bf(v.y); o.z = f2bf(v.z); o.w = f2bf(v.w);
            ((ushort4*)xb)[i] = o;
        }
        return;
    }
    blk -= CB;
    const float* W; unsigned short* Wt; int K, Nc, bx, by;
    if (blk < 64) {            // W1: K=128, N=512 -> 16 x 4
        W = W1; Wt = W1t; K = 128; Nc = 512;
        bx = (blk & 15) * 32; by = (blk >> 4) * 32;
    } else {                   // W2: K=512, N=256 -> 8 x 16
        blk -= 64;
        W = W2; Wt = W2t; K = 512; Nc = 256;
        bx = (blk & 7) * 32; by = (blk >> 3) * 32;
    }
    int tx = threadIdx.x & 31, ty = threadIdx.x >> 5;
    #pragma unroll
    for (int r = 0; r < 32; r += 8)
        tile[ty + r][tx] = W[(size_t)(by + ty + r) * Nc + bx + tx];
    __syncthreads();
    #pragma unroll
    for (int r = 0; r < 32; r += 8)
        Wt[(size_t)(bx + ty + r) * K + by + tx] = f2bf(tile[tx][ty + r]);
}

// ---------------- CSR build ----------------
__global__ void hist_kernel(const int* __restrict__ ei, int E, int* __restrict__ counts) {
    int i = blockIdx.x * blockDim.x + threadIdx.x;
    if (i >= 2 * E) return;
    int dst = (i < E) ? ei[E + i] : ei[i - E];
    atomicAdd(&counts[dst], 1);
}

__global__ __launch_bounds__(1024) void scan_kernel(int* __restrict__ counts_cursor,
                                                    int* __restrict__ ofs, int N) {
    __shared__ int part[1024];
    int t = threadIdx.x;
    int chunk = (N + 1023) / 1024;
    int b = t * chunk;
    int e = b + chunk; if (e > N) e = N;
    int s = 0;
    int i = b;
    if ((chunk & 3) == 0) {
        for (; i + 4 <= e; i += 4) {
            int4 v = *(const int4*)&counts_cursor[i];
            s += v.x + v.y + v.z + v.w;
        }
    }
    for (; i < e; ++i) s += counts_cursor[i];
    part[t] = s;
    __syncthreads();
    for (int o = 1; o < 1024; o <<= 1) {
        int v = (t >= o) ? part[t - o] : 0;
        __syncthreads();
        part[t] += v;
        __syncthreads();
    }
    int run = part[t] - s;
    i = b;
    if ((chunk & 3) == 0) {
        for (; i + 4 <= e; i += 4) {
            int4 c = *(const int4*)&counts_cursor[i];
            int4 o4;
            o4.x = run; run += c.x;
            o4.y = run; run += c.y;
            o4.z = run; run += c.z;
            o4.w = run; run += c.w;
            *(int4*)&ofs[i] = o4;
            counts_cursor[i]     = o4.x;
            counts_cursor[i + 1] = o4.y;
            counts_cursor[i + 2] = o4.z;
            counts_cursor[i + 3] = o4.w;
        }
    }
    for (; i < e; ++i) {
        int c = counts_cursor[i];
        ofs[i] = run;
        counts_cursor[i] = run;
        run += c;
    }
    if (t == 1023) ofs[N] = part[1023];
}

__global__ void scatter_kernel(const int* __restrict__ ei, int E,
                               int* __restrict__ cursor, int* __restrict__ esrc) {
    int i = blockIdx.x * blockDim.x + threadIdx.x;
    if (i >= 2 * E) return;
    int src = ei[i];
    int dst = (i < E) ? ei[E + i] : ei[i - E];
    int pos = atomicAdd(&cursor[dst], 1);
    esrc[pos] = src;
}

// ---------------- bf16 MFMA GEMM (64x128 tile) + fused attention epilogue ----------------
// Both modes: C out = fp8 e4m3 (consumed only by edge-agg gathers; att scores come
// from the fp32 accumulators here, so fp8 C costs only the gather payload precision).
// MODE 1 (N_=512): one col-tile == one head -> as/ad[r*4+blockIdx.x] direct write.
// MODE 2 (N_=256): att spans both col-tiles -> atomicAdd partials (pre-zeroed).
// Cs staging aliases As/Bs — safe: K-loop ends with __syncthreads.
template<int MODE>
__global__ __launch_bounds__(256) void bgemm_kernel(
        const unsigned short* __restrict__ A,   // [M,K] bf16
        const unsigned short* __restrict__ Bt,  // [N,K] bf16
        unsigned char* __restrict__ Cout,       // [M,N_] fp8
        const float* __restrict__ att_src,
        const float* __restrict__ att_dst,
        float* __restrict__ as_out,
        float* __restrict__ ad_out,
        int M, int N_, int K) {
    constexpr int CPADB = 144;                               // Cs row stride (bytes)
    __shared__ __align__(16) unsigned char smem[12288];
    unsigned short* As = (unsigned short*)smem;              // 4 KB
    unsigned short* Bs = (unsigned short*)(smem + 4096);     // 8 KB
    __shared__ float sd_s[4][32];
    __shared__ float sd_d[4][32];
    const int t = threadIdx.x;
    const int lane = t & 63;
    const int wave = t >> 6;
    const int row0 = blockIdx.y * 64, col0 = blockIdx.x * 128;
    const int wr = (wave >> 1) * 32, wc = (wave & 1) * 64;
    float4v acc[2][4] = {};
    for (int k0 = 0; k0 < K; k0 += 32) {
        {
            int i = t;
            int gr = row0 + (i >> 2); if (gr >= M) gr = M - 1;
            const unsigned short* gp = A + (size_t)gr * K + k0 + ((i & 3) << 3);
            __builtin_amdgcn_global_load_lds(
                (const __attribute__((address_space(1))) unsigned int*)gp,
                (__attribute__((address_space(3))) unsigned int*)&As[i * 8], 16, 0, 0);
        }
        #pragma unroll
        for (int c = 0; c < 2; ++c) {
            int i = c * 256 + t;
            int gn = col0 + (i >> 2);
            const unsigned short* gp = Bt + (size_t)gn * K + k0 + ((i & 3) << 3);
            __builtin_amdgcn_global_load_lds(
                (const __attribute__((address_space(1))) unsigned int*)gp,
                (__attribute__((address_space(3))) unsigned int*)&Bs[i * 8], 16, 0, 0);
        }
        __syncthreads();
        short8 af[2], bfr[4];
        #pragma unroll
        for (int i = 0; i < 2; ++i)
            af[i] = *(const short8*)&As[(wr + i * 16 + (lane & 15)) * 32 + (lane >> 4) * 8];
        #pragma unroll
        for (int j = 0; j < 4; ++j)
            bfr[j] = *(const short8*)&Bs[(wc + j * 16 + (lane & 15)) * 32 + (lane >> 4) * 8];
        #pragma unroll
        for (int i = 0; i < 2; ++i)
            #pragma unroll
            for (int j = 0; j < 4; ++j)
                acc[i][j] = __builtin_amdgcn_mfma_f32_16x16x32_bf16(af[i], bfr[j], acc[i][j], 0, 0, 0);
        __syncthreads();
    }
    // epilogue: stage fp8 C into (aliased) LDS + attention row-dots
    float asv[4], adv[4];
    #pragma unroll
    for (int j = 0; j < 4; ++j) {
        int cc = col0 + wc + j * 16 + (lane & 15);
        asv[j] = att_src[cc];
        adv[j] = att_dst[cc];
    }
    #pragma unroll
    for (int i = 0; i < 2; ++i) {
        #pragma unroll
        for (int p = 0; p < 4; ++p) {
            int rr = wr + i * 16 + (lane >> 4) * 4 + p;
            #pragma unroll
            for (int j = 0; j < 4; ++j)
                smem[rr * CPADB + wc + j * 16 + (lane & 15)] = f2fp8(acc[i][j][p]);
            float s = acc[i][0][p] * asv[0] + acc[i][1][p] * asv[1]
                    + acc[i][2][p] * asv[2] + acc[i][3][p] * asv[3];
            float d = acc[i][0][p] * adv[0] + acc[i][1][p] * adv[1]
                    + acc[i][2][p] * adv[2] + acc[i][3][p] * adv[3];
            #pragma unroll
            for (int o = 1; o <= 8; o <<= 1) { s += __shfl_xor(s, o); d += __shfl_xor(d, o); }
            if ((lane & 15) == 0) {
                int ridx = i * 16 + (lane >> 4) * 4 + p;
                sd_s[wave][ridx] = s;
                sd_d[wave][ridx] = d;
            }
        }
    }
    __syncthreads();
    // coalesced C store: 64 rows x 128 B = 512 int4
    #pragma unroll
    for (int it = 0; it < 2; ++it) {
        int idx = it * 256 + t;
        int row = idx >> 3, c16 = (idx & 7) * 16;
        int gr = row0 + row;
        if (gr < M)
            *(int4*)&Cout[(size_t)gr * N_ + col0 + c16] = *(const int4*)&smem[row * CPADB + c16];
    }
    if ((wave & 1) == 0 && lane < 32) {
        float s = sd_s[wave][lane] + sd_s[wave + 1][lane];
        float d = sd_d[wave][lane] + sd_d[wave + 1][lane];
        int r = row0 + wr + lane;
        if (r < M) {
            if (MODE == 1) {
                as_out[r * 4 + blockIdx.x] = s;
                ad_out[r * 4 + blockIdx.x] = d;
            } else {
                atomicAdd(&as_out[r], s);
                atomicAdd(&ad_out[r], d);
            }
        }
    }
}

// ---------------- edge aggregate L1: fp8 gathers ----------------
__global__ __launch_bounds__(256) void edge_agg1_kernel(
        const unsigned char* __restrict__ h1f8,   // [N,512] fp8 e4m3
        const float4* __restrict__ as14,
        const float4* __restrict__ ad14,
        const int* __restrict__ ofs,
        const int* __restrict__ esrc,
        const float* __restrict__ b1,
        unsigned short* __restrict__ ho1b, int N) {
    int wave = threadIdx.x >> 6, lane = threadIdx.x & 63;
    int node = blockIdx.x * 4 + wave;
    if (node >= N) return;
    int beg = ofs[node], end = ofs[node + 1];
    float4 asn = as14[node], adn = ad14[node];
    float w0 = __expf(lrelu(asn.x + adn.x));
    float w1 = __expf(lrelu(asn.y + adn.y));
    float w2 = __expf(lrelu(asn.z + adn.z));
    float w3 = __expf(lrelu(asn.w + adn.w));
    int hd = lane >> 4;
    int c0 = lane * 8;
    float wsh = sel4(w0, w1, w2, w3, hd);
    float acc[8];
    {
        int2 rs = *(const int2*)&h1f8[(size_t)node * 512 + c0];
        float f[8]; fp8x8_dec(rs, f);
        #pragma unroll
        for (int k = 0; k < 8; ++k) acc[k] = wsh * f[k];
    }
    float d0 = 0.f, d1 = 0.f, d2 = 0.f, d3 = 0.f;
    for (int cb = beg; cb < end; cb += 64) {
        int idx = cb + lane;
        int sl = esrc[idx < end ? idx : end - 1];
        float4 wl = make_float4(0.f, 0.f, 0.f, 0.f);
        if (idx < end) {
            float4 a = as14[sl];
            wl.x = __expf(lrelu(a.x + adn.x));
            wl.y = __expf(lrelu(a.y + adn.y));
            wl.z = __expf(lrelu(a.z + adn.z));
            wl.w = __expf(lrelu(a.w + adn.w));
            d0 += wl.x; d1 += wl.y; d2 += wl.z; d3 += wl.w;
        }
        int jmax = end - cb; if (jmax > 64) jmax = 64;
        int j = 0;
        for (; j + 4 <= jmax; j += 4) {
            int s0 = __shfl(sl, j), s1 = __shfl(sl, j + 1);
            int s2 = __shfl(sl, j + 2), s3 = __shfl(sl, j + 3);
            float u0 = sel4(__shfl(wl.x, j), __shfl(wl.y, j), __shfl(wl.z, j), __shfl(wl.w, j), hd);
            float u1 = sel4(__shfl(wl.x, j + 1), __shfl(wl.y, j + 1), __shfl(wl.z, j + 1), __shfl(wl.w, j + 1), hd);
            float u2 = sel4(__shfl(wl.x, j + 2), __shfl(wl.y, j + 2), __shfl(wl.z, j + 2), __shfl(wl.w, j + 2), hd);
            float u3 = sel4(__shfl(wl.x, j + 3), __shfl(wl.y, j + 3), __shfl(wl.z, j + 3), __shfl(wl.w, j + 3), hd);
            int2 r0 = *(const int2*)&h1f8[(size_t)s0 * 512 + c0];
            int2 r1 = *(const int2*)&h1f8[(size_t)s1 * 512 + c0];
            int2 r2 = *(const int2*)&h1f8[(size_t)s2 * 512 + c0];
            int2 r3 = *(const int2*)&h1f8[(size_t)s3 * 512 + c0];
            float f0[8], f1[8], f2[8], f3[8];
            fp8x8_dec(r0, f0); fp8x8_dec(r1, f1); fp8x8_dec(r2, f2); fp8x8_dec(r3, f3);
            #pragma unroll
            for (int k = 0; k < 8; ++k)
                acc[k] += u0 * f0[k] + u1 * f1[k] + u2 * f2[k] + u3 * f3[k];
        }
        for (; j < jmax; ++j) {
            int s = __shfl(sl, j);
            float u = sel4(__shfl(wl.x, j), __shfl(wl.y, j), __shfl(wl.z, j), __shfl(wl.w, j), hd);
            int2 r = *(const int2*)&h1f8[(size_t)s * 512 + c0];
            float f[8]; fp8x8_dec(r, f);
            #pragma unroll
            for (int k = 0; k < 8; ++k) acc[k] += u * f[k];
        }
    }
    #pragma unroll
    for (int o = 32; o > 0; o >>= 1) {
        d0 += __shfl_xor(d0, o); d1 += __shfl_xor(d1, o);
        d2 += __shfl_xor(d2, o); d3 += __shfl_xor(d3, o);
    }
    d0 += w0; d1 += w1; d2 += w2; d3 += w3;
    float dh = sel4(d0, d1, d2, d3, hd);
    float inv = 1.f / dh;
    float4 bA = *(const float4*)&b1[c0], bB = *(const float4*)&b1[c0 + 4];
    float v0 = fmaxf(acc[0] * inv + bA.x, 0.f), v1 = fmaxf(acc[1] * inv + bA.y, 0.f);
    float v2 = fmaxf(acc[2] * inv + bA.z, 0.f), v3 = fmaxf(acc[3] * inv + bA.w, 0.f);
    float v4 = fmaxf(acc[4] * inv + bB.x, 0.f), v5 = fmaxf(acc[5] * inv + bB.y, 0.f);
    float v6 = fmaxf(acc[6] * inv + bB.z, 0.f), v7 = fmaxf(acc[7] * inv + bB.w, 0.f);
    int4 o;
    o.x = (int)((unsigned)f2bf(v0) | ((unsigned)f2bf(v1) << 16));
    o.y = (int)((unsigned)f2bf(v2) | ((unsigned)f2bf(v3) << 16));
    o.z = (int)((unsigned)f2bf(v4) | ((unsigned)f2bf(v5) << 16));
    o.w = (int)((unsigned)f2bf(v6) | ((unsigned)f2bf(v7) << 16));
    *(int4*)&ho1b[(size_t)node * 512 + c0] = o;
}

// ---------------- edge aggregate L2: fp8 dword gathers, unroll-8 ----------------
__global__ __launch_bounds__(256) void edge_agg2_kernel(
        const unsigned char* __restrict__ h2f8,   // [N,256] fp8 e4m3
        const float* __restrict__ as2,
        const float* __restrict__ ad2,
        const int* __restrict__ ofs,
        const int* __restrict__ esrc,
        const float* __restrict__ b2,
        unsigned short* __restrict__ ho2b, int N) {
    int wave = threadIdx.x >> 6, lane = threadIdx.x & 63;
    int node = blockIdx.x * 4 + wave;
    if (node >= N) return;
    int beg = ofs[node], end = ofs[node + 1];
    float adn = ad2[node];
    float wself = __expf(lrelu(as2[node] + adn));
    int c0 = lane * 4;                       // channel == byte offset (fp8)
    float a0, a1, a2, a3;
    {
        int r = *(const int*)&h2f8[(size_t)node * 256 + c0];
        float f[4]; fp8x4_dec(r, f);
        a0 = wself * f[0]; a1 = wself * f[1]; a2 = wself * f[2]; a3 = wself * f[3];
    }
    float dsum = 0.f;
    for (int cb = beg; cb < end; cb += 64) {
        int idx = cb + lane;
        int sl = esrc[idx < end ? idx : end - 1];
        float wl = 0.f;
        if (idx < end) {
            wl = __expf(lrelu(as2[sl] + adn));
            dsum += wl;
        }
        int jmax = end - cb; if (jmax > 64) jmax = 64;
        int j = 0;
        for (; j + 8 <= jmax; j += 8) {
            int ss[8]; float u[8]; int r[8];
            #pragma unroll
            for (int q = 0; q < 8; ++q) {
                ss[q] = __shfl(sl, j + q);
                u[q] = __shfl(wl, j + q);
            }
            #pragma unroll
            for (int q = 0; q < 8; ++q) r[q] = *(const int*)&h2f8[(size_t)ss[q] * 256 + c0];
            #pragma unroll
            for (int q = 0; q < 8; ++q) {
                float f[4]; fp8x4_dec(r[q], f);
                a0 += u[q] * f[0]; a1 += u[q] * f[1];
                a2 += u[q] * f[2]; a3 += u[q] * f[3];
            }
        }
        for (; j < jmax; ++j) {
            int s = __shfl(sl, j);
            float u = __shfl(wl, j);
            int r = *(const int*)&h2f8[(size_t)s * 256 + c0];
            float f[4]; fp8x4_dec(r, f);
            a0 += u * f[0]; a1 += u * f[1]; a2 += u * f[2]; a3 += u * f[3];
        }
    }
    #pragma unroll
    for (int o = 32; o > 0; o >>= 1) dsum += __shfl_xor(dsum, o);
    dsum += wself;
    float inv = 1.f / dsum;
    float4 bv = *(const float4*)&b2[c0];
    float v0 = a0 * inv + bv.x, v1 = a1 * inv + bv.y;
    float v2 = a2 * inv + bv.z, v3 = a3 * inv + bv.w;
    int2 o;
    o.x = (int)((unsigned)f2bf(v0) | ((unsigned)f2bf(v1) << 16));
    o.y = (int)((unsigned)f2bf(v2) | ((unsigned)f2bf(v3) << 16));
    *(int2*)&ho2b[(size_t)node * 256 + c0] = o;
}

// ---------------- global max pool, stage 1 (batch is sorted; bf16 input) ----------------
__global__ __launch_bounds__(256) void pool1_kernel(const unsigned short* __restrict__ ho2b,
                                                    const int* __restrict__ batch,
                                                    int N, float* __restrict__ part) {
    int g = blockIdx.x, c = blockIdx.y, t = threadIdx.x;
    int lo = 0, hi = N;
    while (lo < hi) { int mid = (lo + hi) >> 1; if (batch[mid] < g) lo = mid + 1; else hi = mid; }
    int start = lo;
    lo = 0; hi = N;
    while (lo < hi) { int mid = (lo + hi) >> 1; if (batch[mid] < g + 1) lo = mid + 1; else hi = mid; }
    int end = lo;
    int len = end - start;
    int cb = start + (int)(((long long)len * c) / PCHUNK);
    int ce = start + (int)(((long long)len * (c + 1)) / PCHUNK);
    float m = -INFINITY;
    for (int n = cb; n < ce; ++n) m = fmaxf(m, bfu(ho2b[(size_t)n * 256 + t]));
    part[((size_t)g * PCHUNK + c) * 256 + t] = m;
}

// ---------------- FC head (+pool stage 2) + log_softmax ----------------
__global__ __launch_bounds__(64) void head_kernel(const float* __restrict__ part,
                                                  const float* __restrict__ fc1w,
                                                  const float* __restrict__ fc1b,
                                                  const float* __restrict__ fc2w,
                                                  const float* __restrict__ fc2b,
                                                  float* __restrict__ out) {
    __shared__ float gr[256];
    __shared__ float hid[64];
    __shared__ float o10[NCLS];
    int g = blockIdx.x, t = threadIdx.x;
    for (int i = t; i < 256; i += 64) {
        float m = -INFINITY;
        #pragma unroll
        for (int c = 0; c < PCHUNK; ++c)
            m = fmaxf(m, part[((size_t)g * PCHUNK + c) * 256 + i]);
        gr[i] = m;
    }
    __syncthreads();
    float s = fc1b[t];
    for (int k = 0; k < 256; ++k) s += gr[k] * fc1w[k * 64 + t];
    hid[t] = s > 0.f ? s : 0.f;
    __syncthreads();
    if (t < NCLS) {
        float s2 = fc2b[t];
        for (int k = 0; k < 64; ++k) s2 += hid[k] * fc2w[k * NCLS + t];
        o10[t] = s2;
    }
    __syncthreads();
    if (t == 0) {
        float mx = -INFINITY;
        for (int c = 0; c < NCLS; ++c) mx = fmaxf(mx, o10[c]);
        float se = 0.f;
        for (int c = 0; c < NCLS; ++c) se += __expf(o10[c] - mx);
        float lse = mx + logf(se);
        for (int c = 0; c < NCLS; ++c) out[g * NCLS + c] = o10[c] - lse;
    }
}

extern "C" void kernel_launch(void* const* d_in, const int* in_sizes, int n_in,
                              void* d_out, int out_size, void* d_ws, size_t ws_size,
                              hipStream_t stream) {
    (void)n_in; (void)out_size; (void)ws_size;
    const float* x        = (const float*)d_in[0];
    const int*   ei       = (const int*)d_in[1];
    const int*   batch    = (const int*)d_in[2];
    const float* W1       = (const float*)d_in[3];
    const float* att_src1 = (const float*)d_in[4];
    const float* att_dst1 = (const float*)d_in[5];
    const float* b1       = (const float*)d_in[6];
    const float* W2       = (const float*)d_in[7];
    const float* att_src2 = (const float*)d_in[8];
    const float* att_dst2 = (const float*)d_in[9];
    const float* b2       = (const float*)d_in[10];
    const float* fc1w     = (const float*)d_in[11];
    const float* fc1b     = (const float*)d_in[12];
    const float* fc2w     = (const float*)d_in[13];
    const float* fc2b     = (const float*)d_in[14];

    const int N = in_sizes[2];
    const int E = in_sizes[1] / 2;
    const int tot = 2 * E;

    char* base = (char*)d_ws;
    size_t off = 0;
    auto alloc = [&](size_t bytes) -> void* {
        void* p = base + off;
        off = (off + bytes + 255) & ~(size_t)255;
        return p;
    };
    int*   ofs    = (int*)alloc((size_t)(N + 1) * 4);
    int*   cursor = (int*)alloc((size_t)N * 4);    // cursor, as2, ad2 zeroed by prep
    float* as2    = (float*)alloc((size_t)N * 4);
    float* ad2    = (float*)alloc((size_t)N * 4);
    int*   esrc   = (int*)alloc((size_t)tot * 4);
    float* as1    = (float*)alloc((size_t)N * HEADS * 4);
    float* ad1    = (float*)alloc((size_t)N * HEADS * 4);
    unsigned short* xb   = (unsigned short*)alloc((size_t)N * FDIM * 2);
    unsigned short* W1t  = (unsigned short*)alloc((size_t)512 * 128 * 2);
    unsigned short* W2t  = (unsigned short*)alloc((size_t)256 * 512 * 2);
    unsigned char*  h1f8 = (unsigned char*)alloc((size_t)N * 512);
    unsigned short* ho1b = (unsigned short*)alloc((size_t)N * 512 * 2);
    unsigned char*  h2f8 = (unsigned char*)alloc((size_t)N * 256);
    unsigned short* ho2b = (unsigned short*)alloc((size_t)N * 256 * 2);
    float* ppart  = (float*)alloc((size_t)NGRAPH * PCHUNK * 256 * 4);

    // fused prep: zero (cursor..ad2) + cvt(x) + tconv(W1) + tconv(W2)
    int nzero = (int)(((size_t)((char*)ad2 - (char*)cursor) + (size_t)N * 4) / 4);
    int ZB = (nzero + 255) / 256;
    int n4 = N * FDIM / 4;
    int CB = (n4 + 255) / 256;
    prep_kernel<<<ZB + CB + 64 + 128, 256, 0, stream>>>(
        cursor, nzero, x, xb, n4, W1, W1t, W2, W2t, ZB, CB);

    // CSR build
    hist_kernel<<<(tot + 255) / 256, 256, 0, stream>>>(ei, E, cursor);
    scan_kernel<<<1, 1024, 0, stream>>>(cursor, ofs, N);
    scatter_kernel<<<(tot + 255) / 256, 256, 0, stream>>>(ei, E, cursor, esrc);

    // Layer 1: h1 = x @ W1 (fp8 out); att1 fused into epilogue
    bgemm_kernel<1><<<dim3(512 / 128, (N + 63) / 64), 256, 0, stream>>>(
        xb, W1t, h1f8, att_src1, att_dst1, as1, ad1, N, 512, 128);
    edge_agg1_kernel<<<(N + 3) / 4, 256, 0, stream>>>(h1f8, (const float4*)as1, (const float4*)ad1,
                                                      ofs, esrc, b1, ho1b, N);

    // Layer 2: h2 = ho1 @ W2 (fp8 out); att2 fused (atomic partials)
    bgemm_kernel<2><<<dim3(256 / 128, (N + 63) / 64), 256, 0, stream>>>(
        ho1b, W2t, h2f8, att_src2, att_dst2, as2, ad2, N, 256, 512);
    edge_agg2_kernel<<<(N + 3) / 4, 256, 0, stream>>>(h2f8, as2, ad2, ofs, esrc, b2, ho2b, N);

    // Pool stage 1 + fused (pool stage 2 + head)
    pool1_kernel<<<dim3(NGRAPH, PCHUNK), 256, 0, stream>>>(ho2b, batch, N, ppart);
    head_kernel<<<NGRAPH, 64, 0, stream>>>(ppart, fc1w, fc1b, fc2w, fc2b, (float*)d_out);
}